// Round 9
// baseline (786.998 us; speedup 1.0000x reference)
//
#include <hip/hip_runtime.h>

#define HD 128

constexpr int N_ATOMS = 20000;
constexpr int N_EDGES = 320000;
constexpr int NLAY   = 4;
constexpr int NMOL   = 200;
constexpr float FCUT  = 5.0f;
constexpr float DELTA = FCUT / 127.0f;
constexpr float GCOEFF = -0.5f / (DELTA * DELTA);
constexpr float PI_F  = 3.14159265358979323846f;
constexpr float LN2F  = 0.6931471805599453f;

typedef unsigned short u16;
typedef __attribute__((ext_vector_type(8))) short short8v;
typedef __attribute__((ext_vector_type(4))) float f32x4;

__device__ __forceinline__ float sspf(float x) {
  return fmaxf(x, 0.0f) + log1pf(expf(-fabsf(x))) - LN2F;
}
__device__ __forceinline__ float sigmf(float x) {
  return 1.0f / (1.0f + expf(-x));
}

// bf16 pack/unpack (round-to-nearest-even)
__device__ __forceinline__ unsigned bfpack(float a, float b) {
  unsigned ua = __float_as_uint(a);
  unsigned ub = __float_as_uint(b);
  ua = (ua + 0x7FFFu + ((ua >> 16) & 1u)) >> 16;
  ub = (ub + 0x7FFFu + ((ub >> 16) & 1u)) >> 16;
  return (ub << 16) | ua;
}
__device__ __forceinline__ float bflo(unsigned p) { return __uint_as_float(p << 16); }
__device__ __forceinline__ float bfhi(unsigned p) { return __uint_as_float(p & 0xFFFF0000u); }
__device__ __forceinline__ u16 f2bf(float x) {
  unsigned u = __float_as_uint(x);
  u = (u + 0x7FFFu + ((u >> 16) & 1u)) >> 16;
  return (u16)u;
}
__device__ __forceinline__ float bf2f(u16 b) { return __uint_as_float((unsigned)b << 16); }

// split f32 into hi bf16 (truncate) + lo bf16, packed u32 (hi<<16 | lo)
__device__ __forceinline__ unsigned packhl(float s) {
  unsigned hs = __float_as_uint(s) & 0xffff0000u;
  float lo = s - __uint_as_float(hs);
  return hs | (__float_as_uint(lo) >> 16);
}

// two f32 bit patterns -> hi-pair uint and lo-pair uint (bf16 pairs)
__device__ __forceinline__ unsigned hpair_f32(unsigned a, unsigned b, unsigned& lopair) {
  unsigned ha = a & 0xffff0000u, hb = b & 0xffff0000u;
  float la = __uint_as_float(a) - __uint_as_float(ha);
  float lb = __uint_as_float(b) - __uint_as_float(hb);
  lopair = (__float_as_uint(lb) & 0xffff0000u) | (__float_as_uint(la) >> 16);
  return hb | (ha >> 16);
}

// ------------------------------------------------------------------
// small elementwise kernels
// ------------------------------------------------------------------

__global__ __launch_bounds__(256) void h0_k(
    const float* __restrict__ emb, const int* __restrict__ z,
    float* __restrict__ h0)
{
  int i = blockIdx.x * 256 + threadIdx.x;
  if (i >= N_ATOMS * HD) return;
  int n = i >> 7, k = i & 127;
  h0[i] = emb[z[n] * HD + k];
}

// bf16 weight prep:
//  wsel 0..2 (lin1,lin2,blk): wp = bf16(W) row-major, wt = bf16(W^T)
//  wsel 3..4 (mlp_w1,mlp_w2): mt = bf16(W^T) only
__global__ __launch_bounds__(256) void wprep_k(
    const float* __restrict__ l1, const float* __restrict__ l2,
    const float* __restrict__ bw, const float* __restrict__ mw1,
    const float* __restrict__ mw2,
    u16* __restrict__ wt, u16* __restrict__ wp, u16* __restrict__ mt)
{
  int i = blockIdx.x * 256 + threadIdx.x;
  if (i >= NLAY * 5 * HD * HD) return;
  int e = i & (HD * HD - 1);
  int wl = i >> 14;
  int wsel = wl % 5;
  int lay = wl / 5;
  const float* W;
  if      (wsel == 0) W = l1;
  else if (wsel == 1) W = l2;
  else if (wsel == 2) W = bw;
  else if (wsel == 3) W = mw1;
  else                W = mw2;
  W += (size_t)lay * HD * HD;
  u16 b = f2bf(W[e]);
  int k = e >> 7, n = e & 127;
  if (wsel < 3) {
    size_t base = (size_t)(lay * 3 + wsel) << 14;
    wp[base + e] = b;
    wt[base + (size_t)n * HD + k] = b;
  } else {
    size_t base = (size_t)(lay * 2 + (wsel - 3)) << 14;
    mt[base + (size_t)n * HD + k] = b;
  }
}

// ------------------------------------------------------------------
// CSR build: combined histogram, dual scan (+degree histogram), scatter
// ------------------------------------------------------------------
__global__ __launch_bounds__(256) void histboth_k(
    const int* __restrict__ row, const int* __restrict__ col,
    int* __restrict__ cntR, int* __restrict__ cntC)
{
  int e = blockIdx.x * 256 + threadIdx.x;
  if (e >= N_EDGES) return;
  atomicAdd(&cntC[col[e]], 1);
  atomicAdd(&cntR[row[e]], 1);
}

// block 0: cnt0 -> cptr,cur0,binc ; block 1: cnt1 -> rptr,cur1,binr
// register-cached; also builds the degree histogram (bin = 255-min(d,255))
// via per-block LDS atomics + exclusive plain store (no global atomics)
__global__ __launch_bounds__(256) void scan2_k(
    const int* __restrict__ cnt0, const int* __restrict__ cnt1,
    int* __restrict__ cptr, int* __restrict__ rptr,
    int* __restrict__ cur0, int* __restrict__ cur1,
    int* __restrict__ binc, int* __restrict__ binr)
{
  constexpr int CH = 80;  // 256*80 = 20480 >= 20001; 320 B/thread, 16B-aligned
  __shared__ int part[256];
  __shared__ int lh[256];
  const int* cnt = blockIdx.x == 0 ? cnt0 : cnt1;
  int* ptr = blockIdx.x == 0 ? cptr : rptr;
  int* cur = blockIdx.x == 0 ? cur0 : cur1;
  int* bin = blockIdx.x == 0 ? binc : binr;
  int t = threadIdx.x;
  lh[t] = 0;
  int base = t * CH;
  int v[CH];
  if (base + CH <= N_ATOMS) {
#pragma unroll
    for (int i = 0; i < CH / 4; i++) {
      int4 q = *(const int4*)(cnt + base + i * 4);
      v[4*i+0] = q.x; v[4*i+1] = q.y; v[4*i+2] = q.z; v[4*i+3] = q.w;
    }
  } else {
#pragma unroll
    for (int i = 0; i < CH; i++)
      v[i] = (base + i < N_ATOMS) ? cnt[base + i] : 0;
  }
  __syncthreads();   // lh zeroed everywhere before atomics
#pragma unroll
  for (int i = 0; i < CH; i++)
    if (base + i < N_ATOMS) atomicAdd(&lh[255 - min(v[i], 255)], 1);
  int s = 0;
#pragma unroll
  for (int i = 0; i < CH; i++) s += v[i];
  part[t] = s;
  __syncthreads();   // all lh atomics + part writes complete
  bin[t] = lh[t];    // exclusive per-block ownership: plain store
  for (int off = 1; off < 256; off <<= 1) {
    int u = (t >= off) ? part[t - off] : 0;
    __syncthreads();
    part[t] += u;
    __syncthreads();
  }
  int run = part[t] - s;
#pragma unroll
  for (int i = 0; i < CH; i++) {
    int idx = base + i;
    if (idx < N_ATOMS) { ptr[idx] = run; cur[idx] = run; }
    else if (idx == N_ATOMS) ptr[idx] = run;
    run += v[i];
  }
}

// geometry + both-direction CSR scatter; stores packed {other|i0<<16, t}
__global__ __launch_bounds__(256) void scatboth_k(
    const float* __restrict__ pos, const int* __restrict__ row,
    const int* __restrict__ col, int* __restrict__ cur0,
    int* __restrict__ cur1, uint2* __restrict__ cpk2,
    uint2* __restrict__ rpk2, int* __restrict__ cslot, float inv_h)
{
  int e = blockIdx.x * 256 + threadIdx.x;
  if (e >= N_EDGES) return;
  int r = row[e], c = col[e];
  float dx = pos[3*r+0] - pos[3*c+0];
  float dy = pos[3*r+1] - pos[3*c+1];
  float dz = pos[3*r+2] - pos[3*c+2];
  float d = sqrtf(dx*dx + dy*dy + dz*dz);
  float fi = d * inv_h;
  int i0 = (int)fi;
  float t = fi - (float)i0;
  unsigned pk = (unsigned)c | ((unsigned)i0 << 16);
  unsigned tu = __float_as_uint(t);
  int pr = atomicAdd(&cur1[r], 1);
  rpk2[pr] = make_uint2(pk, tu);
  int pc = atomicAdd(&cur0[c], 1);
  cpk2[pc] = make_uint2((unsigned)r | ((unsigned)i0 << 16), tu);
  cslot[pc] = pr;
}

// ------------------------------------------------------------------
// degree-sort permutation (descending): two-level ranks, no hot
// global atomics (per-block LDS hist -> one range-reserve per bin)
// ------------------------------------------------------------------
__global__ __launch_bounds__(256) void dscan_k(
    int* __restrict__ binc, int* __restrict__ binr)
{
  int* bin = blockIdx.x == 0 ? binc : binr;
  __shared__ int sh[256];
  int t = threadIdx.x;
  int v = bin[t];
  sh[t] = v;
  __syncthreads();
  for (int off = 1; off < 256; off <<= 1) {
    int u = (t >= off) ? sh[t - off] : 0;
    __syncthreads();
    sh[t] += u;
    __syncthreads();
  }
  bin[t] = sh[t] - v;   // exclusive prefix
}

__global__ __launch_bounds__(256) void dscat_k(
    const int* __restrict__ cptr, const int* __restrict__ rptr,
    int* __restrict__ binc, int* __restrict__ binr,
    int* __restrict__ permc, int* __restrict__ permr)
{
  __shared__ int lhc[256], lhr[256], lbc[256], lbr[256];
  int t = threadIdx.x;
  lhc[t] = 0; lhr[t] = 0;
  __syncthreads();
  int a = blockIdx.x * 256 + t;
  int bc = 0, br = 0, rc = 0, rr = 0;
  bool valid = a < N_ATOMS;
  if (valid) {
    int dc = cptr[a+1] - cptr[a];
    int dr = rptr[a+1] - rptr[a];
    bc = 255 - min(dc, 255);
    br = 255 - min(dr, 255);
    rc = atomicAdd(&lhc[bc], 1);   // local rank within block+bin
    rr = atomicAdd(&lhr[br], 1);
  }
  __syncthreads();
  if (lhc[t] > 0) lbc[t] = atomicAdd(&binc[t], lhc[t]);  // reserve range
  if (lhr[t] > 0) lbr[t] = atomicAdd(&binr[t], lhr[t]);
  __syncthreads();
  if (valid) {
    permc[lbc[bc] + rc] = a;
    permr[lbr[br] + rr] = a;
  }
}

// ------------------------------------------------------------------
// table build
// ------------------------------------------------------------------
__global__ __launch_bounds__(256) void nodeA_k(
    float* __restrict__ A, float* __restrict__ dA, int nnode, float hstep)
{
  int i = blockIdx.x * 256 + threadIdx.x;
  if (i >= nnode * HD) return;
  int node = i >> 7, g = i & 127;
  float d = (float)node * hstep;
  float t = d - (float)g * DELTA;
  float a = expf(GCOEFF * t * t);
  A[i] = a;
  dA[i] = a * 2.0f * GCOEFF * t;
}

__global__ __launch_bounds__(256) void nodeact_k(
    const float* __restrict__ t1, const float* __restrict__ u,
    float* __restrict__ s, float* __restrict__ sp, int total)
{
  int i = blockIdx.x * 256 + threadIdx.x;
  if (i >= total) return;
  float x = t1[i];
  s[i] = sspf(x);
  sp[i] = sigmf(x) * u[i];
}

__global__ __launch_bounds__(256) void nodecomb_k(
    const float* __restrict__ P0, const float* __restrict__ D0,
    unsigned* __restrict__ T, int nnode, float hstep)
{
  int i = blockIdx.x * 256 + threadIdx.x;
  int total = NLAY * nnode * HD;
  if (i >= total) return;
  int rem = i % (nnode * HD);
  int node = rem >> 7;
  float d = (float)node * hstep;
  float C  = 0.5f * cosf(d * (PI_F / FCUT)) + 0.5f;
  float Cp = -0.5f * sinf(d * (PI_F / FCUT)) * (PI_F / FCUT);
  float p = P0[i], q = D0[i];
  T[i] = bfpack(p * C, q * C + p * Cp);
}

// ------------------------------------------------------------------
// no-LDS MFMA wave GEMM: wave computes rows [m0,m0+16) x cols
// [wbase,wbase+32) of C = A[M,128] @ B[128,128].
// Bt layout: Bt[n*HD + k] = B[k][n] (bf16).
// ------------------------------------------------------------------
__device__ __forceinline__ void wave_mm(
    const float* __restrict__ Av, const u16* __restrict__ Bt,
    int m0, int wbase, int lc, int lg, int mclamp, f32x4 acc[2])
{
  short8v bfr[4][2];
#pragma unroll
  for (int ks = 0; ks < 4; ++ks)
#pragma unroll
    for (int nt = 0; nt < 2; ++nt)
      bfr[ks][nt] = *(const short8v*)(Bt + (size_t)(wbase + nt*16 + lc) * HD + ks*32 + lg*8);
  int ar = m0 + lc;
  if (ar > mclamp) ar = mclamp;   // row-clamped load; garbage rows never stored
  f32x4 z = {0.f, 0.f, 0.f, 0.f};
  acc[0] = z; acc[1] = z;
#pragma unroll
  for (int ks = 0; ks < 4; ++ks) {
    const float* p = Av + (size_t)ar * HD + ks*32 + lg*8;
    uint4 u0 = *(const uint4*)p;
    uint4 u1 = *(const uint4*)(p + 4);
    unsigned p0l, p1l, p2l, p3l;
    unsigned p0h = hpair_f32(u0.x, u0.y, p0l);
    unsigned p1h = hpair_f32(u0.z, u0.w, p1l);
    unsigned p2h = hpair_f32(u1.x, u1.y, p2l);
    unsigned p3h = hpair_f32(u1.z, u1.w, p3l);
    uint4 hv = make_uint4(p0h, p1h, p2h, p3h);
    uint4 lv = make_uint4(p0l, p1l, p2l, p3l);
    short8v ah = *(short8v*)&hv, al = *(short8v*)&lv;
    acc[0] = __builtin_amdgcn_mfma_f32_16x16x32_bf16(ah, bfr[ks][0], acc[0], 0, 0, 0);
    acc[1] = __builtin_amdgcn_mfma_f32_16x16x32_bf16(ah, bfr[ks][1], acc[1], 0, 0, 0);
    acc[0] = __builtin_amdgcn_mfma_f32_16x16x32_bf16(al, bfr[ks][0], acc[0], 0, 0, 0);
    acc[1] = __builtin_amdgcn_mfma_f32_16x16x32_bf16(al, bfr[ks][1], acc[1], 0, 0, 0);
  }
}

// same, A from LDS tile of packed (hi16|lo16) u32, rows [16][132]
__device__ __forceinline__ void wave_mm_lds(
    const unsigned (*__restrict__ Sl)[132], const u16* __restrict__ Bt,
    int wbase, int lc, int lg, f32x4 acc[2])
{
  short8v bfr[4][2];
#pragma unroll
  for (int ks = 0; ks < 4; ++ks)
#pragma unroll
    for (int nt = 0; nt < 2; ++nt)
      bfr[ks][nt] = *(const short8v*)(Bt + (size_t)(wbase + nt*16 + lc) * HD + ks*32 + lg*8);
  f32x4 z = {0.f, 0.f, 0.f, 0.f};
  acc[0] = z; acc[1] = z;
#pragma unroll
  for (int ks = 0; ks < 4; ++ks) {
    uint4 u0 = *(const uint4*)&Sl[lc][ks*32 + lg*8];
    uint4 u1 = *(const uint4*)&Sl[lc][ks*32 + lg*8 + 4];
    uint4 hv = make_uint4(
      (u0.y & 0xffff0000u) | (u0.x >> 16),
      (u0.w & 0xffff0000u) | (u0.z >> 16),
      (u1.y & 0xffff0000u) | (u1.x >> 16),
      (u1.w & 0xffff0000u) | (u1.z >> 16));
    uint4 lv = make_uint4(
      (u0.y << 16) | (u0.x & 0xffffu),
      (u0.w << 16) | (u0.z & 0xffffu),
      (u1.y << 16) | (u1.x & 0xffffu),
      (u1.w << 16) | (u1.z & 0xffffu));
    short8v ah = *(short8v*)&hv, al = *(short8v*)&lv;
    acc[0] = __builtin_amdgcn_mfma_f32_16x16x32_bf16(ah, bfr[ks][0], acc[0], 0, 0, 0);
    acc[1] = __builtin_amdgcn_mfma_f32_16x16x32_bf16(ah, bfr[ks][1], acc[1], 0, 0, 0);
    acc[0] = __builtin_amdgcn_mfma_f32_16x16x32_bf16(al, bfr[ks][0], acc[0], 0, 0, 0);
    acc[1] = __builtin_amdgcn_mfma_f32_16x16x32_bf16(al, bfr[ks][1], acc[1], 0, 0, 0);
  }
}

// hx = h @ W  (Bt = W^T bf16), output u16 bf16  (layer 0 only)
__global__ __launch_bounds__(256) void nmm_hx_k(
    const float* __restrict__ h, const u16* __restrict__ Bt,
    u16* __restrict__ hx, int M)
{
  int t = threadIdx.x, lane = t & 63;
  int lc = lane & 15, lg = lane >> 4;
  int wbase = (t >> 6) * 32;
  int m0 = blockIdx.x * 16;
  f32x4 acc[2];
  wave_mm(h, Bt, m0, wbase, lc, lg, M - 1, acc);
#pragma unroll
  for (int nt = 0; nt < 2; ++nt) {
    int ccol = wbase + nt*16 + lc;
#pragma unroll
    for (int j = 0; j < 4; ++j) {
      int grow = m0 + lg*4 + j;
      if (grow < M) hx[(size_t)grow * HD + ccol] = f2bf(acc[nt][j]);
    }
  }
}

// fused fwd tail: V = agg@l2 + l2b; svb = bf16(sigm(V));
// hout = h + ssp(V)@bw + bb; optional hxn = bf16(hout @ l1next)
__global__ __launch_bounds__(256) void ftail_f_k(
    const float* __restrict__ agg, const u16* __restrict__ l2t,
    const float* __restrict__ l2b, const u16* __restrict__ bwt,
    const float* __restrict__ bb, const float* __restrict__ h,
    u16* __restrict__ svb, float* __restrict__ hout,
    const u16* __restrict__ l1n, u16* __restrict__ hxn, int M)
{
  __shared__ unsigned Sl[16][132];
  int t = threadIdx.x, lane = t & 63;
  int lc = lane & 15, lg = lane >> 4;
  int wbase = (t >> 6) * 32;
  int m0 = blockIdx.x * 16;
  f32x4 acc[2];
  wave_mm(agg, l2t, m0, wbase, lc, lg, M - 1, acc);
#pragma unroll
  for (int nt = 0; nt < 2; ++nt) {
    int ccol = wbase + nt*16 + lc;
    float bv = l2b[ccol];
#pragma unroll
    for (int j = 0; j < 4; ++j) {
      int lrow = lg*4 + j;
      int grow = m0 + lrow;
      float s = 0.0f;
      if (grow < M) {
        float x = acc[nt][j] + bv;
        svb[(size_t)grow * HD + ccol] = f2bf(sigmf(x));
        s = sspf(x);
      }
      Sl[lrow][ccol] = packhl(s);
    }
  }
  __syncthreads();
  wave_mm_lds(Sl, bwt, wbase, lc, lg, acc);

  float ho[2][4];
#pragma unroll
  for (int nt = 0; nt < 2; ++nt) {
    int ccol = wbase + nt*16 + lc;
    float bv = bb[ccol];
#pragma unroll
    for (int j = 0; j < 4; ++j) {
      int grow = m0 + lg*4 + j;
      float x = 0.0f;
      if (grow < M) {
        x = acc[nt][j] + bv + h[(size_t)grow * HD + ccol];
        hout[(size_t)grow * HD + ccol] = x;
      }
      ho[nt][j] = x;
    }
  }
  if (l1n) {
    __syncthreads();   // all waves done reading Sl (bw pass)
#pragma unroll
    for (int nt = 0; nt < 2; ++nt) {
      int ccol = wbase + nt*16 + lc;
#pragma unroll
      for (int j = 0; j < 4; ++j)
        Sl[lg*4 + j][ccol] = packhl(ho[nt][j]);
    }
    __syncthreads();
    wave_mm_lds(Sl, l1n, wbase, lc, lg, acc);
#pragma unroll
    for (int nt = 0; nt < 2; ++nt) {
      int ccol = wbase + nt*16 + lc;
#pragma unroll
      for (int j = 0; j < 4; ++j) {
        int grow = m0 + lg*4 + j;
        if (grow < M) hxn[(size_t)grow * HD + ccol] = f2bf(acc[nt][j]);
      }
    }
  }
}

// fused bwd head, optionally with the previous layer's bwdT GEMM folded in:
//  if aggprev: g = aggprev@l1prev^T + gadd  (store to gout if non-null)
//  else:       g = gdirect
//  dv = (g@bw^T)*sigm(V) (from svb); dagg = dv@l2^T (bf16 out)
__global__ __launch_bounds__(256) void bhead2_f_k(
    const float* __restrict__ aggprev, const u16* __restrict__ l1prev,
    const float* __restrict__ gadd, const float* __restrict__ gdirect,
    const u16* __restrict__ bwp, const u16* __restrict__ svb,
    const u16* __restrict__ l2p, u16* __restrict__ dagg,
    float* __restrict__ gout, int M)
{
  __shared__ unsigned Sl[16][132];
  int t = threadIdx.x, lane = t & 63;
  int lc = lane & 15, lg = lane >> 4;
  int wbase = (t >> 6) * 32;
  int m0 = blockIdx.x * 16;
  f32x4 acc[2];
  if (aggprev) {
    wave_mm(aggprev, l1prev, m0, wbase, lc, lg, M - 1, acc);
#pragma unroll
    for (int nt = 0; nt < 2; ++nt) {
      int ccol = wbase + nt*16 + lc;
#pragma unroll
      for (int j = 0; j < 4; ++j) {
        int lrow = lg*4 + j;
        int grow = m0 + lrow;
        float x = 0.0f;
        if (grow < M) {
          x = acc[nt][j] + gadd[(size_t)grow * HD + ccol];
          if (gout) gout[(size_t)grow * HD + ccol] = x;
        }
        Sl[lrow][ccol] = packhl(x);
      }
    }
    __syncthreads();
    wave_mm_lds(Sl, bwp, wbase, lc, lg, acc);
    __syncthreads();   // all waves done reading g before dv overwrites Sl
  } else {
    wave_mm(gdirect, bwp, m0, wbase, lc, lg, M - 1, acc);
  }
  // dv = acc * sigm(V), pack into Sl
#pragma unroll
  for (int nt = 0; nt < 2; ++nt) {
    int ccol = wbase + nt*16 + lc;
#pragma unroll
    for (int j = 0; j < 4; ++j) {
      int lrow = lg*4 + j;
      int grow = m0 + lrow;
      float dv = 0.0f;
      if (grow < M)
        dv = acc[nt][j] * bf2f(svb[(size_t)grow * HD + ccol]);
      Sl[lrow][ccol] = packhl(dv);
    }
  }
  __syncthreads();
  wave_mm_lds(Sl, l2p, wbase, lc, lg, acc);
#pragma unroll
  for (int nt = 0; nt < 2; ++nt) {
    int ccol = wbase + nt*16 + lc;
#pragma unroll
    for (int j = 0; j < 4; ++j) {
      int grow = m0 + lg*4 + j;
      if (grow < M) dagg[(size_t)grow * HD + ccol] = f2bf(acc[nt][j]);
    }
  }
}

// batched table-build GEMM; blockIdx.z selects (A0,bias0,C0) or (A1,null,C1)
__global__ __launch_bounds__(256) void tblmm2_k(
    const float* __restrict__ A0, const float* __restrict__ A1, size_t astride,
    const u16* __restrict__ Bt, size_t bstride,
    const float* __restrict__ bias0, size_t biasstride,
    float* __restrict__ C0, float* __restrict__ C1, size_t cstride, int M)
{
  int l = blockIdx.y;
  int zz = blockIdx.z;
  const float* A = (zz ? A1 : A0) + (size_t)l * astride;
  const u16* B = Bt + (size_t)l * bstride;
  const float* bias = zz ? nullptr : (bias0 ? bias0 + (size_t)l * biasstride : nullptr);
  float* C = (zz ? C1 : C0) + (size_t)l * cstride;
  int t = threadIdx.x, lane = t & 63;
  int lc = lane & 15, lg = lane >> 4;
  int wbase = (t >> 6) * 32;
  int m0 = blockIdx.x * 16;
  f32x4 acc[2];
  wave_mm(A, B, m0, wbase, lc, lg, M - 1, acc);
#pragma unroll
  for (int nt = 0; nt < 2; ++nt) {
    int ccol = wbase + nt*16 + lc;
    float bv = bias ? bias[ccol] : 0.0f;
#pragma unroll
    for (int j = 0; j < 4; ++j) {
      int grow = m0 + lg*4 + j;
      if (grow < M) C[(size_t)grow * HD + ccol] = acc[nt][j] + bv;
    }
  }
}

// ------------------------------------------------------------------
// forward gather: agg[a] = sum_in hx[src] * P(d).
// One wave per atom; 4 groups of 16 lanes, each group owns every 4th
// edge; each lane covers 8 channels -> 4 independent edge streams.
// ------------------------------------------------------------------
__global__ __launch_bounds__(256) void gath_fwd_k(
    const int* __restrict__ perm, const int* __restrict__ cptr,
    const uint2* __restrict__ cpk2, const unsigned* __restrict__ T,
    const unsigned* __restrict__ hx, float* __restrict__ agg, float hstep)
{
  int ai = blockIdx.x * 4 + (threadIdx.x >> 6);
  if (ai >= N_ATOMS) return;
  int a = perm[ai];
  int lane = threadIdx.x & 63;
  int grp = lane >> 4;
  int l16 = lane & 15;
  int ch = l16 * 8;
  int beg = cptr[a], end = cptr[a + 1];
  float s[8];
#pragma unroll
  for (int c = 0; c < 8; c++) s[c] = 0.f;
  for (int j = beg + grp; j < end; j += 4) {
    uint2 pk2 = cpk2[j];
    float t = __uint_as_float(pk2.y);
    int other = pk2.x & 0xffffu;
    float t2 = t * t, t3 = t2 * t;
    float cx = 2.f*t3 - 3.f*t2 + 1.f;
    float cy = (t3 - 2.f*t2 + t) * hstep;
    float cz = 3.f*t2 - 2.f*t3;
    float cw = (t3 - t2) * hstep;
    const unsigned* tp = T + (size_t)(pk2.x >> 16) * HD + ch;
    uint4 q0a = *(const uint4*)(tp);
    uint4 q0b = *(const uint4*)(tp + 4);
    uint4 q1a = *(const uint4*)(tp + HD);
    uint4 q1b = *(const uint4*)(tp + HD + 4);
    uint4 hp = *(const uint4*)(hx + (size_t)other * 64 + l16 * 4);
    unsigned q0[8] = {q0a.x, q0a.y, q0a.z, q0a.w, q0b.x, q0b.y, q0b.z, q0b.w};
    unsigned q1[8] = {q1a.x, q1a.y, q1a.z, q1a.w, q1b.x, q1b.y, q1b.z, q1b.w};
    unsigned hh[4] = {hp.x, hp.y, hp.z, hp.w};
#pragma unroll
    for (int c = 0; c < 8; c++) {
      float v = cx*bflo(q0[c]) + cy*bfhi(q0[c]) + cz*bflo(q1[c]) + cw*bfhi(q1[c]);
      float hv = (c & 1) ? bfhi(hh[c >> 1]) : bflo(hh[c >> 1]);
      s[c] = fmaf(hv, v, s[c]);
    }
  }
#pragma unroll
  for (int c = 0; c < 8; c++) {
    s[c] += __shfl_xor(s[c], 16, 64);
    s[c] += __shfl_xor(s[c], 32, 64);
  }
  if (grp == 0) {
    *(float4*)(agg + (size_t)a * HD + ch)     = make_float4(s[0], s[1], s[2], s[3]);
    *(float4*)(agg + (size_t)a * HD + ch + 4) = make_float4(s[4], s[5], s[6], s[7]);
  }
}

// ------------------------------------------------------------------
// backward gather: ddslot (write on first layer, else +=);
// dhx only when need_dhx. Same 4x16-lane group structure.
// ------------------------------------------------------------------
__global__ __launch_bounds__(256) void gath_bwd_k(
    const int* __restrict__ perm, const int* __restrict__ rptr,
    const uint2* __restrict__ rpk2, const unsigned* __restrict__ T,
    const unsigned* __restrict__ dagg, const unsigned* __restrict__ hx,
    float* __restrict__ dhx, float* __restrict__ ddslot, int accum,
    int need_dhx, float hstep, float inv_h)
{
  int ai = blockIdx.x * 4 + (threadIdx.x >> 6);
  if (ai >= N_ATOMS) return;
  int a = perm[ai];
  int lane = threadIdx.x & 63;
  int grp = lane >> 4;
  int l16 = lane & 15;
  int ch = l16 * 8;
  int beg = rptr[a], end = rptr[a + 1];
  uint4 hp = *(const uint4*)(hx + (size_t)a * 64 + l16 * 4);
  unsigned hhw[4] = {hp.x, hp.y, hp.z, hp.w};
  float hv[8];
#pragma unroll
  for (int c = 0; c < 8; c++)
    hv[c] = (c & 1) ? bfhi(hhw[c >> 1]) : bflo(hhw[c >> 1]);
  float s[8];
#pragma unroll
  for (int c = 0; c < 8; c++) s[c] = 0.f;
  for (int j = beg + grp; j < end; j += 4) {
    uint2 pk2 = rpk2[j];
    float t = __uint_as_float(pk2.y);
    int other = pk2.x & 0xffffu;
    float t2 = t * t, t3 = t2 * t;
    float cbx = (6.f*t2 - 6.f*t) * inv_h;
    float cby = 3.f*t2 - 4.f*t + 1.f;
    float cbz = -cbx;
    float cbw = 3.f*t2 - 2.f*t;
    const unsigned* tp = T + (size_t)(pk2.x >> 16) * HD + ch;
    uint4 q0a = *(const uint4*)(tp);
    uint4 q0b = *(const uint4*)(tp + 4);
    uint4 q1a = *(const uint4*)(tp + HD);
    uint4 q1b = *(const uint4*)(tp + HD + 4);
    uint4 dp = *(const uint4*)(dagg + (size_t)other * 64 + l16 * 4);
    unsigned q0[8] = {q0a.x, q0a.y, q0a.z, q0a.w, q0b.x, q0b.y, q0b.z, q0b.w};
    unsigned q1[8] = {q1a.x, q1a.y, q1a.z, q1a.w, q1b.x, q1b.y, q1b.z, q1b.w};
    unsigned dw[4] = {dp.x, dp.y, dp.z, dp.w};
    float dot = 0.f;
#pragma unroll
    for (int c = 0; c < 8; c++) {
      float da = (c & 1) ? bfhi(dw[c >> 1]) : bflo(dw[c >> 1]);
      float g = cbx*bflo(q0[c]) + cby*bfhi(q0[c]) + cbz*bflo(q1[c]) + cbw*bfhi(q1[c]);
      dot = fmaf(da * hv[c], g, dot);
      if (need_dhx) {
        float cax = 2.f*t3 - 3.f*t2 + 1.f;
        float cay = (t3 - 2.f*t2 + t) * hstep;
        float caz = 3.f*t2 - 2.f*t3;
        float caw = (t3 - t2) * hstep;
        float v = cax*bflo(q0[c]) + cay*bfhi(q0[c]) + caz*bflo(q1[c]) + caw*bfhi(q1[c]);
        s[c] = fmaf(da, v, s[c]);
      }
    }
#pragma unroll
    for (int off = 8; off > 0; off >>= 1) dot += __shfl_down(dot, off, 16);
    if (l16 == 0) ddslot[j] = accum ? (ddslot[j] + dot) : dot;
  }
  if (need_dhx) {
#pragma unroll
    for (int c = 0; c < 8; c++) {
      s[c] += __shfl_xor(s[c], 16, 64);
      s[c] += __shfl_xor(s[c], 32, 64);
    }
    if (grp == 0) {
      *(float4*)(dhx + (size_t)a * HD + ch)     = make_float4(s[0], s[1], s[2], s[3]);
      *(float4*)(dhx + (size_t)a * HD + ch + 4) = make_float4(s[4], s[5], s[6], s[7]);
    }
  }
}

// ------------------------------------------------------------------
// fused head: s = h4@hw1 + hb1; ea[a] = ssp(s)@hw2 + hb2;
// gh = (sigm(s)*hw2) @ hw1^T
// ------------------------------------------------------------------
__global__ __launch_bounds__(256) void headf_k(
    const float* __restrict__ h4, const float* __restrict__ hw1,
    const float* __restrict__ hb1, const float* __restrict__ hw2,
    const float* __restrict__ hb2, float* __restrict__ ea,
    float* __restrict__ gh)
{
  __shared__ float As[16][68];
  __shared__ float Bs[16][132];
  __shared__ float Ss[64][68];
  __shared__ float red[64][17];
  int t = threadIdx.x;
  int tx = t & 15, ty = t >> 4;
  int m0 = blockIdx.x * 64;

  float acc4[4][4];
#pragma unroll
  for (int r = 0; r < 4; r++)
#pragma unroll
    for (int c = 0; c < 4; c++) acc4[r][c] = 0.0f;

  for (int k0 = 0; k0 < HD; k0 += 16) {
    {
      int rrow = t >> 2;
      int kg = (t & 3) * 4;
      int gm = m0 + rrow;
      float4 av = make_float4(0.f, 0.f, 0.f, 0.f);
      if (gm < N_ATOMS) av = *(const float4*)(h4 + (size_t)gm * HD + k0 + kg);
      As[kg+0][rrow] = av.x; As[kg+1][rrow] = av.y;
      As[kg+2][rrow] = av.z; As[kg+3][rrow] = av.w;
    }
    if (t < 256) {
      int kk = t >> 4;
      int n4 = (t & 15) * 4;
      float4 bv = *(const float4*)(hw1 + (size_t)(k0 + kk) * 64 + n4);
      *(float4*)&Bs[kk][n4] = bv;
    }
    __syncthreads();
#pragma unroll
    for (int kk = 0; kk < 16; kk++) {
      float a[4], b[4];
#pragma unroll
      for (int r = 0; r < 4; r++) a[r] = As[kk][ty * 4 + r];
#pragma unroll
      for (int c = 0; c < 4; c++) b[c] = Bs[kk][tx * 4 + c];
#pragma unroll
      for (int r = 0; r < 4; r++)
#pragma unroll
        for (int c = 0; c < 4; c++) acc4[r][c] = fmaf(a[r], b[c], acc4[r][c]);
    }
    __syncthreads();
  }

  {
    int n0 = tx * 4;
    float b1v[4], w2v[4];
#pragma unroll
    for (int c = 0; c < 4; c++) { b1v[c] = hb1[n0 + c]; w2v[c] = hw2[n0 + c]; }
#pragma unroll
    for (int r = 0; r < 4; r++) {
      int lr = ty * 4 + r;
      float p = 0.0f;
#pragma unroll
      for (int c = 0; c < 4; c++) {
        float x = acc4[r][c] + b1v[c];
        p += sspf(x) * w2v[c];
        Ss[lr][n0 + c] = sigmf(x) * w2v[c];
      }
      red[lr][tx] = p;
    }
  }
  __syncthreads();
  if (t < 64) {
    int gm = m0 + t;
    if (gm < N_ATOMS) {
      float s = hb2[0];
#pragma unroll
      for (int j = 0; j < 16; j++) s += red[t][j];
      ea[gm] = s;
    }
  }

  float acc[4][8];
#pragma unroll
  for (int r = 0; r < 4; r++)
#pragma unroll
    for (int c = 0; c < 8; c++) acc[r][c] = 0.0f;

  for (int j0 = 0; j0 < 64; j0 += 16) {
#pragma unroll
    for (int it = 0; it < 2; it++) {
      int idx = t + it * 256;
      int n = idx >> 2;
      int jg = (idx & 3) * 4;
      float4 bv = *(const float4*)(hw1 + (size_t)n * 64 + j0 + jg);
      Bs[jg+0][n] = bv.x; Bs[jg+1][n] = bv.y;
      Bs[jg+2][n] = bv.z; Bs[jg+3][n] = bv.w;
    }
    __syncthreads();
#pragma unroll
    for (int kk = 0; kk < 16; kk++) {
      float a[4], b[8];
#pragma unroll
      for (int r = 0; r < 4; r++) a[r] = Ss[ty * 4 + r][j0 + kk];
#pragma unroll
      for (int c = 0; c < 8; c++) b[c] = Bs[kk][tx * 8 + c];
#pragma unroll
      for (int r = 0; r < 4; r++)
#pragma unroll
        for (int c = 0; c < 8; c++) acc[r][c] = fmaf(a[r], b[c], acc[r][c]);
    }
    __syncthreads();
  }

  int n0 = tx * 8;
#pragma unroll
  for (int r = 0; r < 4; r++) {
    int gm = m0 + ty * 4 + r;
    if (gm >= N_ATOMS) continue;
    *(float4*)(gh + (size_t)gm * HD + n0)     = *(float4*)&acc[r][0];
    *(float4*)(gh + (size_t)gm * HD + n0 + 4) = *(float4*)&acc[r][4];
  }
}

// ------------------------------------------------------------------
// per-molecule energy reduction
// ------------------------------------------------------------------
__global__ __launch_bounds__(64) void ered_k(
    const int* __restrict__ batch, const float* __restrict__ ea,
    float* __restrict__ energy)
{
  int m = blockIdx.x;
  int lo = 0, hi = N_ATOMS;
  while (lo < hi) { int mid = (lo + hi) >> 1; if (batch[mid] < m) lo = mid + 1; else hi = mid; }
  int beg = lo;
  lo = beg; hi = N_ATOMS;
  while (lo < hi) { int mid = (lo + hi) >> 1; if (batch[mid] < m + 1) lo = mid + 1; else hi = mid; }
  int end = lo;
  float s = 0.0f;
  for (int i = beg + threadIdx.x; i < end; i += 64) s += ea[i];
#pragma unroll
  for (int off = 32; off > 0; off >>= 1) s += __shfl_down(s, off, 64);
  if (threadIdx.x == 0) energy[m] = s;
}

// ------------------------------------------------------------------
// force gather; distance reconstructed from pk2: d = (i0 + t) * hstep
// ------------------------------------------------------------------
__global__ __launch_bounds__(256) void forceg_k(
    const int* __restrict__ rptr, const uint2* __restrict__ rpk2,
    const int* __restrict__ cptr, const uint2* __restrict__ cpk2,
    const int* __restrict__ cslot, const float* __restrict__ ddslot,
    const float* __restrict__ pos, float* __restrict__ force, float hstep)
{
  int idx = blockIdx.x * 256 + threadIdx.x;
  int a = idx >> 3;
  int g = idx & 7;
  if (a >= N_ATOMS) return;
  float px = pos[3*a+0], py = pos[3*a+1], pz = pos[3*a+2];
  float fx = 0.f, fy = 0.f, fz = 0.f;
  int beg = rptr[a], end = rptr[a+1];
  for (int j = beg + g; j < end; j += 8) {
    uint2 p = rpk2[j];
    int o = p.x & 0xffffu;
    float d = ((float)(p.x >> 16) + __uint_as_float(p.y)) * hstep;
    float w = ddslot[j] / d;
    fx -= w * (px - pos[3*o+0]);
    fy -= w * (py - pos[3*o+1]);
    fz -= w * (pz - pos[3*o+2]);
  }
  beg = cptr[a]; end = cptr[a+1];
  for (int j = beg + g; j < end; j += 8) {
    uint2 p = cpk2[j];
    int o = p.x & 0xffffu;
    float d = ((float)(p.x >> 16) + __uint_as_float(p.y)) * hstep;
    float w = ddslot[cslot[j]] / d;
    fx -= w * (px - pos[3*o+0]);
    fy -= w * (py - pos[3*o+1]);
    fz -= w * (pz - pos[3*o+2]);
  }
#pragma unroll
  for (int off = 4; off > 0; off >>= 1) {
    fx += __shfl_down(fx, off, 8);
    fy += __shfl_down(fy, off, 8);
    fz += __shfl_down(fz, off, 8);
  }
  if (g == 0) {
    force[3*a+0] = fx;
    force[3*a+1] = fy;
    force[3*a+2] = fz;
  }
}

// ------------------------------------------------------------------
// host launch
// ------------------------------------------------------------------
static inline int nblk(int m) { return (m + 63) / 64; }

extern "C" void kernel_launch(void* const* d_in, const int* in_sizes, int n_in,
                              void* d_out, int out_size, void* d_ws, size_t ws_size,
                              hipStream_t stream)
{
  const float* pos   = (const float*)d_in[0];
  const int*   z     = (const int*)d_in[1];
  const int*   batch = (const int*)d_in[2];
  const int*   eidx  = (const int*)d_in[3];
  const float* emb   = (const float*)d_in[4];
  const float* mlp_w1 = (const float*)d_in[5];
  const float* mlp_b1 = (const float*)d_in[6];
  const float* mlp_w2 = (const float*)d_in[7];
  const float* mlp_b2 = (const float*)d_in[8];
  const float* lin1_w = (const float*)d_in[9];
  const float* lin2_w = (const float*)d_in[10];
  const float* lin2_b = (const float*)d_in[11];
  const float* blk_w  = (const float*)d_in[12];
  const float* blk_b  = (const float*)d_in[13];
  const float* hw1 = (const float*)d_in[14];
  const float* hb1 = (const float*)d_in[15];
  const float* hw2 = (const float*)d_in[16];
  const float* hb2 = (const float*)d_in[17];

  float* out = (float*)d_out;          // [NMOL] energies ++ [N,3] forces
  float* ws  = (float*)d_ws;

  const int* row = eidx;
  const int* col = eidx + N_EDGES;

  const size_t NH = (size_t)N_ATOMS * HD;
  size_t o = 0;
  float* ddslot = ws + o; o += N_EDGES;
  int* cptr = (int*)(ws + o); o += N_ATOMS + 1;
  int* rptr = (int*)(ws + o); o += N_ATOMS + 1;
  int* cnt0 = (int*)(ws + o); o += N_ATOMS;      // cnt0,cnt1 contiguous:
  int* cnt1 = (int*)(ws + o); o += N_ATOMS;      // one memset
  int* binc = (int*)(ws + o); o += 256;
  int* binr = (int*)(ws + o); o += 256;
  int* cur0 = (int*)(ws + o); o += N_ATOMS;
  int* cur1 = (int*)(ws + o); o += N_ATOMS;
  int* permc = (int*)(ws + o); o += N_ATOMS;
  int* permr = (int*)(ws + o); o += N_ATOMS;
  int* cslot = (int*)(ws + o); o += N_EDGES;
  o = (o + 1) & ~(size_t)1;                      // 8B align for uint2
  uint2* cpk2 = (uint2*)(ws + o); o += (size_t)2 * N_EDGES;
  uint2* rpk2 = (uint2*)(ws + o); o += (size_t)2 * N_EDGES;
  // bf16 weights: wt = transposed, wp = plain, mt = transposed mlp weights
  u16* wt = (u16*)(ws + o); o += (size_t)NLAY * 3 * HD * HD / 2;
  u16* wp = (u16*)(ws + o); o += (size_t)NLAY * 3 * HD * HD / 2;
  u16* mt = (u16*)(ws + o); o += (size_t)NLAY * 2 * HD * HD / 2;
  float* hxb[4];   // bf16 (128 u16 per row) -> NH/2 floats each
  for (int i = 0; i < 4; i++) { hxb[i] = ws + o; o += NH / 2; }
  float* svb[4];   // bf16 sigm(V) -> NH/2 floats each
  for (int i = 0; i < 4; i++) { svb[i] = ws + o; o += NH / 2; }
  float* hA  = ws + o; o += NH;
  float* hB  = ws + o; o += NH;
  float* agg = ws + o; o += NH;       // fwd agg / bwd dhx / table temps
  float* g0b = ws + o; o += NH;
  float* g1b = ws + o; o += NH;
  float* dgb = ws + o; o += NH / 2;   // dagg(bf16) / ea / table temps

  // table: bf16 pairs {P*C, (P*C)'}, 1 uint per (node,ch)
  int NT = 1024;
  while (NT > 128) {
    size_t need = o + (size_t)NLAY * (NT + 1) * HD;
    if (need * sizeof(float) <= ws_size) break;
    NT >>= 1;
  }
  const int NN = NT + 1;
  const float hstep = FCUT / (float)NT;
  const float inv_h = (float)NT / FCUT;
  unsigned* T = (unsigned*)(ws + o); o += (size_t)NLAY * NN * HD;

  const int EB = (N_EDGES + 255) / 256;
  const int ABK = (N_ATOMS + 255) / 256;

  hipMemsetAsync(cnt0, 0, 2 * N_ATOMS * sizeof(int), stream);

  wprep_k<<<(NLAY * 5 * HD * HD + 255) / 256, 256, 0, stream>>>(
      lin1_w, lin2_w, blk_w, mlp_w1, mlp_w2, wt, wp, mt);

  // ---------------- CSR build (both directions) ----------------
  histboth_k<<<EB, 256, 0, stream>>>(row, col, cnt1, cnt0);
  scan2_k<<<2, 256, 0, stream>>>(cnt0, cnt1, cptr, rptr, cur0, cur1, binc, binr);
  scatboth_k<<<EB, 256, 0, stream>>>(pos, row, col, cur0, cur1, cpk2, rpk2,
                                     cslot, inv_h);

  // ---------------- degree-sort perms for gather balance ----------------
  dscan_k<<<2, 256, 0, stream>>>(binc, binr);
  dscat_k<<<ABK, 256, 0, stream>>>(cptr, rptr, binc, binr, permc, permr);

  // ---------------- build filter tables (all 4 layers) ----------------
  {
    const size_t LNH = (size_t)NN * HD;
    float* Anode  = agg;
    float* dAnode = agg + LNH;
    float* t1 = dgb;
    float* u  = g0b;
    float* s  = g1b;
    float* sp = hA;
    nodeA_k<<<((int)LNH + 255) / 256, 256, 0, stream>>>(Anode, dAnode, NN, hstep);
    dim3 gB16((NN + 15) / 16, NLAY, 2);
    tblmm2_k<<<gB16, 256, 0, stream>>>(Anode, dAnode, 0, mt, 32768,
                                       mlp_b1, HD, t1, u, LNH, NN);
    int tot = (int)(NLAY * LNH);
    nodeact_k<<<(tot + 255) / 256, 256, 0, stream>>>(t1, u, s, sp, tot);
    float* P0 = dgb;
    float* D0 = g0b;
    tblmm2_k<<<gB16, 256, 0, stream>>>(s, sp, LNH, mt + 16384, 32768,
                                       mlp_b2, HD, P0, D0, LNH, NN);
    nodecomb_k<<<(tot + 255) / 256, 256, 0, stream>>>(P0, D0, T, NN, hstep);
  }

  h0_k<<<(N_ATOMS * HD + 255) / 256, 256, 0, stream>>>(emb, z, hA);

  const int AB = (N_ATOMS + 3) / 4;
  const int GB = nblk(N_ATOMS);
  const int NB16 = (N_ATOMS + 15) / 16;   // 1250 blocks for no-LDS MFMA GEMMs

  // ---------------- forward ----------------
  float* hcur = hA;
  float* hnxt = hB;
  nmm_hx_k<<<NB16, 256, 0, stream>>>(hcur, wt, (u16*)hxb[0], N_ATOMS);
  for (int i = 0; i < NLAY; i++) {
    const u16* l2t = wt + ((size_t)(i*3 + 1) << 14);
    const u16* bwt = wt + ((size_t)(i*3 + 2) << 14);
    const u16* l1n = (i < NLAY - 1) ? wt + ((size_t)((i+1)*3 + 0) << 14) : nullptr;
    u16* hxn = (i < NLAY - 1) ? (u16*)hxb[i+1] : nullptr;
    const float* l2bi = lin2_b + (size_t)i * HD;
    const float* bbi  = blk_b + (size_t)i * HD;
    const unsigned* Tl = T + (size_t)i * NN * HD;

    gath_fwd_k<<<AB, 256, 0, stream>>>(permc, cptr, cpk2, Tl,
                                       (const unsigned*)hxb[i], agg, hstep);
    ftail_f_k<<<NB16, 256, 0, stream>>>(agg, l2t, l2bi, bwt, bbi, hcur,
                                        (u16*)svb[i], hnxt, l1n, hxn, N_ATOMS);
    float* tmp = hcur; hcur = hnxt; hnxt = tmp;
  }

  // ---------------- head (fused) + per-molecule energy ----------------
  // NLAY even -> hcur == hA here
  float* ea = dgb;
  headf_k<<<GB, 256, 0, stream>>>(hcur, hw1, hb1, hw2, hb2, ea, g0b);
  ered_k<<<NMOL, 64, 0, stream>>>(batch, ea, out);

  // ---------------- backward ----------------
  // g_3 = gh (g0b). For i < 3 the bwdT GEMM of layer i+1 is fused into
  // bhead2: g_i = agg(dhx_{i+1}) @ l1_{i+1}^T + g_{i+1}, stored to gnxt
  // (except at i==0 where g_0 is never consumed).
  float* gcur = g0b;
  float* gnxt = g1b;
  for (int i = NLAY - 1; i >= 0; i--) {
    const u16* l2p = wp + ((size_t)(i*3 + 1) << 14);
    const u16* bwp = wp + ((size_t)(i*3 + 2) << 14);
    const unsigned* Tl = T + (size_t)i * NN * HD;

    if (i == NLAY - 1) {
      bhead2_f_k<<<NB16, 256, 0, stream>>>(nullptr, nullptr, nullptr, gcur,
                                           bwp, (const u16*)svb[i], l2p,
                                           (u16*)dgb, nullptr, N_ATOMS);
    } else {
      const u16* l1nx = wp + ((size_t)((i+1)*3 + 0) << 14);
      float* gout = (i > 0) ? gnxt : nullptr;
      bhead2_f_k<<<NB16, 256, 0, stream>>>(agg, l1nx, gcur, nullptr,
                                           bwp, (const u16*)svb[i], l2p,
                                           (u16*)dgb, gout, N_ATOMS);
      if (i > 0) { float* tmp = gcur; gcur = gnxt; gnxt = tmp; }
    }
    gath_bwd_k<<<AB, 256, 0, stream>>>(permr, rptr, rpk2, Tl,
                                       (const unsigned*)dgb,
                                       (const unsigned*)hxb[i], agg, ddslot,
                                       i != NLAY - 1, i != 0, hstep, inv_h);
  }

  forceg_k<<<(N_ATOMS * 8 + 255) / 256, 256, 0, stream>>>(
      rptr, rpk2, cptr, cpk2, cslot, ddslot, pos, out + NMOL, hstep);
}

// Round 10
// 761.667 us; speedup vs baseline: 1.0333x; 1.0333x over previous
//
#include <hip/hip_runtime.h>

#define HD 128

constexpr int N_ATOMS = 20000;
constexpr int N_EDGES = 320000;
constexpr int NLAY   = 4;
constexpr int NMOL   = 200;
constexpr float FCUT  = 5.0f;
constexpr float DELTA = FCUT / 127.0f;
constexpr float GCOEFF = -0.5f / (DELTA * DELTA);
constexpr float PI_F  = 3.14159265358979323846f;
constexpr float LN2F  = 0.6931471805599453f;

typedef unsigned short u16;
typedef __attribute__((ext_vector_type(8))) short short8v;
typedef __attribute__((ext_vector_type(4))) float f32x4;

__device__ __forceinline__ float sspf(float x) {
  return fmaxf(x, 0.0f) + log1pf(expf(-fabsf(x))) - LN2F;
}
__device__ __forceinline__ float sigmf(float x) {
  return 1.0f / (1.0f + expf(-x));
}

// bf16 pack/unpack (round-to-nearest-even)
__device__ __forceinline__ unsigned bfpack(float a, float b) {
  unsigned ua = __float_as_uint(a);
  unsigned ub = __float_as_uint(b);
  ua = (ua + 0x7FFFu + ((ua >> 16) & 1u)) >> 16;
  ub = (ub + 0x7FFFu + ((ub >> 16) & 1u)) >> 16;
  return (ub << 16) | ua;
}
__device__ __forceinline__ float bflo(unsigned p) { return __uint_as_float(p << 16); }
__device__ __forceinline__ float bfhi(unsigned p) { return __uint_as_float(p & 0xFFFF0000u); }
__device__ __forceinline__ u16 f2bf(float x) {
  unsigned u = __float_as_uint(x);
  u = (u + 0x7FFFu + ((u >> 16) & 1u)) >> 16;
  return (u16)u;
}
__device__ __forceinline__ float bf2f(u16 b) { return __uint_as_float((unsigned)b << 16); }

// split f32 into hi bf16 (truncate) + lo bf16, packed u32 (hi<<16 | lo)
__device__ __forceinline__ unsigned packhl(float s) {
  unsigned hs = __float_as_uint(s) & 0xffff0000u;
  float lo = s - __uint_as_float(hs);
  return hs | (__float_as_uint(lo) >> 16);
}

// two f32 bit patterns -> hi-pair uint and lo-pair uint (bf16 pairs)
__device__ __forceinline__ unsigned hpair_f32(unsigned a, unsigned b, unsigned& lopair) {
  unsigned ha = a & 0xffff0000u, hb = b & 0xffff0000u;
  float la = __uint_as_float(a) - __uint_as_float(ha);
  float lb = __uint_as_float(b) - __uint_as_float(hb);
  lopair = (__float_as_uint(lb) & 0xffff0000u) | (__float_as_uint(la) >> 16);
  return hb | (ha >> 16);
}

// ------------------------------------------------------------------
// small elementwise kernels
// ------------------------------------------------------------------

__global__ __launch_bounds__(256) void h0_k(
    const float* __restrict__ emb, const int* __restrict__ z,
    float* __restrict__ h0)
{
  int i = blockIdx.x * 256 + threadIdx.x;
  if (i >= N_ATOMS * HD) return;
  int n = i >> 7, k = i & 127;
  h0[i] = emb[z[n] * HD + k];
}

// bf16 weight prep:
//  wsel 0..2 (lin1,lin2,blk): wp = bf16(W) row-major, wt = bf16(W^T)
//  wsel 3..4 (mlp_w1,mlp_w2): mt = bf16(W^T) only
__global__ __launch_bounds__(256) void wprep_k(
    const float* __restrict__ l1, const float* __restrict__ l2,
    const float* __restrict__ bw, const float* __restrict__ mw1,
    const float* __restrict__ mw2,
    u16* __restrict__ wt, u16* __restrict__ wp, u16* __restrict__ mt)
{
  int i = blockIdx.x * 256 + threadIdx.x;
  if (i >= NLAY * 5 * HD * HD) return;
  int e = i & (HD * HD - 1);
  int wl = i >> 14;
  int wsel = wl % 5;
  int lay = wl / 5;
  const float* W;
  if      (wsel == 0) W = l1;
  else if (wsel == 1) W = l2;
  else if (wsel == 2) W = bw;
  else if (wsel == 3) W = mw1;
  else                W = mw2;
  W += (size_t)lay * HD * HD;
  u16 b = f2bf(W[e]);
  int k = e >> 7, n = e & 127;
  if (wsel < 3) {
    size_t base = (size_t)(lay * 3 + wsel) << 14;
    wp[base + e] = b;
    wt[base + (size_t)n * HD + k] = b;
  } else {
    size_t base = (size_t)(lay * 2 + (wsel - 3)) << 14;
    mt[base + (size_t)n * HD + k] = b;
  }
}

// ------------------------------------------------------------------
// CSR build: combined histogram, dual scan (+degree histogram), scatter
// ------------------------------------------------------------------
__global__ __launch_bounds__(256) void histboth_k(
    const int* __restrict__ row, const int* __restrict__ col,
    int* __restrict__ cntR, int* __restrict__ cntC)
{
  int e = blockIdx.x * 256 + threadIdx.x;
  if (e >= N_EDGES) return;
  atomicAdd(&cntC[col[e]], 1);
  atomicAdd(&cntR[row[e]], 1);
}

// block 0: cnt0 -> cptr,cur0,binc ; block 1: cnt1 -> rptr,cur1,binr
// register-cached; also builds the degree histogram (bin = 255-min(d,255))
// via per-block LDS atomics + exclusive plain store (no global atomics)
__global__ __launch_bounds__(256) void scan2_k(
    const int* __restrict__ cnt0, const int* __restrict__ cnt1,
    int* __restrict__ cptr, int* __restrict__ rptr,
    int* __restrict__ cur0, int* __restrict__ cur1,
    int* __restrict__ binc, int* __restrict__ binr)
{
  constexpr int CH = 80;  // 256*80 = 20480 >= 20001; 320 B/thread, 16B-aligned
  __shared__ int part[256];
  __shared__ int lh[256];
  const int* cnt = blockIdx.x == 0 ? cnt0 : cnt1;
  int* ptr = blockIdx.x == 0 ? cptr : rptr;
  int* cur = blockIdx.x == 0 ? cur0 : cur1;
  int* bin = blockIdx.x == 0 ? binc : binr;
  int t = threadIdx.x;
  lh[t] = 0;
  int base = t * CH;
  int v[CH];
  if (base + CH <= N_ATOMS) {
#pragma unroll
    for (int i = 0; i < CH / 4; i++) {
      int4 q = *(const int4*)(cnt + base + i * 4);
      v[4*i+0] = q.x; v[4*i+1] = q.y; v[4*i+2] = q.z; v[4*i+3] = q.w;
    }
  } else {
#pragma unroll
    for (int i = 0; i < CH; i++)
      v[i] = (base + i < N_ATOMS) ? cnt[base + i] : 0;
  }
  __syncthreads();   // lh zeroed everywhere before atomics
#pragma unroll
  for (int i = 0; i < CH; i++)
    if (base + i < N_ATOMS) atomicAdd(&lh[255 - min(v[i], 255)], 1);
  int s = 0;
#pragma unroll
  for (int i = 0; i < CH; i++) s += v[i];
  part[t] = s;
  __syncthreads();   // all lh atomics + part writes complete
  bin[t] = lh[t];    // exclusive per-block ownership: plain store
  for (int off = 1; off < 256; off <<= 1) {
    int u = (t >= off) ? part[t - off] : 0;
    __syncthreads();
    part[t] += u;
    __syncthreads();
  }
  int run = part[t] - s;
#pragma unroll
  for (int i = 0; i < CH; i++) {
    int idx = base + i;
    if (idx < N_ATOMS) { ptr[idx] = run; cur[idx] = run; }
    else if (idx == N_ATOMS) ptr[idx] = run;
    run += v[i];
  }
}

// geometry + both-direction CSR scatter; stores packed {other|i0<<16, t}
__global__ __launch_bounds__(256) void scatboth_k(
    const float* __restrict__ pos, const int* __restrict__ row,
    const int* __restrict__ col, int* __restrict__ cur0,
    int* __restrict__ cur1, uint2* __restrict__ cpk2,
    uint2* __restrict__ rpk2, int* __restrict__ cslot, float inv_h)
{
  int e = blockIdx.x * 256 + threadIdx.x;
  if (e >= N_EDGES) return;
  int r = row[e], c = col[e];
  float dx = pos[3*r+0] - pos[3*c+0];
  float dy = pos[3*r+1] - pos[3*c+1];
  float dz = pos[3*r+2] - pos[3*c+2];
  float d = sqrtf(dx*dx + dy*dy + dz*dz);
  float fi = d * inv_h;
  int i0 = (int)fi;
  float t = fi - (float)i0;
  unsigned pk = (unsigned)c | ((unsigned)i0 << 16);
  unsigned tu = __float_as_uint(t);
  int pr = atomicAdd(&cur1[r], 1);
  rpk2[pr] = make_uint2(pk, tu);
  int pc = atomicAdd(&cur0[c], 1);
  cpk2[pc] = make_uint2((unsigned)r | ((unsigned)i0 << 16), tu);
  cslot[pc] = pr;
}

// ------------------------------------------------------------------
// degree-sort permutation (descending): two-level ranks, no hot
// global atomics (per-block LDS hist -> one range-reserve per bin)
// ------------------------------------------------------------------
__global__ __launch_bounds__(256) void dscan_k(
    int* __restrict__ binc, int* __restrict__ binr)
{
  int* bin = blockIdx.x == 0 ? binc : binr;
  __shared__ int sh[256];
  int t = threadIdx.x;
  int v = bin[t];
  sh[t] = v;
  __syncthreads();
  for (int off = 1; off < 256; off <<= 1) {
    int u = (t >= off) ? sh[t - off] : 0;
    __syncthreads();
    sh[t] += u;
    __syncthreads();
  }
  bin[t] = sh[t] - v;   // exclusive prefix
}

__global__ __launch_bounds__(256) void dscat_k(
    const int* __restrict__ cptr, const int* __restrict__ rptr,
    int* __restrict__ binc, int* __restrict__ binr,
    int* __restrict__ permc, int* __restrict__ permr)
{
  __shared__ int lhc[256], lhr[256], lbc[256], lbr[256];
  int t = threadIdx.x;
  lhc[t] = 0; lhr[t] = 0;
  __syncthreads();
  int a = blockIdx.x * 256 + t;
  int bc = 0, br = 0, rc = 0, rr = 0;
  bool valid = a < N_ATOMS;
  if (valid) {
    int dc = cptr[a+1] - cptr[a];
    int dr = rptr[a+1] - rptr[a];
    bc = 255 - min(dc, 255);
    br = 255 - min(dr, 255);
    rc = atomicAdd(&lhc[bc], 1);   // local rank within block+bin
    rr = atomicAdd(&lhr[br], 1);
  }
  __syncthreads();
  if (lhc[t] > 0) lbc[t] = atomicAdd(&binc[t], lhc[t]);  // reserve range
  if (lhr[t] > 0) lbr[t] = atomicAdd(&binr[t], lhr[t]);
  __syncthreads();
  if (valid) {
    permc[lbc[bc] + rc] = a;
    permr[lbr[br] + rr] = a;
  }
}

// ------------------------------------------------------------------
// table build
// ------------------------------------------------------------------
__global__ __launch_bounds__(256) void nodeA_k(
    float* __restrict__ A, float* __restrict__ dA, int nnode, float hstep)
{
  int i = blockIdx.x * 256 + threadIdx.x;
  if (i >= nnode * HD) return;
  int node = i >> 7, g = i & 127;
  float d = (float)node * hstep;
  float t = d - (float)g * DELTA;
  float a = expf(GCOEFF * t * t);
  A[i] = a;
  dA[i] = a * 2.0f * GCOEFF * t;
}

__global__ __launch_bounds__(256) void nodeact_k(
    const float* __restrict__ t1, const float* __restrict__ u,
    float* __restrict__ s, float* __restrict__ sp, int total)
{
  int i = blockIdx.x * 256 + threadIdx.x;
  if (i >= total) return;
  float x = t1[i];
  s[i] = sspf(x);
  sp[i] = sigmf(x) * u[i];
}

__global__ __launch_bounds__(256) void nodecomb_k(
    const float* __restrict__ P0, const float* __restrict__ D0,
    unsigned* __restrict__ T, int nnode, float hstep)
{
  int i = blockIdx.x * 256 + threadIdx.x;
  int total = NLAY * nnode * HD;
  if (i >= total) return;
  int rem = i % (nnode * HD);
  int node = rem >> 7;
  float d = (float)node * hstep;
  float C  = 0.5f * cosf(d * (PI_F / FCUT)) + 0.5f;
  float Cp = -0.5f * sinf(d * (PI_F / FCUT)) * (PI_F / FCUT);
  float p = P0[i], q = D0[i];
  T[i] = bfpack(p * C, q * C + p * Cp);
}

// ------------------------------------------------------------------
// no-LDS MFMA wave GEMM: wave computes rows [m0,m0+16) x cols
// [wbase,wbase+32) of C = A[M,128] @ B[128,128].
// Bt layout: Bt[n*HD + k] = B[k][n] (bf16).
// ------------------------------------------------------------------
__device__ __forceinline__ void wave_mm(
    const float* __restrict__ Av, const u16* __restrict__ Bt,
    int m0, int wbase, int lc, int lg, int mclamp, f32x4 acc[2])
{
  short8v bfr[4][2];
#pragma unroll
  for (int ks = 0; ks < 4; ++ks)
#pragma unroll
    for (int nt = 0; nt < 2; ++nt)
      bfr[ks][nt] = *(const short8v*)(Bt + (size_t)(wbase + nt*16 + lc) * HD + ks*32 + lg*8);
  int ar = m0 + lc;
  if (ar > mclamp) ar = mclamp;   // row-clamped load; garbage rows never stored
  f32x4 z = {0.f, 0.f, 0.f, 0.f};
  acc[0] = z; acc[1] = z;
#pragma unroll
  for (int ks = 0; ks < 4; ++ks) {
    const float* p = Av + (size_t)ar * HD + ks*32 + lg*8;
    uint4 u0 = *(const uint4*)p;
    uint4 u1 = *(const uint4*)(p + 4);
    unsigned p0l, p1l, p2l, p3l;
    unsigned p0h = hpair_f32(u0.x, u0.y, p0l);
    unsigned p1h = hpair_f32(u0.z, u0.w, p1l);
    unsigned p2h = hpair_f32(u1.x, u1.y, p2l);
    unsigned p3h = hpair_f32(u1.z, u1.w, p3l);
    uint4 hv = make_uint4(p0h, p1h, p2h, p3h);
    uint4 lv = make_uint4(p0l, p1l, p2l, p3l);
    short8v ah = *(short8v*)&hv, al = *(short8v*)&lv;
    acc[0] = __builtin_amdgcn_mfma_f32_16x16x32_bf16(ah, bfr[ks][0], acc[0], 0, 0, 0);
    acc[1] = __builtin_amdgcn_mfma_f32_16x16x32_bf16(ah, bfr[ks][1], acc[1], 0, 0, 0);
    acc[0] = __builtin_amdgcn_mfma_f32_16x16x32_bf16(al, bfr[ks][0], acc[0], 0, 0, 0);
    acc[1] = __builtin_amdgcn_mfma_f32_16x16x32_bf16(al, bfr[ks][1], acc[1], 0, 0, 0);
  }
}

// same, A from LDS tile of packed (hi16|lo16) u32, rows [16][132]
__device__ __forceinline__ void wave_mm_lds(
    const unsigned (*__restrict__ Sl)[132], const u16* __restrict__ Bt,
    int wbase, int lc, int lg, f32x4 acc[2])
{
  short8v bfr[4][2];
#pragma unroll
  for (int ks = 0; ks < 4; ++ks)
#pragma unroll
    for (int nt = 0; nt < 2; ++nt)
      bfr[ks][nt] = *(const short8v*)(Bt + (size_t)(wbase + nt*16 + lc) * HD + ks*32 + lg*8);
  f32x4 z = {0.f, 0.f, 0.f, 0.f};
  acc[0] = z; acc[1] = z;
#pragma unroll
  for (int ks = 0; ks < 4; ++ks) {
    uint4 u0 = *(const uint4*)&Sl[lc][ks*32 + lg*8];
    uint4 u1 = *(const uint4*)&Sl[lc][ks*32 + lg*8 + 4];
    uint4 hv = make_uint4(
      (u0.y & 0xffff0000u) | (u0.x >> 16),
      (u0.w & 0xffff0000u) | (u0.z >> 16),
      (u1.y & 0xffff0000u) | (u1.x >> 16),
      (u1.w & 0xffff0000u) | (u1.z >> 16));
    uint4 lv = make_uint4(
      (u0.y << 16) | (u0.x & 0xffffu),
      (u0.w << 16) | (u0.z & 0xffffu),
      (u1.y << 16) | (u1.x & 0xffffu),
      (u1.w << 16) | (u1.z & 0xffffu));
    short8v ah = *(short8v*)&hv, al = *(short8v*)&lv;
    acc[0] = __builtin_amdgcn_mfma_f32_16x16x32_bf16(ah, bfr[ks][0], acc[0], 0, 0, 0);
    acc[1] = __builtin_amdgcn_mfma_f32_16x16x32_bf16(ah, bfr[ks][1], acc[1], 0, 0, 0);
    acc[0] = __builtin_amdgcn_mfma_f32_16x16x32_bf16(al, bfr[ks][0], acc[0], 0, 0, 0);
    acc[1] = __builtin_amdgcn_mfma_f32_16x16x32_bf16(al, bfr[ks][1], acc[1], 0, 0, 0);
  }
}

// hx = h @ W  (Bt = W^T bf16), output u16 bf16  (layer 0 only)
__global__ __launch_bounds__(256) void nmm_hx_k(
    const float* __restrict__ h, const u16* __restrict__ Bt,
    u16* __restrict__ hx, int M)
{
  int t = threadIdx.x, lane = t & 63;
  int lc = lane & 15, lg = lane >> 4;
  int wbase = (t >> 6) * 32;
  int m0 = blockIdx.x * 16;
  f32x4 acc[2];
  wave_mm(h, Bt, m0, wbase, lc, lg, M - 1, acc);
#pragma unroll
  for (int nt = 0; nt < 2; ++nt) {
    int ccol = wbase + nt*16 + lc;
#pragma unroll
    for (int j = 0; j < 4; ++j) {
      int grow = m0 + lg*4 + j;
      if (grow < M) hx[(size_t)grow * HD + ccol] = f2bf(acc[nt][j]);
    }
  }
}

// fused fwd tail: V = agg@l2 + l2b; svb = bf16(sigm(V));
// hout = h + ssp(V)@bw + bb; optional hxn = bf16(hout @ l1next)
__global__ __launch_bounds__(256) void ftail_f_k(
    const float* __restrict__ agg, const u16* __restrict__ l2t,
    const float* __restrict__ l2b, const u16* __restrict__ bwt,
    const float* __restrict__ bb, const float* __restrict__ h,
    u16* __restrict__ svb, float* __restrict__ hout,
    const u16* __restrict__ l1n, u16* __restrict__ hxn, int M)
{
  __shared__ unsigned Sl[16][132];
  int t = threadIdx.x, lane = t & 63;
  int lc = lane & 15, lg = lane >> 4;
  int wbase = (t >> 6) * 32;
  int m0 = blockIdx.x * 16;
  f32x4 acc[2];
  wave_mm(agg, l2t, m0, wbase, lc, lg, M - 1, acc);
#pragma unroll
  for (int nt = 0; nt < 2; ++nt) {
    int ccol = wbase + nt*16 + lc;
    float bv = l2b[ccol];
#pragma unroll
    for (int j = 0; j < 4; ++j) {
      int lrow = lg*4 + j;
      int grow = m0 + lrow;
      float s = 0.0f;
      if (grow < M) {
        float x = acc[nt][j] + bv;
        svb[(size_t)grow * HD + ccol] = f2bf(sigmf(x));
        s = sspf(x);
      }
      Sl[lrow][ccol] = packhl(s);
    }
  }
  __syncthreads();
  wave_mm_lds(Sl, bwt, wbase, lc, lg, acc);

  float ho[2][4];
#pragma unroll
  for (int nt = 0; nt < 2; ++nt) {
    int ccol = wbase + nt*16 + lc;
    float bv = bb[ccol];
#pragma unroll
    for (int j = 0; j < 4; ++j) {
      int grow = m0 + lg*4 + j;
      float x = 0.0f;
      if (grow < M) {
        x = acc[nt][j] + bv + h[(size_t)grow * HD + ccol];
        hout[(size_t)grow * HD + ccol] = x;
      }
      ho[nt][j] = x;
    }
  }
  if (l1n) {
    __syncthreads();   // all waves done reading Sl (bw pass)
#pragma unroll
    for (int nt = 0; nt < 2; ++nt) {
      int ccol = wbase + nt*16 + lc;
#pragma unroll
      for (int j = 0; j < 4; ++j)
        Sl[lg*4 + j][ccol] = packhl(ho[nt][j]);
    }
    __syncthreads();
    wave_mm_lds(Sl, l1n, wbase, lc, lg, acc);
#pragma unroll
    for (int nt = 0; nt < 2; ++nt) {
      int ccol = wbase + nt*16 + lc;
#pragma unroll
      for (int j = 0; j < 4; ++j) {
        int grow = m0 + lg*4 + j;
        if (grow < M) hxn[(size_t)grow * HD + ccol] = f2bf(acc[nt][j]);
      }
    }
  }
}

// fused bwd head, optionally with the previous layer's bwdT GEMM folded in:
//  if aggprev: g = aggprev@l1prev^T + gadd  (store to gout if non-null)
//  else:       g = gdirect
//  dv = (g@bw^T)*sigm(V) (from svb); dagg = dv@l2^T (bf16 out)
__global__ __launch_bounds__(256) void bhead2_f_k(
    const float* __restrict__ aggprev, const u16* __restrict__ l1prev,
    const float* __restrict__ gadd, const float* __restrict__ gdirect,
    const u16* __restrict__ bwp, const u16* __restrict__ svb,
    const u16* __restrict__ l2p, u16* __restrict__ dagg,
    float* __restrict__ gout, int M)
{
  __shared__ unsigned Sl[16][132];
  int t = threadIdx.x, lane = t & 63;
  int lc = lane & 15, lg = lane >> 4;
  int wbase = (t >> 6) * 32;
  int m0 = blockIdx.x * 16;
  f32x4 acc[2];
  if (aggprev) {
    wave_mm(aggprev, l1prev, m0, wbase, lc, lg, M - 1, acc);
#pragma unroll
    for (int nt = 0; nt < 2; ++nt) {
      int ccol = wbase + nt*16 + lc;
#pragma unroll
      for (int j = 0; j < 4; ++j) {
        int lrow = lg*4 + j;
        int grow = m0 + lrow;
        float x = 0.0f;
        if (grow < M) {
          x = acc[nt][j] + gadd[(size_t)grow * HD + ccol];
          if (gout) gout[(size_t)grow * HD + ccol] = x;
        }
        Sl[lrow][ccol] = packhl(x);
      }
    }
    __syncthreads();
    wave_mm_lds(Sl, bwp, wbase, lc, lg, acc);
    __syncthreads();   // all waves done reading g before dv overwrites Sl
  } else {
    wave_mm(gdirect, bwp, m0, wbase, lc, lg, M - 1, acc);
  }
  // dv = acc * sigm(V), pack into Sl
#pragma unroll
  for (int nt = 0; nt < 2; ++nt) {
    int ccol = wbase + nt*16 + lc;
#pragma unroll
    for (int j = 0; j < 4; ++j) {
      int lrow = lg*4 + j;
      int grow = m0 + lrow;
      float dv = 0.0f;
      if (grow < M)
        dv = acc[nt][j] * bf2f(svb[(size_t)grow * HD + ccol]);
      Sl[lrow][ccol] = packhl(dv);
    }
  }
  __syncthreads();
  wave_mm_lds(Sl, l2p, wbase, lc, lg, acc);
#pragma unroll
  for (int nt = 0; nt < 2; ++nt) {
    int ccol = wbase + nt*16 + lc;
#pragma unroll
    for (int j = 0; j < 4; ++j) {
      int grow = m0 + lg*4 + j;
      if (grow < M) dagg[(size_t)grow * HD + ccol] = f2bf(acc[nt][j]);
    }
  }
}

// batched table-build GEMM; blockIdx.z selects (A0,bias0,C0) or (A1,null,C1)
__global__ __launch_bounds__(256) void tblmm2_k(
    const float* __restrict__ A0, const float* __restrict__ A1, size_t astride,
    const u16* __restrict__ Bt, size_t bstride,
    const float* __restrict__ bias0, size_t biasstride,
    float* __restrict__ C0, float* __restrict__ C1, size_t cstride, int M)
{
  int l = blockIdx.y;
  int zz = blockIdx.z;
  const float* A = (zz ? A1 : A0) + (size_t)l * astride;
  const u16* B = Bt + (size_t)l * bstride;
  const float* bias = zz ? nullptr : (bias0 ? bias0 + (size_t)l * biasstride : nullptr);
  float* C = (zz ? C1 : C0) + (size_t)l * cstride;
  int t = threadIdx.x, lane = t & 63;
  int lc = lane & 15, lg = lane >> 4;
  int wbase = (t >> 6) * 32;
  int m0 = blockIdx.x * 16;
  f32x4 acc[2];
  wave_mm(A, B, m0, wbase, lc, lg, M - 1, acc);
#pragma unroll
  for (int nt = 0; nt < 2; ++nt) {
    int ccol = wbase + nt*16 + lc;
    float bv = bias ? bias[ccol] : 0.0f;
#pragma unroll
    for (int j = 0; j < 4; ++j) {
      int grow = m0 + lg*4 + j;
      if (grow < M) C[(size_t)grow * HD + ccol] = acc[nt][j] + bv;
    }
  }
}

// ------------------------------------------------------------------
// forward gather: agg[a] = sum_in hx[src] * P(d); coeffs from (i0,t)
// atoms visited via degree-sorted perm for wave load balance
// ------------------------------------------------------------------
__global__ __launch_bounds__(256) void gath_fwd_k(
    const int* __restrict__ perm, const int* __restrict__ cptr,
    const uint2* __restrict__ cpk2, const unsigned* __restrict__ T,
    const unsigned* __restrict__ hx, float* __restrict__ agg, float hstep)
{
  int ai = blockIdx.x * 4 + (threadIdx.x >> 6);
  if (ai >= N_ATOMS) return;
  int a = perm[ai];
  int half = (threadIdx.x >> 5) & 1;
  int l32 = threadIdx.x & 31;
  int ch = l32 * 4;
  int beg = cptr[a], end = cptr[a + 1];
  float s0 = 0.f, s1 = 0.f, s2 = 0.f, s3 = 0.f;
#pragma unroll 2
  for (int j = beg + half; j < end; j += 2) {
    uint2 pk2 = cpk2[j];
    float t = __uint_as_float(pk2.y);
    int other = pk2.x & 0xffffu;
    float t2 = t * t, t3 = t2 * t;
    float cx = 2.f*t3 - 3.f*t2 + 1.f;
    float cy = (t3 - 2.f*t2 + t) * hstep;
    float cz = 3.f*t2 - 2.f*t3;
    float cw = (t3 - t2) * hstep;
    const unsigned* tp = T + (size_t)(pk2.x >> 16) * HD + ch;
    uint4 q0 = *(const uint4*)(tp);
    uint4 q1 = *(const uint4*)(tp + HD);
    uint2 hp = *(const uint2*)(hx + (size_t)other * 64 + l32 * 2);
    float v0 = cx*bflo(q0.x) + cy*bfhi(q0.x) + cz*bflo(q1.x) + cw*bfhi(q1.x);
    float v1 = cx*bflo(q0.y) + cy*bfhi(q0.y) + cz*bflo(q1.y) + cw*bfhi(q1.y);
    float v2 = cx*bflo(q0.z) + cy*bfhi(q0.z) + cz*bflo(q1.z) + cw*bfhi(q1.z);
    float v3 = cx*bflo(q0.w) + cy*bfhi(q0.w) + cz*bflo(q1.w) + cw*bfhi(q1.w);
    s0 = fmaf(bflo(hp.x), v0, s0);
    s1 = fmaf(bfhi(hp.x), v1, s1);
    s2 = fmaf(bflo(hp.y), v2, s2);
    s3 = fmaf(bfhi(hp.y), v3, s3);
  }
  s0 += __shfl_xor(s0, 32, 64);
  s1 += __shfl_xor(s1, 32, 64);
  s2 += __shfl_xor(s2, 32, 64);
  s3 += __shfl_xor(s3, 32, 64);
  if (half == 0)
    *(float4*)(agg + (size_t)a * HD + ch) = make_float4(s0, s1, s2, s3);
}

// ------------------------------------------------------------------
// backward gather: ddslot (write on first layer, else +=);
// dhx only when need_dhx (dead at the last backward layer)
// ------------------------------------------------------------------
__global__ __launch_bounds__(256) void gath_bwd_k(
    const int* __restrict__ perm, const int* __restrict__ rptr,
    const uint2* __restrict__ rpk2, const unsigned* __restrict__ T,
    const unsigned* __restrict__ dagg, const unsigned* __restrict__ hx,
    float* __restrict__ dhx, float* __restrict__ ddslot, int accum,
    int need_dhx, float hstep, float inv_h)
{
  int ai = blockIdx.x * 4 + (threadIdx.x >> 6);
  if (ai >= N_ATOMS) return;
  int a = perm[ai];
  int half = (threadIdx.x >> 5) & 1;
  int l32 = threadIdx.x & 31;
  int ch = l32 * 4;
  int beg = rptr[a], end = rptr[a + 1];
  uint2 hp = *(const uint2*)(hx + (size_t)a * 64 + l32 * 2);
  float h0 = bflo(hp.x), h1 = bfhi(hp.x), h2 = bflo(hp.y), h3 = bfhi(hp.y);
  float s0 = 0.f, s1 = 0.f, s2 = 0.f, s3 = 0.f;
#pragma unroll 2
  for (int j = beg + half; j < end; j += 2) {
    uint2 pk2 = rpk2[j];
    float t = __uint_as_float(pk2.y);
    int other = pk2.x & 0xffffu;
    float t2 = t * t, t3 = t2 * t;
    float cbx = (6.f*t2 - 6.f*t) * inv_h;
    float cby = 3.f*t2 - 4.f*t + 1.f;
    float cbz = -cbx;
    float cbw = 3.f*t2 - 2.f*t;
    const unsigned* tp = T + (size_t)(pk2.x >> 16) * HD + ch;
    uint4 q0 = *(const uint4*)(tp);
    uint4 q1 = *(const uint4*)(tp + HD);
    uint2 dp = *(const uint2*)(dagg + (size_t)other * 64 + l32 * 2);
    float da0 = bflo(dp.x), da1 = bfhi(dp.x), da2 = bflo(dp.y), da3 = bfhi(dp.y);
    float x0l = bflo(q0.x), x0h = bfhi(q0.x), y0l = bflo(q1.x), y0h = bfhi(q1.x);
    float x1l = bflo(q0.y), x1h = bfhi(q0.y), y1l = bflo(q1.y), y1h = bfhi(q1.y);
    float x2l = bflo(q0.z), x2h = bfhi(q0.z), y2l = bflo(q1.z), y2h = bfhi(q1.z);
    float x3l = bflo(q0.w), x3h = bfhi(q0.w), y3l = bflo(q1.w), y3h = bfhi(q1.w);
    float g0 = cbx*x0l + cby*x0h + cbz*y0l + cbw*y0h;
    float g1 = cbx*x1l + cby*x1h + cbz*y1l + cbw*y1h;
    float g2 = cbx*x2l + cby*x2h + cbz*y2l + cbw*y2h;
    float g3 = cbx*x3l + cby*x3h + cbz*y3l + cbw*y3h;
    float dah0 = da0*h0, dah1 = da1*h1, dah2 = da2*h2, dah3 = da3*h3;
    float dot = dah0*g0;
    dot = fmaf(dah1, g1, dot);
    dot = fmaf(dah2, g2, dot);
    dot = fmaf(dah3, g3, dot);
#pragma unroll
    for (int off = 16; off > 0; off >>= 1) dot += __shfl_down(dot, off, 32);
    if (l32 == 0) ddslot[j] = accum ? (ddslot[j] + dot) : dot;
    if (need_dhx) {
      float cax = 2.f*t3 - 3.f*t2 + 1.f;
      float cay = (t3 - 2.f*t2 + t) * hstep;
      float caz = 3.f*t2 - 2.f*t3;
      float caw = (t3 - t2) * hstep;
      float v0 = cax*x0l + cay*x0h + caz*y0l + caw*y0h;
      float v1 = cax*x1l + cay*x1h + caz*y1l + caw*y1h;
      float v2 = cax*x2l + cay*x2h + caz*y2l + caw*y2h;
      float v3 = cax*x3l + cay*x3h + caz*y3l + caw*y3h;
      s0 = fmaf(da0, v0, s0);
      s1 = fmaf(da1, v1, s1);
      s2 = fmaf(da2, v2, s2);
      s3 = fmaf(da3, v3, s3);
    }
  }
  if (need_dhx) {
    s0 += __shfl_xor(s0, 32, 64);
    s1 += __shfl_xor(s1, 32, 64);
    s2 += __shfl_xor(s2, 32, 64);
    s3 += __shfl_xor(s3, 32, 64);
    if (half == 0)
      *(float4*)(dhx + (size_t)a * HD + ch) = make_float4(s0, s1, s2, s3);
  }
}

// ------------------------------------------------------------------
// fused head: s = h4@hw1 + hb1; ea[a] = ssp(s)@hw2 + hb2;
// gh = (sigm(s)*hw2) @ hw1^T
// ------------------------------------------------------------------
__global__ __launch_bounds__(256) void headf_k(
    const float* __restrict__ h4, const float* __restrict__ hw1,
    const float* __restrict__ hb1, const float* __restrict__ hw2,
    const float* __restrict__ hb2, float* __restrict__ ea,
    float* __restrict__ gh)
{
  __shared__ float As[16][68];
  __shared__ float Bs[16][132];
  __shared__ float Ss[64][68];
  __shared__ float red[64][17];
  int t = threadIdx.x;
  int tx = t & 15, ty = t >> 4;
  int m0 = blockIdx.x * 64;

  float acc4[4][4];
#pragma unroll
  for (int r = 0; r < 4; r++)
#pragma unroll
    for (int c = 0; c < 4; c++) acc4[r][c] = 0.0f;

  for (int k0 = 0; k0 < HD; k0 += 16) {
    {
      int rrow = t >> 2;
      int kg = (t & 3) * 4;
      int gm = m0 + rrow;
      float4 av = make_float4(0.f, 0.f, 0.f, 0.f);
      if (gm < N_ATOMS) av = *(const float4*)(h4 + (size_t)gm * HD + k0 + kg);
      As[kg+0][rrow] = av.x; As[kg+1][rrow] = av.y;
      As[kg+2][rrow] = av.z; As[kg+3][rrow] = av.w;
    }
    if (t < 256) {
      int kk = t >> 4;
      int n4 = (t & 15) * 4;
      float4 bv = *(const float4*)(hw1 + (size_t)(k0 + kk) * 64 + n4);
      *(float4*)&Bs[kk][n4] = bv;
    }
    __syncthreads();
#pragma unroll
    for (int kk = 0; kk < 16; kk++) {
      float a[4], b[4];
#pragma unroll
      for (int r = 0; r < 4; r++) a[r] = As[kk][ty * 4 + r];
#pragma unroll
      for (int c = 0; c < 4; c++) b[c] = Bs[kk][tx * 4 + c];
#pragma unroll
      for (int r = 0; r < 4; r++)
#pragma unroll
        for (int c = 0; c < 4; c++) acc4[r][c] = fmaf(a[r], b[c], acc4[r][c]);
    }
    __syncthreads();
  }

  {
    int n0 = tx * 4;
    float b1v[4], w2v[4];
#pragma unroll
    for (int c = 0; c < 4; c++) { b1v[c] = hb1[n0 + c]; w2v[c] = hw2[n0 + c]; }
#pragma unroll
    for (int r = 0; r < 4; r++) {
      int lr = ty * 4 + r;
      float p = 0.0f;
#pragma unroll
      for (int c = 0; c < 4; c++) {
        float x = acc4[r][c] + b1v[c];
        p += sspf(x) * w2v[c];
        Ss[lr][n0 + c] = sigmf(x) * w2v[c];
      }
      red[lr][tx] = p;
    }
  }
  __syncthreads();
  if (t < 64) {
    int gm = m0 + t;
    if (gm < N_ATOMS) {
      float s = hb2[0];
#pragma unroll
      for (int j = 0; j < 16; j++) s += red[t][j];
      ea[gm] = s;
    }
  }

  float acc[4][8];
#pragma unroll
  for (int r = 0; r < 4; r++)
#pragma unroll
    for (int c = 0; c < 8; c++) acc[r][c] = 0.0f;

  for (int j0 = 0; j0 < 64; j0 += 16) {
#pragma unroll
    for (int it = 0; it < 2; it++) {
      int idx = t + it * 256;
      int n = idx >> 2;
      int jg = (idx & 3) * 4;
      float4 bv = *(const float4*)(hw1 + (size_t)n * 64 + j0 + jg);
      Bs[jg+0][n] = bv.x; Bs[jg+1][n] = bv.y;
      Bs[jg+2][n] = bv.z; Bs[jg+3][n] = bv.w;
    }
    __syncthreads();
#pragma unroll
    for (int kk = 0; kk < 16; kk++) {
      float a[4], b[8];
#pragma unroll
      for (int r = 0; r < 4; r++) a[r] = Ss[ty * 4 + r][j0 + kk];
#pragma unroll
      for (int c = 0; c < 8; c++) b[c] = Bs[kk][tx * 8 + c];
#pragma unroll
      for (int r = 0; r < 4; r++)
#pragma unroll
        for (int c = 0; c < 8; c++) acc[r][c] = fmaf(a[r], b[c], acc[r][c]);
    }
    __syncthreads();
  }

  int n0 = tx * 8;
#pragma unroll
  for (int r = 0; r < 4; r++) {
    int gm = m0 + ty * 4 + r;
    if (gm >= N_ATOMS) continue;
    *(float4*)(gh + (size_t)gm * HD + n0)     = *(float4*)&acc[r][0];
    *(float4*)(gh + (size_t)gm * HD + n0 + 4) = *(float4*)&acc[r][4];
  }
}

// ------------------------------------------------------------------
// per-molecule energy reduction
// ------------------------------------------------------------------
__global__ __launch_bounds__(64) void ered_k(
    const int* __restrict__ batch, const float* __restrict__ ea,
    float* __restrict__ energy)
{
  int m = blockIdx.x;
  int lo = 0, hi = N_ATOMS;
  while (lo < hi) { int mid = (lo + hi) >> 1; if (batch[mid] < m) lo = mid + 1; else hi = mid; }
  int beg = lo;
  lo = beg; hi = N_ATOMS;
  while (lo < hi) { int mid = (lo + hi) >> 1; if (batch[mid] < m + 1) lo = mid + 1; else hi = mid; }
  int end = lo;
  float s = 0.0f;
  for (int i = beg + threadIdx.x; i < end; i += 64) s += ea[i];
#pragma unroll
  for (int off = 32; off > 0; off >>= 1) s += __shfl_down(s, off, 64);
  if (threadIdx.x == 0) energy[m] = s;
}

// ------------------------------------------------------------------
// force gather; distance reconstructed from pk2: d = (i0 + t) * hstep
// ------------------------------------------------------------------
__global__ __launch_bounds__(256) void forceg_k(
    const int* __restrict__ rptr, const uint2* __restrict__ rpk2,
    const int* __restrict__ cptr, const uint2* __restrict__ cpk2,
    const int* __restrict__ cslot, const float* __restrict__ ddslot,
    const float* __restrict__ pos, float* __restrict__ force, float hstep)
{
  int idx = blockIdx.x * 256 + threadIdx.x;
  int a = idx >> 3;
  int g = idx & 7;
  if (a >= N_ATOMS) return;
  float px = pos[3*a+0], py = pos[3*a+1], pz = pos[3*a+2];
  float fx = 0.f, fy = 0.f, fz = 0.f;
  int beg = rptr[a], end = rptr[a+1];
  for (int j = beg + g; j < end; j += 8) {
    uint2 p = rpk2[j];
    int o = p.x & 0xffffu;
    float d = ((float)(p.x >> 16) + __uint_as_float(p.y)) * hstep;
    float w = ddslot[j] / d;
    fx -= w * (px - pos[3*o+0]);
    fy -= w * (py - pos[3*o+1]);
    fz -= w * (pz - pos[3*o+2]);
  }
  beg = cptr[a]; end = cptr[a+1];
  for (int j = beg + g; j < end; j += 8) {
    uint2 p = cpk2[j];
    int o = p.x & 0xffffu;
    float d = ((float)(p.x >> 16) + __uint_as_float(p.y)) * hstep;
    float w = ddslot[cslot[j]] / d;
    fx -= w * (px - pos[3*o+0]);
    fy -= w * (py - pos[3*o+1]);
    fz -= w * (pz - pos[3*o+2]);
  }
#pragma unroll
  for (int off = 4; off > 0; off >>= 1) {
    fx += __shfl_down(fx, off, 8);
    fy += __shfl_down(fy, off, 8);
    fz += __shfl_down(fz, off, 8);
  }
  if (g == 0) {
    force[3*a+0] = fx;
    force[3*a+1] = fy;
    force[3*a+2] = fz;
  }
}

// ------------------------------------------------------------------
// host launch
// ------------------------------------------------------------------
static inline int nblk(int m) { return (m + 63) / 64; }

extern "C" void kernel_launch(void* const* d_in, const int* in_sizes, int n_in,
                              void* d_out, int out_size, void* d_ws, size_t ws_size,
                              hipStream_t stream)
{
  const float* pos   = (const float*)d_in[0];
  const int*   z     = (const int*)d_in[1];
  const int*   batch = (const int*)d_in[2];
  const int*   eidx  = (const int*)d_in[3];
  const float* emb   = (const float*)d_in[4];
  const float* mlp_w1 = (const float*)d_in[5];
  const float* mlp_b1 = (const float*)d_in[6];
  const float* mlp_w2 = (const float*)d_in[7];
  const float* mlp_b2 = (const float*)d_in[8];
  const float* lin1_w = (const float*)d_in[9];
  const float* lin2_w = (const float*)d_in[10];
  const float* lin2_b = (const float*)d_in[11];
  const float* blk_w  = (const float*)d_in[12];
  const float* blk_b  = (const float*)d_in[13];
  const float* hw1 = (const float*)d_in[14];
  const float* hb1 = (const float*)d_in[15];
  const float* hw2 = (const float*)d_in[16];
  const float* hb2 = (const float*)d_in[17];

  float* out = (float*)d_out;          // [NMOL] energies ++ [N,3] forces
  float* ws  = (float*)d_ws;

  const int* row = eidx;
  const int* col = eidx + N_EDGES;

  const size_t NH = (size_t)N_ATOMS * HD;
  size_t o = 0;
  float* ddslot = ws + o; o += N_EDGES;
  int* cptr = (int*)(ws + o); o += N_ATOMS + 1;
  int* rptr = (int*)(ws + o); o += N_ATOMS + 1;
  int* cnt0 = (int*)(ws + o); o += N_ATOMS;      // cnt0,cnt1 contiguous:
  int* cnt1 = (int*)(ws + o); o += N_ATOMS;      // one memset
  int* binc = (int*)(ws + o); o += 256;
  int* binr = (int*)(ws + o); o += 256;
  int* cur0 = (int*)(ws + o); o += N_ATOMS;
  int* cur1 = (int*)(ws + o); o += N_ATOMS;
  int* permc = (int*)(ws + o); o += N_ATOMS;
  int* permr = (int*)(ws + o); o += N_ATOMS;
  int* cslot = (int*)(ws + o); o += N_EDGES;
  o = (o + 1) & ~(size_t)1;                      // 8B align for uint2
  uint2* cpk2 = (uint2*)(ws + o); o += (size_t)2 * N_EDGES;
  uint2* rpk2 = (uint2*)(ws + o); o += (size_t)2 * N_EDGES;
  // bf16 weights: wt = transposed, wp = plain, mt = transposed mlp weights
  u16* wt = (u16*)(ws + o); o += (size_t)NLAY * 3 * HD * HD / 2;
  u16* wp = (u16*)(ws + o); o += (size_t)NLAY * 3 * HD * HD / 2;
  u16* mt = (u16*)(ws + o); o += (size_t)NLAY * 2 * HD * HD / 2;
  float* hxb[4];   // bf16 (128 u16 per row) -> NH/2 floats each
  for (int i = 0; i < 4; i++) { hxb[i] = ws + o; o += NH / 2; }
  float* svb[4];   // bf16 sigm(V) -> NH/2 floats each
  for (int i = 0; i < 4; i++) { svb[i] = ws + o; o += NH / 2; }
  float* hA  = ws + o; o += NH;
  float* hB  = ws + o; o += NH;
  float* agg = ws + o; o += NH;       // fwd agg / bwd dhx / table temps
  float* g0b = ws + o; o += NH;
  float* g1b = ws + o; o += NH;
  float* dgb = ws + o; o += NH / 2;   // dagg(bf16) / ea / table temps

  // table: bf16 pairs {P*C, (P*C)'}, 1 uint per (node,ch)
  int NT = 1024;
  while (NT > 128) {
    size_t need = o + (size_t)NLAY * (NT + 1) * HD;
    if (need * sizeof(float) <= ws_size) break;
    NT >>= 1;
  }
  const int NN = NT + 1;
  const float hstep = FCUT / (float)NT;
  const float inv_h = (float)NT / FCUT;
  unsigned* T = (unsigned*)(ws + o); o += (size_t)NLAY * NN * HD;

  const int EB = (N_EDGES + 255) / 256;
  const int ABK = (N_ATOMS + 255) / 256;

  hipMemsetAsync(cnt0, 0, 2 * N_ATOMS * sizeof(int), stream);

  wprep_k<<<(NLAY * 5 * HD * HD + 255) / 256, 256, 0, stream>>>(
      lin1_w, lin2_w, blk_w, mlp_w1, mlp_w2, wt, wp, mt);

  // ---------------- CSR build (both directions) ----------------
  histboth_k<<<EB, 256, 0, stream>>>(row, col, cnt1, cnt0);
  scan2_k<<<2, 256, 0, stream>>>(cnt0, cnt1, cptr, rptr, cur0, cur1, binc, binr);
  scatboth_k<<<EB, 256, 0, stream>>>(pos, row, col, cur0, cur1, cpk2, rpk2,
                                     cslot, inv_h);

  // ---------------- degree-sort perms for gather balance ----------------
  dscan_k<<<2, 256, 0, stream>>>(binc, binr);
  dscat_k<<<ABK, 256, 0, stream>>>(cptr, rptr, binc, binr, permc, permr);

  // ---------------- build filter tables (all 4 layers) ----------------
  {
    const size_t LNH = (size_t)NN * HD;
    float* Anode  = agg;
    float* dAnode = agg + LNH;
    float* t1 = dgb;
    float* u  = g0b;
    float* s  = g1b;
    float* sp = hA;
    nodeA_k<<<((int)LNH + 255) / 256, 256, 0, stream>>>(Anode, dAnode, NN, hstep);
    dim3 gB16((NN + 15) / 16, NLAY, 2);
    tblmm2_k<<<gB16, 256, 0, stream>>>(Anode, dAnode, 0, mt, 32768,
                                       mlp_b1, HD, t1, u, LNH, NN);
    int tot = (int)(NLAY * LNH);
    nodeact_k<<<(tot + 255) / 256, 256, 0, stream>>>(t1, u, s, sp, tot);
    float* P0 = dgb;
    float* D0 = g0b;
    tblmm2_k<<<gB16, 256, 0, stream>>>(s, sp, LNH, mt + 16384, 32768,
                                       mlp_b2, HD, P0, D0, LNH, NN);
    nodecomb_k<<<(tot + 255) / 256, 256, 0, stream>>>(P0, D0, T, NN, hstep);
  }

  h0_k<<<(N_ATOMS * HD + 255) / 256, 256, 0, stream>>>(emb, z, hA);

  const int AB = (N_ATOMS + 3) / 4;
  const int GB = nblk(N_ATOMS);
  const int NB16 = (N_ATOMS + 15) / 16;   // 1250 blocks for no-LDS MFMA GEMMs

  // ---------------- forward ----------------
  float* hcur = hA;
  float* hnxt = hB;
  nmm_hx_k<<<NB16, 256, 0, stream>>>(hcur, wt, (u16*)hxb[0], N_ATOMS);
  for (int i = 0; i < NLAY; i++) {
    const u16* l2t = wt + ((size_t)(i*3 + 1) << 14);
    const u16* bwt = wt + ((size_t)(i*3 + 2) << 14);
    const u16* l1n = (i < NLAY - 1) ? wt + ((size_t)((i+1)*3 + 0) << 14) : nullptr;
    u16* hxn = (i < NLAY - 1) ? (u16*)hxb[i+1] : nullptr;
    const float* l2bi = lin2_b + (size_t)i * HD;
    const float* bbi  = blk_b + (size_t)i * HD;
    const unsigned* Tl = T + (size_t)i * NN * HD;

    gath_fwd_k<<<AB, 256, 0, stream>>>(permc, cptr, cpk2, Tl,
                                       (const unsigned*)hxb[i], agg, hstep);
    ftail_f_k<<<NB16, 256, 0, stream>>>(agg, l2t, l2bi, bwt, bbi, hcur,
                                        (u16*)svb[i], hnxt, l1n, hxn, N_ATOMS);
    float* tmp = hcur; hcur = hnxt; hnxt = tmp;
  }

  // ---------------- head (fused) + per-molecule energy ----------------
  // NLAY even -> hcur == hA here
  float* ea = dgb;
  headf_k<<<GB, 256, 0, stream>>>(hcur, hw1, hb1, hw2, hb2, ea, g0b);
  ered_k<<<NMOL, 64, 0, stream>>>(batch, ea, out);

  // ---------------- backward ----------------
  // g_3 = gh (g0b). For i < 3 the bwdT GEMM of layer i+1 is fused into
  // bhead2: g_i = agg(dhx_{i+1}) @ l1_{i+1}^T + g_{i+1}, stored to gnxt
  // (except at i==0 where g_0 is never consumed).
  float* gcur = g0b;
  float* gnxt = g1b;
  for (int i = NLAY - 1; i >= 0; i--) {
    const u16* l2p = wp + ((size_t)(i*3 + 1) << 14);
    const u16* bwp = wp + ((size_t)(i*3 + 2) << 14);
    const unsigned* Tl = T + (size_t)i * NN * HD;

    if (i == NLAY - 1) {
      bhead2_f_k<<<NB16, 256, 0, stream>>>(nullptr, nullptr, nullptr, gcur,
                                           bwp, (const u16*)svb[i], l2p,
                                           (u16*)dgb, nullptr, N_ATOMS);
    } else {
      const u16* l1nx = wp + ((size_t)((i+1)*3 + 0) << 14);
      float* gout = (i > 0) ? gnxt : nullptr;
      bhead2_f_k<<<NB16, 256, 0, stream>>>(agg, l1nx, gcur, nullptr,
                                           bwp, (const u16*)svb[i], l2p,
                                           (u16*)dgb, gout, N_ATOMS);
      if (i > 0) { float* tmp = gcur; gcur = gnxt; gnxt = tmp; }
    }
    gath_bwd_k<<<AB, 256, 0, stream>>>(permr, rptr, rpk2, Tl,
                                       (const unsigned*)dgb,
                                       (const unsigned*)hxb[i], agg, ddslot,
                                       i != NLAY - 1, i != 0, hstep, inv_h);
  }

  forceg_k<<<(N_ATOMS * 8 + 255) / 256, 256, 0, stream>>>(
      rptr, rpk2, cptr, cpk2, cslot, ddslot, pos, out + NMOL, hstep);
}

// Round 11
// 753.121 us; speedup vs baseline: 1.0450x; 1.0113x over previous
//
#include <hip/hip_runtime.h>

#define HD 128

constexpr int N_ATOMS = 20000;
constexpr int N_EDGES = 320000;
constexpr int NLAY   = 4;
constexpr int NMOL   = 200;
constexpr float FCUT  = 5.0f;
constexpr float DELTA = FCUT / 127.0f;
constexpr float GCOEFF = -0.5f / (DELTA * DELTA);
constexpr float PI_F  = 3.14159265358979323846f;
constexpr float LN2F  = 0.6931471805599453f;

typedef unsigned short u16;
typedef __attribute__((ext_vector_type(8))) short short8v;
typedef __attribute__((ext_vector_type(4))) float f32x4;

__device__ __forceinline__ float sspf(float x) {
  return fmaxf(x, 0.0f) + log1pf(expf(-fabsf(x))) - LN2F;
}
__device__ __forceinline__ float sigmf(float x) {
  return 1.0f / (1.0f + expf(-x));
}

// bf16 pack/unpack (round-to-nearest-even)
__device__ __forceinline__ unsigned bfpack(float a, float b) {
  unsigned ua = __float_as_uint(a);
  unsigned ub = __float_as_uint(b);
  ua = (ua + 0x7FFFu + ((ua >> 16) & 1u)) >> 16;
  ub = (ub + 0x7FFFu + ((ub >> 16) & 1u)) >> 16;
  return (ub << 16) | ua;
}
__device__ __forceinline__ float bflo(unsigned p) { return __uint_as_float(p << 16); }
__device__ __forceinline__ float bfhi(unsigned p) { return __uint_as_float(p & 0xFFFF0000u); }
__device__ __forceinline__ u16 f2bf(float x) {
  unsigned u = __float_as_uint(x);
  u = (u + 0x7FFFu + ((u >> 16) & 1u)) >> 16;
  return (u16)u;
}
__device__ __forceinline__ float bf2f(u16 b) { return __uint_as_float((unsigned)b << 16); }

// split f32 into hi bf16 (truncate) + lo bf16, packed u32 (hi<<16 | lo)
__device__ __forceinline__ unsigned packhl(float s) {
  unsigned hs = __float_as_uint(s) & 0xffff0000u;
  float lo = s - __uint_as_float(hs);
  return hs | (__float_as_uint(lo) >> 16);
}

// two f32 bit patterns -> hi-pair uint and lo-pair uint (bf16 pairs)
__device__ __forceinline__ unsigned hpair_f32(unsigned a, unsigned b, unsigned& lopair) {
  unsigned ha = a & 0xffff0000u, hb = b & 0xffff0000u;
  float la = __uint_as_float(a) - __uint_as_float(ha);
  float lb = __uint_as_float(b) - __uint_as_float(hb);
  lopair = (__float_as_uint(lb) & 0xffff0000u) | (__float_as_uint(la) >> 16);
  return hb | (ha >> 16);
}

// ------------------------------------------------------------------
// small elementwise kernels
// ------------------------------------------------------------------

__global__ __launch_bounds__(256) void h0_k(
    const float* __restrict__ emb, const int* __restrict__ z,
    float* __restrict__ h0)
{
  int i = blockIdx.x * 256 + threadIdx.x;
  if (i >= N_ATOMS * HD) return;
  int n = i >> 7, k = i & 127;
  h0[i] = emb[z[n] * HD + k];
}

// bf16 weight prep:
//  wsel 0..2 (lin1,lin2,blk): wp = bf16(W) row-major, wt = bf16(W^T)
//  wsel 3..4 (mlp_w1,mlp_w2): mt = bf16(W^T) only
__global__ __launch_bounds__(256) void wprep_k(
    const float* __restrict__ l1, const float* __restrict__ l2,
    const float* __restrict__ bw, const float* __restrict__ mw1,
    const float* __restrict__ mw2,
    u16* __restrict__ wt, u16* __restrict__ wp, u16* __restrict__ mt)
{
  int i = blockIdx.x * 256 + threadIdx.x;
  if (i >= NLAY * 5 * HD * HD) return;
  int e = i & (HD * HD - 1);
  int wl = i >> 14;
  int wsel = wl % 5;
  int lay = wl / 5;
  const float* W;
  if      (wsel == 0) W = l1;
  else if (wsel == 1) W = l2;
  else if (wsel == 2) W = bw;
  else if (wsel == 3) W = mw1;
  else                W = mw2;
  W += (size_t)lay * HD * HD;
  u16 b = f2bf(W[e]);
  int k = e >> 7, n = e & 127;
  if (wsel < 3) {
    size_t base = (size_t)(lay * 3 + wsel) << 14;
    wp[base + e] = b;
    wt[base + (size_t)n * HD + k] = b;
  } else {
    size_t base = (size_t)(lay * 2 + (wsel - 3)) << 14;
    mt[base + (size_t)n * HD + k] = b;
  }
}

// head weight prep: hw1 [128][64] -> hw1t [64][128] (transposed, stride HD)
// and hw1b [128][64] (row-major, stride 64), both bf16
__global__ __launch_bounds__(256) void hprep_k(
    const float* __restrict__ hw1, u16* __restrict__ hw1t,
    u16* __restrict__ hw1b)
{
  int e = blockIdx.x * 256 + threadIdx.x;
  if (e >= HD * 64) return;
  int k = e >> 6, n = e & 63;
  u16 b = f2bf(hw1[e]);
  hw1b[e] = b;
  hw1t[(size_t)n * HD + k] = b;
}

// ------------------------------------------------------------------
// CSR build: combined histogram, dual scan (+degree histogram), scatter
// ------------------------------------------------------------------
__global__ __launch_bounds__(256) void histboth_k(
    const int* __restrict__ row, const int* __restrict__ col,
    int* __restrict__ cntR, int* __restrict__ cntC)
{
  int e = blockIdx.x * 256 + threadIdx.x;
  if (e >= N_EDGES) return;
  atomicAdd(&cntC[col[e]], 1);
  atomicAdd(&cntR[row[e]], 1);
}

// block 0: cnt0 -> cptr,cur0,binc ; block 1: cnt1 -> rptr,cur1,binr
__global__ __launch_bounds__(256) void scan2_k(
    const int* __restrict__ cnt0, const int* __restrict__ cnt1,
    int* __restrict__ cptr, int* __restrict__ rptr,
    int* __restrict__ cur0, int* __restrict__ cur1,
    int* __restrict__ binc, int* __restrict__ binr)
{
  constexpr int CH = 80;  // 256*80 = 20480 >= 20001
  __shared__ int part[256];
  __shared__ int lh[256];
  const int* cnt = blockIdx.x == 0 ? cnt0 : cnt1;
  int* ptr = blockIdx.x == 0 ? cptr : rptr;
  int* cur = blockIdx.x == 0 ? cur0 : cur1;
  int* bin = blockIdx.x == 0 ? binc : binr;
  int t = threadIdx.x;
  lh[t] = 0;
  int base = t * CH;
  int v[CH];
  if (base + CH <= N_ATOMS) {
#pragma unroll
    for (int i = 0; i < CH / 4; i++) {
      int4 q = *(const int4*)(cnt + base + i * 4);
      v[4*i+0] = q.x; v[4*i+1] = q.y; v[4*i+2] = q.z; v[4*i+3] = q.w;
    }
  } else {
#pragma unroll
    for (int i = 0; i < CH; i++)
      v[i] = (base + i < N_ATOMS) ? cnt[base + i] : 0;
  }
  __syncthreads();
#pragma unroll
  for (int i = 0; i < CH; i++)
    if (base + i < N_ATOMS) atomicAdd(&lh[255 - min(v[i], 255)], 1);
  int s = 0;
#pragma unroll
  for (int i = 0; i < CH; i++) s += v[i];
  part[t] = s;
  __syncthreads();
  bin[t] = lh[t];
  for (int off = 1; off < 256; off <<= 1) {
    int u = (t >= off) ? part[t - off] : 0;
    __syncthreads();
    part[t] += u;
    __syncthreads();
  }
  int run = part[t] - s;
#pragma unroll
  for (int i = 0; i < CH; i++) {
    int idx = base + i;
    if (idx < N_ATOMS) { ptr[idx] = run; cur[idx] = run; }
    else if (idx == N_ATOMS) ptr[idx] = run;
    run += v[i];
  }
}

// geometry + both-direction CSR scatter; stores packed {other|i0<<16, t}
__global__ __launch_bounds__(256) void scatboth_k(
    const float* __restrict__ pos, const int* __restrict__ row,
    const int* __restrict__ col, int* __restrict__ cur0,
    int* __restrict__ cur1, uint2* __restrict__ cpk2,
    uint2* __restrict__ rpk2, int* __restrict__ cslot, float inv_h)
{
  int e = blockIdx.x * 256 + threadIdx.x;
  if (e >= N_EDGES) return;
  int r = row[e], c = col[e];
  float dx = pos[3*r+0] - pos[3*c+0];
  float dy = pos[3*r+1] - pos[3*c+1];
  float dz = pos[3*r+2] - pos[3*c+2];
  float d = sqrtf(dx*dx + dy*dy + dz*dz);
  float fi = d * inv_h;
  int i0 = (int)fi;
  float t = fi - (float)i0;
  unsigned pk = (unsigned)c | ((unsigned)i0 << 16);
  unsigned tu = __float_as_uint(t);
  int pr = atomicAdd(&cur1[r], 1);
  rpk2[pr] = make_uint2(pk, tu);
  int pc = atomicAdd(&cur0[c], 1);
  cpk2[pc] = make_uint2((unsigned)r | ((unsigned)i0 << 16), tu);
  cslot[pc] = pr;
}

// ------------------------------------------------------------------
// degree-sort permutation (descending)
// ------------------------------------------------------------------
__global__ __launch_bounds__(256) void dscan_k(
    int* __restrict__ binc, int* __restrict__ binr)
{
  int* bin = blockIdx.x == 0 ? binc : binr;
  __shared__ int sh[256];
  int t = threadIdx.x;
  int v = bin[t];
  sh[t] = v;
  __syncthreads();
  for (int off = 1; off < 256; off <<= 1) {
    int u = (t >= off) ? sh[t - off] : 0;
    __syncthreads();
    sh[t] += u;
    __syncthreads();
  }
  bin[t] = sh[t] - v;   // exclusive prefix
}

__global__ __launch_bounds__(256) void dscat_k(
    const int* __restrict__ cptr, const int* __restrict__ rptr,
    int* __restrict__ binc, int* __restrict__ binr,
    int* __restrict__ permc, int* __restrict__ permr)
{
  __shared__ int lhc[256], lhr[256], lbc[256], lbr[256];
  int t = threadIdx.x;
  lhc[t] = 0; lhr[t] = 0;
  __syncthreads();
  int a = blockIdx.x * 256 + t;
  int bc = 0, br = 0, rc = 0, rr = 0;
  bool valid = a < N_ATOMS;
  if (valid) {
    int dc = cptr[a+1] - cptr[a];
    int dr = rptr[a+1] - rptr[a];
    bc = 255 - min(dc, 255);
    br = 255 - min(dr, 255);
    rc = atomicAdd(&lhc[bc], 1);
    rr = atomicAdd(&lhr[br], 1);
  }
  __syncthreads();
  if (lhc[t] > 0) lbc[t] = atomicAdd(&binc[t], lhc[t]);
  if (lhr[t] > 0) lbr[t] = atomicAdd(&binr[t], lhr[t]);
  __syncthreads();
  if (valid) {
    permc[lbc[bc] + rc] = a;
    permr[lbr[br] + rr] = a;
  }
}

// ------------------------------------------------------------------
// table build
// ------------------------------------------------------------------
__global__ __launch_bounds__(256) void nodeA_k(
    float* __restrict__ A, float* __restrict__ dA, int nnode, float hstep)
{
  int i = blockIdx.x * 256 + threadIdx.x;
  if (i >= nnode * HD) return;
  int node = i >> 7, g = i & 127;
  float d = (float)node * hstep;
  float t = d - (float)g * DELTA;
  float a = expf(GCOEFF * t * t);
  A[i] = a;
  dA[i] = a * 2.0f * GCOEFF * t;
}

__global__ __launch_bounds__(256) void nodeact_k(
    const float* __restrict__ t1, const float* __restrict__ u,
    float* __restrict__ s, float* __restrict__ sp, int total)
{
  int i = blockIdx.x * 256 + threadIdx.x;
  if (i >= total) return;
  float x = t1[i];
  s[i] = sspf(x);
  sp[i] = sigmf(x) * u[i];
}

__global__ __launch_bounds__(256) void nodecomb_k(
    const float* __restrict__ P0, const float* __restrict__ D0,
    unsigned* __restrict__ T, int nnode, float hstep)
{
  int i = blockIdx.x * 256 + threadIdx.x;
  int total = NLAY * nnode * HD;
  if (i >= total) return;
  int rem = i % (nnode * HD);
  int node = rem >> 7;
  float d = (float)node * hstep;
  float C  = 0.5f * cosf(d * (PI_F / FCUT)) + 0.5f;
  float Cp = -0.5f * sinf(d * (PI_F / FCUT)) * (PI_F / FCUT);
  float p = P0[i], q = D0[i];
  T[i] = bfpack(p * C, q * C + p * Cp);
}

// ------------------------------------------------------------------
// no-LDS MFMA wave GEMM: wave computes rows [m0,m0+16) x cols
// [wbase,wbase+32) of C = A[M,128] @ B[128,ncols]. Bt stride = HD.
// ------------------------------------------------------------------
__device__ __forceinline__ void wave_mm(
    const float* __restrict__ Av, const u16* __restrict__ Bt,
    int m0, int wbase, int lc, int lg, int mclamp, f32x4 acc[2])
{
  short8v bfr[4][2];
#pragma unroll
  for (int ks = 0; ks < 4; ++ks)
#pragma unroll
    for (int nt = 0; nt < 2; ++nt)
      bfr[ks][nt] = *(const short8v*)(Bt + (size_t)(wbase + nt*16 + lc) * HD + ks*32 + lg*8);
  int ar = m0 + lc;
  if (ar > mclamp) ar = mclamp;   // row-clamped load; garbage rows never stored
  f32x4 z = {0.f, 0.f, 0.f, 0.f};
  acc[0] = z; acc[1] = z;
#pragma unroll
  for (int ks = 0; ks < 4; ++ks) {
    const float* p = Av + (size_t)ar * HD + ks*32 + lg*8;
    uint4 u0 = *(const uint4*)p;
    uint4 u1 = *(const uint4*)(p + 4);
    unsigned p0l, p1l, p2l, p3l;
    unsigned p0h = hpair_f32(u0.x, u0.y, p0l);
    unsigned p1h = hpair_f32(u0.z, u0.w, p1l);
    unsigned p2h = hpair_f32(u1.x, u1.y, p2l);
    unsigned p3h = hpair_f32(u1.z, u1.w, p3l);
    uint4 hv = make_uint4(p0h, p1h, p2h, p3h);
    uint4 lv = make_uint4(p0l, p1l, p2l, p3l);
    short8v ah = *(short8v*)&hv, al = *(short8v*)&lv;
    acc[0] = __builtin_amdgcn_mfma_f32_16x16x32_bf16(ah, bfr[ks][0], acc[0], 0, 0, 0);
    acc[1] = __builtin_amdgcn_mfma_f32_16x16x32_bf16(ah, bfr[ks][1], acc[1], 0, 0, 0);
    acc[0] = __builtin_amdgcn_mfma_f32_16x16x32_bf16(al, bfr[ks][0], acc[0], 0, 0, 0);
    acc[1] = __builtin_amdgcn_mfma_f32_16x16x32_bf16(al, bfr[ks][1], acc[1], 0, 0, 0);
  }
}

// same, A from LDS tile of packed (hi16|lo16) u32, rows [16][132]
__device__ __forceinline__ void wave_mm_lds(
    const unsigned (*__restrict__ Sl)[132], const u16* __restrict__ Bt,
    int wbase, int lc, int lg, f32x4 acc[2])
{
  short8v bfr[4][2];
#pragma unroll
  for (int ks = 0; ks < 4; ++ks)
#pragma unroll
    for (int nt = 0; nt < 2; ++nt)
      bfr[ks][nt] = *(const short8v*)(Bt + (size_t)(wbase + nt*16 + lc) * HD + ks*32 + lg*8);
  f32x4 z = {0.f, 0.f, 0.f, 0.f};
  acc[0] = z; acc[1] = z;
#pragma unroll
  for (int ks = 0; ks < 4; ++ks) {
    uint4 u0 = *(const uint4*)&Sl[lc][ks*32 + lg*8];
    uint4 u1 = *(const uint4*)&Sl[lc][ks*32 + lg*8 + 4];
    uint4 hv = make_uint4(
      (u0.y & 0xffff0000u) | (u0.x >> 16),
      (u0.w & 0xffff0000u) | (u0.z >> 16),
      (u1.y & 0xffff0000u) | (u1.x >> 16),
      (u1.w & 0xffff0000u) | (u1.z >> 16));
    uint4 lv = make_uint4(
      (u0.y << 16) | (u0.x & 0xffffu),
      (u0.w << 16) | (u0.z & 0xffffu),
      (u1.y << 16) | (u1.x & 0xffffu),
      (u1.w << 16) | (u1.z & 0xffffu));
    short8v ah = *(short8v*)&hv, al = *(short8v*)&lv;
    acc[0] = __builtin_amdgcn_mfma_f32_16x16x32_bf16(ah, bfr[ks][0], acc[0], 0, 0, 0);
    acc[1] = __builtin_amdgcn_mfma_f32_16x16x32_bf16(ah, bfr[ks][1], acc[1], 0, 0, 0);
    acc[0] = __builtin_amdgcn_mfma_f32_16x16x32_bf16(al, bfr[ks][0], acc[0], 0, 0, 0);
    acc[1] = __builtin_amdgcn_mfma_f32_16x16x32_bf16(al, bfr[ks][1], acc[1], 0, 0, 0);
  }
}

// hx = h @ W  (Bt = W^T bf16), output u16 bf16  (layer 0 only)
__global__ __launch_bounds__(256) void nmm_hx_k(
    const float* __restrict__ h, const u16* __restrict__ Bt,
    u16* __restrict__ hx, int M)
{
  int t = threadIdx.x, lane = t & 63;
  int lc = lane & 15, lg = lane >> 4;
  int wbase = (t >> 6) * 32;
  int m0 = blockIdx.x * 16;
  f32x4 acc[2];
  wave_mm(h, Bt, m0, wbase, lc, lg, M - 1, acc);
#pragma unroll
  for (int nt = 0; nt < 2; ++nt) {
    int ccol = wbase + nt*16 + lc;
#pragma unroll
    for (int j = 0; j < 4; ++j) {
      int grow = m0 + lg*4 + j;
      if (grow < M) hx[(size_t)grow * HD + ccol] = f2bf(acc[nt][j]);
    }
  }
}

// fused fwd tail: V = agg@l2 + l2b; svb = bf16(sigm(V));
// hout = h + ssp(V)@bw + bb; optional hxn = bf16(hout @ l1next)
__global__ __launch_bounds__(256) void ftail_f_k(
    const float* __restrict__ agg, const u16* __restrict__ l2t,
    const float* __restrict__ l2b, const u16* __restrict__ bwt,
    const float* __restrict__ bb, const float* __restrict__ h,
    u16* __restrict__ svb, float* __restrict__ hout,
    const u16* __restrict__ l1n, u16* __restrict__ hxn, int M)
{
  __shared__ unsigned Sl[16][132];
  int t = threadIdx.x, lane = t & 63;
  int lc = lane & 15, lg = lane >> 4;
  int wbase = (t >> 6) * 32;
  int m0 = blockIdx.x * 16;
  f32x4 acc[2];
  wave_mm(agg, l2t, m0, wbase, lc, lg, M - 1, acc);
#pragma unroll
  for (int nt = 0; nt < 2; ++nt) {
    int ccol = wbase + nt*16 + lc;
    float bv = l2b[ccol];
#pragma unroll
    for (int j = 0; j < 4; ++j) {
      int lrow = lg*4 + j;
      int grow = m0 + lrow;
      float s = 0.0f;
      if (grow < M) {
        float x = acc[nt][j] + bv;
        svb[(size_t)grow * HD + ccol] = f2bf(sigmf(x));
        s = sspf(x);
      }
      Sl[lrow][ccol] = packhl(s);
    }
  }
  __syncthreads();
  wave_mm_lds(Sl, bwt, wbase, lc, lg, acc);

  float ho[2][4];
#pragma unroll
  for (int nt = 0; nt < 2; ++nt) {
    int ccol = wbase + nt*16 + lc;
    float bv = bb[ccol];
#pragma unroll
    for (int j = 0; j < 4; ++j) {
      int grow = m0 + lg*4 + j;
      float x = 0.0f;
      if (grow < M) {
        x = acc[nt][j] + bv + h[(size_t)grow * HD + ccol];
        hout[(size_t)grow * HD + ccol] = x;
      }
      ho[nt][j] = x;
    }
  }
  if (l1n) {
    __syncthreads();   // all waves done reading Sl (bw pass)
#pragma unroll
    for (int nt = 0; nt < 2; ++nt) {
      int ccol = wbase + nt*16 + lc;
#pragma unroll
      for (int j = 0; j < 4; ++j)
        Sl[lg*4 + j][ccol] = packhl(ho[nt][j]);
    }
    __syncthreads();
    wave_mm_lds(Sl, l1n, wbase, lc, lg, acc);
#pragma unroll
    for (int nt = 0; nt < 2; ++nt) {
      int ccol = wbase + nt*16 + lc;
#pragma unroll
      for (int j = 0; j < 4; ++j) {
        int grow = m0 + lg*4 + j;
        if (grow < M) hxn[(size_t)grow * HD + ccol] = f2bf(acc[nt][j]);
      }
    }
  }
}

// fused bwd head, optionally with the previous layer's bwdT GEMM folded in
__global__ __launch_bounds__(256) void bhead2_f_k(
    const float* __restrict__ aggprev, const u16* __restrict__ l1prev,
    const float* __restrict__ gadd, const float* __restrict__ gdirect,
    const u16* __restrict__ bwp, const u16* __restrict__ svb,
    const u16* __restrict__ l2p, u16* __restrict__ dagg,
    float* __restrict__ gout, int M)
{
  __shared__ unsigned Sl[16][132];
  int t = threadIdx.x, lane = t & 63;
  int lc = lane & 15, lg = lane >> 4;
  int wbase = (t >> 6) * 32;
  int m0 = blockIdx.x * 16;
  f32x4 acc[2];
  if (aggprev) {
    wave_mm(aggprev, l1prev, m0, wbase, lc, lg, M - 1, acc);
#pragma unroll
    for (int nt = 0; nt < 2; ++nt) {
      int ccol = wbase + nt*16 + lc;
#pragma unroll
      for (int j = 0; j < 4; ++j) {
        int lrow = lg*4 + j;
        int grow = m0 + lrow;
        float x = 0.0f;
        if (grow < M) {
          x = acc[nt][j] + gadd[(size_t)grow * HD + ccol];
          if (gout) gout[(size_t)grow * HD + ccol] = x;
        }
        Sl[lrow][ccol] = packhl(x);
      }
    }
    __syncthreads();
    wave_mm_lds(Sl, bwp, wbase, lc, lg, acc);
    __syncthreads();   // all waves done reading g before dv overwrites Sl
  } else {
    wave_mm(gdirect, bwp, m0, wbase, lc, lg, M - 1, acc);
  }
  // dv = acc * sigm(V), pack into Sl
#pragma unroll
  for (int nt = 0; nt < 2; ++nt) {
    int ccol = wbase + nt*16 + lc;
#pragma unroll
    for (int j = 0; j < 4; ++j) {
      int lrow = lg*4 + j;
      int grow = m0 + lrow;
      float dv = 0.0f;
      if (grow < M)
        dv = acc[nt][j] * bf2f(svb[(size_t)grow * HD + ccol]);
      Sl[lrow][ccol] = packhl(dv);
    }
  }
  __syncthreads();
  wave_mm_lds(Sl, l2p, wbase, lc, lg, acc);
#pragma unroll
  for (int nt = 0; nt < 2; ++nt) {
    int ccol = wbase + nt*16 + lc;
#pragma unroll
    for (int j = 0; j < 4; ++j) {
      int grow = m0 + lg*4 + j;
      if (grow < M) dagg[(size_t)grow * HD + ccol] = f2bf(acc[nt][j]);
    }
  }
}

// batched table-build GEMM; blockIdx.z selects (A0,bias0,C0) or (A1,null,C1)
__global__ __launch_bounds__(256) void tblmm2_k(
    const float* __restrict__ A0, const float* __restrict__ A1, size_t astride,
    const u16* __restrict__ Bt, size_t bstride,
    const float* __restrict__ bias0, size_t biasstride,
    float* __restrict__ C0, float* __restrict__ C1, size_t cstride, int M)
{
  int l = blockIdx.y;
  int zz = blockIdx.z;
  const float* A = (zz ? A1 : A0) + (size_t)l * astride;
  const u16* B = Bt + (size_t)l * bstride;
  const float* bias = zz ? nullptr : (bias0 ? bias0 + (size_t)l * biasstride : nullptr);
  float* C = (zz ? C1 : C0) + (size_t)l * cstride;
  int t = threadIdx.x, lane = t & 63;
  int lc = lane & 15, lg = lane >> 4;
  int wbase = (t >> 6) * 32;
  int m0 = blockIdx.x * 16;
  f32x4 acc[2];
  wave_mm(A, B, m0, wbase, lc, lg, M - 1, acc);
#pragma unroll
  for (int nt = 0; nt < 2; ++nt) {
    int ccol = wbase + nt*16 + lc;
    float bv = bias ? bias[ccol] : 0.0f;
#pragma unroll
    for (int j = 0; j < 4; ++j) {
      int grow = m0 + lg*4 + j;
      if (grow < M) C[(size_t)grow * HD + ccol] = acc[nt][j] + bv;
    }
  }
}

// ------------------------------------------------------------------
// MFMA fused head: 32 rows/block, 4 waves.
// Phase1: s = h4@hw1 + hb1 (K=128, 64 cols); wave w -> rows (w>>1)*16,
//         cols (w&1)*32 via wave_mm (hw1t stride HD).
// ea[m] = ssp(s)@hw2 + hb2 (LDS reduce).
// Phase2: gh = (sigm(s)*hw2) @ hw1^T (K=64, 128 cols); wave w -> rows
//         (w>>1)*16, cols (w&1)*64 (4 col-tiles), A from packed LDS.
// ------------------------------------------------------------------
__global__ __launch_bounds__(256) void headf_mfma_k(
    const float* __restrict__ h4, const u16* __restrict__ hw1t,
    const float* __restrict__ hb1, const float* __restrict__ hw2f,
    const u16* __restrict__ hw1b, const float* __restrict__ hb2,
    float* __restrict__ ea, float* __restrict__ gh, int M)
{
  __shared__ unsigned Sl[32][68];
  __shared__ float spd[32][68];
  int t = threadIdx.x, lane = t & 63, w = t >> 6;
  int lc = lane & 15, lg = lane >> 4;
  int rowh = w >> 1;
  int m0 = blockIdx.x * 32 + rowh * 16;
  int wbase = (w & 1) * 32;
  f32x4 acc[2];
  wave_mm(h4, hw1t, m0, wbase, lc, lg, M - 1, acc);
#pragma unroll
  for (int nt = 0; nt < 2; ++nt) {
    int ccol = wbase + nt*16 + lc;
    float b1 = hb1[ccol], w2 = hw2f[ccol];
#pragma unroll
    for (int j = 0; j < 4; ++j) {
      int lrow = rowh*16 + lg*4 + j;
      float x = acc[nt][j] + b1;
      Sl[lrow][ccol] = packhl(sigmf(x) * w2);
      spd[lrow][ccol] = sspf(x) * w2;
    }
  }
  __syncthreads();
  if (t < 32) {
    int gm = blockIdx.x * 32 + t;
    if (gm < M) {
      float s = hb2[0];
#pragma unroll
      for (int j = 0; j < 64; ++j) s += spd[t][j];
      ea[gm] = s;
    }
  }
  // phase 2: K=64, 4 col-tiles per wave, A row = rowh*16 + lc
  int cb = (w & 1) * 64;
  short8v bfr[2][4];
#pragma unroll
  for (int ks = 0; ks < 2; ++ks)
#pragma unroll
    for (int nt = 0; nt < 4; ++nt)
      bfr[ks][nt] = *(const short8v*)(hw1b + (size_t)(cb + nt*16 + lc) * 64 + ks*32 + lg*8);
  f32x4 z = {0.f, 0.f, 0.f, 0.f};
  f32x4 acc4[4];
#pragma unroll
  for (int nt = 0; nt < 4; ++nt) acc4[nt] = z;
#pragma unroll
  for (int ks = 0; ks < 2; ++ks) {
    uint4 u0 = *(const uint4*)&Sl[rowh*16 + lc][ks*32 + lg*8];
    uint4 u1 = *(const uint4*)&Sl[rowh*16 + lc][ks*32 + lg*8 + 4];
    uint4 hv = make_uint4(
      (u0.y & 0xffff0000u) | (u0.x >> 16),
      (u0.w & 0xffff0000u) | (u0.z >> 16),
      (u1.y & 0xffff0000u) | (u1.x >> 16),
      (u1.w & 0xffff0000u) | (u1.z >> 16));
    uint4 lv = make_uint4(
      (u0.y << 16) | (u0.x & 0xffffu),
      (u0.w << 16) | (u0.z & 0xffffu),
      (u1.y << 16) | (u1.x & 0xffffu),
      (u1.w << 16) | (u1.z & 0xffffu));
    short8v ah = *(short8v*)&hv, al = *(short8v*)&lv;
#pragma unroll
    for (int nt = 0; nt < 4; ++nt) {
      acc4[nt] = __builtin_amdgcn_mfma_f32_16x16x32_bf16(ah, bfr[ks][nt], acc4[nt], 0, 0, 0);
      acc4[nt] = __builtin_amdgcn_mfma_f32_16x16x32_bf16(al, bfr[ks][nt], acc4[nt], 0, 0, 0);
    }
  }
#pragma unroll
  for (int nt = 0; nt < 4; ++nt) {
    int ccol = cb + nt*16 + lc;
#pragma unroll
    for (int j = 0; j < 4; ++j) {
      int grow = m0 + lg*4 + j;
      if (grow < M) gh[(size_t)grow * HD + ccol] = acc4[nt][j];
    }
  }
}

// ------------------------------------------------------------------
// forward gather: agg[a] = sum_in hx[src] * P(d); coeffs from (i0,t)
// ------------------------------------------------------------------
__global__ __launch_bounds__(256) void gath_fwd_k(
    const int* __restrict__ perm, const int* __restrict__ cptr,
    const uint2* __restrict__ cpk2, const unsigned* __restrict__ T,
    const unsigned* __restrict__ hx, float* __restrict__ agg, float hstep)
{
  int ai = blockIdx.x * 4 + (threadIdx.x >> 6);
  if (ai >= N_ATOMS) return;
  int a = perm[ai];
  int half = (threadIdx.x >> 5) & 1;
  int l32 = threadIdx.x & 31;
  int ch = l32 * 4;
  int beg = cptr[a], end = cptr[a + 1];
  float s0 = 0.f, s1 = 0.f, s2 = 0.f, s3 = 0.f;
#pragma unroll 2
  for (int j = beg + half; j < end; j += 2) {
    uint2 pk2 = cpk2[j];
    float t = __uint_as_float(pk2.y);
    int other = pk2.x & 0xffffu;
    float t2 = t * t, t3 = t2 * t;
    float cx = 2.f*t3 - 3.f*t2 + 1.f;
    float cy = (t3 - 2.f*t2 + t) * hstep;
    float cz = 3.f*t2 - 2.f*t3;
    float cw = (t3 - t2) * hstep;
    const unsigned* tp = T + (size_t)(pk2.x >> 16) * HD + ch;
    uint4 q0 = *(const uint4*)(tp);
    uint4 q1 = *(const uint4*)(tp + HD);
    uint2 hp = *(const uint2*)(hx + (size_t)other * 64 + l32 * 2);
    float v0 = cx*bflo(q0.x) + cy*bfhi(q0.x) + cz*bflo(q1.x) + cw*bfhi(q1.x);
    float v1 = cx*bflo(q0.y) + cy*bfhi(q0.y) + cz*bflo(q1.y) + cw*bfhi(q1.y);
    float v2 = cx*bflo(q0.z) + cy*bfhi(q0.z) + cz*bflo(q1.z) + cw*bfhi(q1.z);
    float v3 = cx*bflo(q0.w) + cy*bfhi(q0.w) + cz*bflo(q1.w) + cw*bfhi(q1.w);
    s0 = fmaf(bflo(hp.x), v0, s0);
    s1 = fmaf(bfhi(hp.x), v1, s1);
    s2 = fmaf(bflo(hp.y), v2, s2);
    s3 = fmaf(bfhi(hp.y), v3, s3);
  }
  s0 += __shfl_xor(s0, 32, 64);
  s1 += __shfl_xor(s1, 32, 64);
  s2 += __shfl_xor(s2, 32, 64);
  s3 += __shfl_xor(s3, 32, 64);
  if (half == 0)
    *(float4*)(agg + (size_t)a * HD + ch) = make_float4(s0, s1, s2, s3);
}

// ------------------------------------------------------------------
// backward gather: ddslot (write on first layer, else +=);
// dhx only when need_dhx (dead at the last backward layer)
// ------------------------------------------------------------------
__global__ __launch_bounds__(256) void gath_bwd_k(
    const int* __restrict__ perm, const int* __restrict__ rptr,
    const uint2* __restrict__ rpk2, const unsigned* __restrict__ T,
    const unsigned* __restrict__ dagg, const unsigned* __restrict__ hx,
    float* __restrict__ dhx, float* __restrict__ ddslot, int accum,
    int need_dhx, float hstep, float inv_h)
{
  int ai = blockIdx.x * 4 + (threadIdx.x >> 6);
  if (ai >= N_ATOMS) return;
  int a = perm[ai];
  int half = (threadIdx.x >> 5) & 1;
  int l32 = threadIdx.x & 31;
  int ch = l32 * 4;
  int beg = rptr[a], end = rptr[a + 1];
  uint2 hp = *(const uint2*)(hx + (size_t)a * 64 + l32 * 2);
  float h0 = bflo(hp.x), h1 = bfhi(hp.x), h2 = bflo(hp.y), h3 = bfhi(hp.y);
  float s0 = 0.f, s1 = 0.f, s2 = 0.f, s3 = 0.f;
#pragma unroll 2
  for (int j = beg + half; j < end; j += 2) {
    uint2 pk2 = rpk2[j];
    float t = __uint_as_float(pk2.y);
    int other = pk2.x & 0xffffu;
    float t2 = t * t, t3 = t2 * t;
    float cbx = (6.f*t2 - 6.f*t) * inv_h;
    float cby = 3.f*t2 - 4.f*t + 1.f;
    float cbz = -cbx;
    float cbw = 3.f*t2 - 2.f*t;
    const unsigned* tp = T + (size_t)(pk2.x >> 16) * HD + ch;
    uint4 q0 = *(const uint4*)(tp);
    uint4 q1 = *(const uint4*)(tp + HD);
    uint2 dp = *(const uint2*)(dagg + (size_t)other * 64 + l32 * 2);
    float da0 = bflo(dp.x), da1 = bfhi(dp.x), da2 = bflo(dp.y), da3 = bfhi(dp.y);
    float x0l = bflo(q0.x), x0h = bfhi(q0.x), y0l = bflo(q1.x), y0h = bfhi(q1.x);
    float x1l = bflo(q0.y), x1h = bfhi(q0.y), y1l = bflo(q1.y), y1h = bfhi(q1.y);
    float x2l = bflo(q0.z), x2h = bfhi(q0.z), y2l = bflo(q1.z), y2h = bfhi(q1.z);
    float x3l = bflo(q0.w), x3h = bfhi(q0.w), y3l = bflo(q1.w), y3h = bfhi(q1.w);
    float g0 = cbx*x0l + cby*x0h + cbz*y0l + cbw*y0h;
    float g1 = cbx*x1l + cby*x1h + cbz*y1l + cbw*y1h;
    float g2 = cbx*x2l + cby*x2h + cbz*y2l + cbw*y2h;
    float g3 = cbx*x3l + cby*x3h + cbz*y3l + cbw*y3h;
    float dah0 = da0*h0, dah1 = da1*h1, dah2 = da2*h2, dah3 = da3*h3;
    float dot = dah0*g0;
    dot = fmaf(dah1, g1, dot);
    dot = fmaf(dah2, g2, dot);
    dot = fmaf(dah3, g3, dot);
#pragma unroll
    for (int off = 16; off > 0; off >>= 1) dot += __shfl_down(dot, off, 32);
    if (l32 == 0) ddslot[j] = accum ? (ddslot[j] + dot) : dot;
    if (need_dhx) {
      float cax = 2.f*t3 - 3.f*t2 + 1.f;
      float cay = (t3 - 2.f*t2 + t) * hstep;
      float caz = 3.f*t2 - 2.f*t3;
      float caw = (t3 - t2) * hstep;
      float v0 = cax*x0l + cay*x0h + caz*y0l + caw*y0h;
      float v1 = cax*x1l + cay*x1h + caz*y1l + caw*y1h;
      float v2 = cax*x2l + cay*x2h + caz*y2l + caw*y2h;
      float v3 = cax*x3l + cay*x3h + caz*y3l + caw*y3h;
      s0 = fmaf(da0, v0, s0);
      s1 = fmaf(da1, v1, s1);
      s2 = fmaf(da2, v2, s2);
      s3 = fmaf(da3, v3, s3);
    }
  }
  if (need_dhx) {
    s0 += __shfl_xor(s0, 32, 64);
    s1 += __shfl_xor(s1, 32, 64);
    s2 += __shfl_xor(s2, 32, 64);
    s3 += __shfl_xor(s3, 32, 64);
    if (half == 0)
      *(float4*)(dhx + (size_t)a * HD + ch) = make_float4(s0, s1, s2, s3);
  }
}

// ------------------------------------------------------------------
// per-molecule energy reduction
// ------------------------------------------------------------------
__global__ __launch_bounds__(64) void ered_k(
    const int* __restrict__ batch, const float* __restrict__ ea,
    float* __restrict__ energy)
{
  int m = blockIdx.x;
  int lo = 0, hi = N_ATOMS;
  while (lo < hi) { int mid = (lo + hi) >> 1; if (batch[mid] < m) lo = mid + 1; else hi = mid; }
  int beg = lo;
  lo = beg; hi = N_ATOMS;
  while (lo < hi) { int mid = (lo + hi) >> 1; if (batch[mid] < m + 1) lo = mid + 1; else hi = mid; }
  int end = lo;
  float s = 0.0f;
  for (int i = beg + threadIdx.x; i < end; i += 64) s += ea[i];
#pragma unroll
  for (int off = 32; off > 0; off >>= 1) s += __shfl_down(s, off, 64);
  if (threadIdx.x == 0) energy[m] = s;
}

// ------------------------------------------------------------------
// force gather; distance reconstructed from pk2: d = (i0 + t) * hstep
// ------------------------------------------------------------------
__global__ __launch_bounds__(256) void forceg_k(
    const int* __restrict__ rptr, const uint2* __restrict__ rpk2,
    const int* __restrict__ cptr, const uint2* __restrict__ cpk2,
    const int* __restrict__ cslot, const float* __restrict__ ddslot,
    const float* __restrict__ pos, float* __restrict__ force, float hstep)
{
  int idx = blockIdx.x * 256 + threadIdx.x;
  int a = idx >> 3;
  int g = idx & 7;
  if (a >= N_ATOMS) return;
  float px = pos[3*a+0], py = pos[3*a+1], pz = pos[3*a+2];
  float fx = 0.f, fy = 0.f, fz = 0.f;
  int beg = rptr[a], end = rptr[a+1];
  for (int j = beg + g; j < end; j += 8) {
    uint2 p = rpk2[j];
    int o = p.x & 0xffffu;
    float d = ((float)(p.x >> 16) + __uint_as_float(p.y)) * hstep;
    float w = ddslot[j] / d;
    fx -= w * (px - pos[3*o+0]);
    fy -= w * (py - pos[3*o+1]);
    fz -= w * (pz - pos[3*o+2]);
  }
  beg = cptr[a]; end = cptr[a+1];
  for (int j = beg + g; j < end; j += 8) {
    uint2 p = cpk2[j];
    int o = p.x & 0xffffu;
    float d = ((float)(p.x >> 16) + __uint_as_float(p.y)) * hstep;
    float w = ddslot[cslot[j]] / d;
    fx -= w * (px - pos[3*o+0]);
    fy -= w * (py - pos[3*o+1]);
    fz -= w * (pz - pos[3*o+2]);
  }
#pragma unroll
  for (int off = 4; off > 0; off >>= 1) {
    fx += __shfl_down(fx, off, 8);
    fy += __shfl_down(fy, off, 8);
    fz += __shfl_down(fz, off, 8);
  }
  if (g == 0) {
    force[3*a+0] = fx;
    force[3*a+1] = fy;
    force[3*a+2] = fz;
  }
}

// ------------------------------------------------------------------
// host launch
// ------------------------------------------------------------------
static inline int nblk(int m) { return (m + 63) / 64; }

extern "C" void kernel_launch(void* const* d_in, const int* in_sizes, int n_in,
                              void* d_out, int out_size, void* d_ws, size_t ws_size,
                              hipStream_t stream)
{
  const float* pos   = (const float*)d_in[0];
  const int*   z     = (const int*)d_in[1];
  const int*   batch = (const int*)d_in[2];
  const int*   eidx  = (const int*)d_in[3];
  const float* emb   = (const float*)d_in[4];
  const float* mlp_w1 = (const float*)d_in[5];
  const float* mlp_b1 = (const float*)d_in[6];
  const float* mlp_w2 = (const float*)d_in[7];
  const float* mlp_b2 = (const float*)d_in[8];
  const float* lin1_w = (const float*)d_in[9];
  const float* lin2_w = (const float*)d_in[10];
  const float* lin2_b = (const float*)d_in[11];
  const float* blk_w  = (const float*)d_in[12];
  const float* blk_b  = (const float*)d_in[13];
  const float* hw1 = (const float*)d_in[14];
  const float* hb1 = (const float*)d_in[15];
  const float* hw2 = (const float*)d_in[16];
  const float* hb2 = (const float*)d_in[17];

  float* out = (float*)d_out;          // [NMOL] energies ++ [N,3] forces
  float* ws  = (float*)d_ws;

  const int* row = eidx;
  const int* col = eidx + N_EDGES;

  const size_t NH = (size_t)N_ATOMS * HD;
  size_t o = 0;
  float* ddslot = ws + o; o += N_EDGES;
  int* cptr = (int*)(ws + o); o += N_ATOMS + 1;
  int* rptr = (int*)(ws + o); o += N_ATOMS + 1;
  int* cnt0 = (int*)(ws + o); o += N_ATOMS;      // cnt0,cnt1 contiguous:
  int* cnt1 = (int*)(ws + o); o += N_ATOMS;      // one memset
  int* binc = (int*)(ws + o); o += 256;
  int* binr = (int*)(ws + o); o += 256;
  int* cur0 = (int*)(ws + o); o += N_ATOMS;
  int* cur1 = (int*)(ws + o); o += N_ATOMS;
  int* permc = (int*)(ws + o); o += N_ATOMS;
  int* permr = (int*)(ws + o); o += N_ATOMS;
  int* cslot = (int*)(ws + o); o += N_EDGES;
  o = (o + 1) & ~(size_t)1;                      // 8B align for uint2
  uint2* cpk2 = (uint2*)(ws + o); o += (size_t)2 * N_EDGES;
  uint2* rpk2 = (uint2*)(ws + o); o += (size_t)2 * N_EDGES;
  // bf16 weights: wt = transposed, wp = plain, mt = transposed mlp weights
  u16* wt = (u16*)(ws + o); o += (size_t)NLAY * 3 * HD * HD / 2;
  u16* wp = (u16*)(ws + o); o += (size_t)NLAY * 3 * HD * HD / 2;
  u16* mt = (u16*)(ws + o); o += (size_t)NLAY * 2 * HD * HD / 2;
  u16* hw1t = (u16*)(ws + o); o += (size_t)HD * 64 / 2;   // [64][128] bf16
  u16* hw1b = (u16*)(ws + o); o += (size_t)HD * 64 / 2;   // [128][64] bf16
  float* hxb[4];   // bf16 (128 u16 per row) -> NH/2 floats each
  for (int i = 0; i < 4; i++) { hxb[i] = ws + o; o += NH / 2; }
  float* svb[4];   // bf16 sigm(V) -> NH/2 floats each
  for (int i = 0; i < 4; i++) { svb[i] = ws + o; o += NH / 2; }
  float* hA  = ws + o; o += NH;
  float* hB  = ws + o; o += NH;
  float* agg = ws + o; o += NH;       // fwd agg / bwd dhx / table temps
  float* g0b = ws + o; o += NH;
  float* g1b = ws + o; o += NH;
  float* dgb = ws + o; o += NH / 2;   // dagg(bf16) / ea / table temps

  // table: bf16 pairs {P*C, (P*C)'}, 1 uint per (node,ch)
  int NT = 1024;
  while (NT > 128) {
    size_t need = o + (size_t)NLAY * (NT + 1) * HD;
    if (need * sizeof(float) <= ws_size) break;
    NT >>= 1;
  }
  const int NN = NT + 1;
  const float hstep = FCUT / (float)NT;
  const float inv_h = (float)NT / FCUT;
  unsigned* T = (unsigned*)(ws + o); o += (size_t)NLAY * NN * HD;

  const int EB = (N_EDGES + 255) / 256;
  const int ABK = (N_ATOMS + 255) / 256;

  hipMemsetAsync(cnt0, 0, 2 * N_ATOMS * sizeof(int), stream);

  wprep_k<<<(NLAY * 5 * HD * HD + 255) / 256, 256, 0, stream>>>(
      lin1_w, lin2_w, blk_w, mlp_w1, mlp_w2, wt, wp, mt);
  hprep_k<<<(HD * 64 + 255) / 256, 256, 0, stream>>>(hw1, hw1t, hw1b);

  // ---------------- CSR build (both directions) ----------------
  histboth_k<<<EB, 256, 0, stream>>>(row, col, cnt1, cnt0);
  scan2_k<<<2, 256, 0, stream>>>(cnt0, cnt1, cptr, rptr, cur0, cur1, binc, binr);
  scatboth_k<<<EB, 256, 0, stream>>>(pos, row, col, cur0, cur1, cpk2, rpk2,
                                     cslot, inv_h);

  // ---------------- degree-sort perms for gather balance ----------------
  dscan_k<<<2, 256, 0, stream>>>(binc, binr);
  dscat_k<<<ABK, 256, 0, stream>>>(cptr, rptr, binc, binr, permc, permr);

  // ---------------- build filter tables (all 4 layers) ----------------
  {
    const size_t LNH = (size_t)NN * HD;
    float* Anode  = agg;
    float* dAnode = agg + LNH;
    float* t1 = dgb;
    float* u  = g0b;
    float* s  = g1b;
    float* sp = hA;
    nodeA_k<<<((int)LNH + 255) / 256, 256, 0, stream>>>(Anode, dAnode, NN, hstep);
    dim3 gB16((NN + 15) / 16, NLAY, 2);
    tblmm2_k<<<gB16, 256, 0, stream>>>(Anode, dAnode, 0, mt, 32768,
                                       mlp_b1, HD, t1, u, LNH, NN);
    int tot = (int)(NLAY * LNH);
    nodeact_k<<<(tot + 255) / 256, 256, 0, stream>>>(t1, u, s, sp, tot);
    float* P0 = dgb;
    float* D0 = g0b;
    tblmm2_k<<<gB16, 256, 0, stream>>>(s, sp, LNH, mt + 16384, 32768,
                                       mlp_b2, HD, P0, D0, LNH, NN);
    nodecomb_k<<<(tot + 255) / 256, 256, 0, stream>>>(P0, D0, T, NN, hstep);
  }

  h0_k<<<(N_ATOMS * HD + 255) / 256, 256, 0, stream>>>(emb, z, hA);

  const int AB = (N_ATOMS + 3) / 4;
  const int NB16 = (N_ATOMS + 15) / 16;   // 1250 blocks for no-LDS MFMA GEMMs
  const int HB = (N_ATOMS + 31) / 32;     // 625 blocks for the MFMA head

  // ---------------- forward ----------------
  float* hcur = hA;
  float* hnxt = hB;
  nmm_hx_k<<<NB16, 256, 0, stream>>>(hcur, wt, (u16*)hxb[0], N_ATOMS);
  for (int i = 0; i < NLAY; i++) {
    const u16* l2t = wt + ((size_t)(i*3 + 1) << 14);
    const u16* bwt = wt + ((size_t)(i*3 + 2) << 14);
    const u16* l1n = (i < NLAY - 1) ? wt + ((size_t)((i+1)*3 + 0) << 14) : nullptr;
    u16* hxn = (i < NLAY - 1) ? (u16*)hxb[i+1] : nullptr;
    const float* l2bi = lin2_b + (size_t)i * HD;
    const float* bbi  = blk_b + (size_t)i * HD;
    const unsigned* Tl = T + (size_t)i * NN * HD;

    gath_fwd_k<<<AB, 256, 0, stream>>>(permc, cptr, cpk2, Tl,
                                       (const unsigned*)hxb[i], agg, hstep);
    ftail_f_k<<<NB16, 256, 0, stream>>>(agg, l2t, l2bi, bwt, bbi, hcur,
                                        (u16*)svb[i], hnxt, l1n, hxn, N_ATOMS);
    float* tmp = hcur; hcur = hnxt; hnxt = tmp;
  }

  // ---------------- head (MFMA fused) + per-molecule energy ----------------
  // NLAY even -> hcur == hA here
  float* ea = dgb;
  headf_mfma_k<<<HB, 256, 0, stream>>>(hcur, hw1t, hb1, hw2, hw1b, hb2,
                                       ea, g0b, N_ATOMS);
  ered_k<<<NMOL, 64, 0, stream>>>(batch, ea, out);

  // ---------------- backward ----------------
  // g_3 = gh (g0b). For i < 3 the bwdT GEMM of layer i+1 is fused into
  // bhead2: g_i = agg(dhx_{i+1}) @ l1_{i+1}^T + g_{i+1}, stored to gnxt
  // (except at i==0 where g_0 is never consumed).
  float* gcur = g0b;
  float* gnxt = g1b;
  for (int i = NLAY - 1; i >= 0; i--) {
    const u16* l2p = wp + ((size_t)(i*3 + 1) << 14);
    const u16* bwp = wp + ((size_t)(i*3 + 2) << 14);
    const unsigned* Tl = T + (size_t)i * NN * HD;

    if (i == NLAY - 1) {
      bhead2_f_k<<<NB16, 256, 0, stream>>>(nullptr, nullptr, nullptr, gcur,
                                           bwp, (const u16*)svb[i], l2p,
                                           (u16*)dgb, nullptr, N_ATOMS);
    } else {
      const u16* l1nx = wp + ((size_t)((i+1)*3 + 0) << 14);
      float* gout = (i > 0) ? gnxt : nullptr;
      bhead2_f_k<<<NB16, 256, 0, stream>>>(agg, l1nx, gcur, nullptr,
                                           bwp, (const u16*)svb[i], l2p,
                                           (u16*)dgb, gout, N_ATOMS);
      if (i > 0) { float* tmp = gcur; gcur = gnxt; gnxt = tmp; }
    }
    gath_bwd_k<<<AB, 256, 0, stream>>>(permr, rptr, rpk2, Tl,
                                       (const unsigned*)dgb,
                                       (const unsigned*)hxb[i], agg, ddslot,
                                       i != NLAY - 1, i != 0, hstep, inv_h);
  }

  forceg_k<<<(N_ATOMS * 8 + 255) / 256, 256, 0, stream>>>(
      rptr, rpk2, cptr, cpk2, cslot, ddslot, pos, out + NMOL, hstep);
}

// Round 12
// 749.236 us; speedup vs baseline: 1.0504x; 1.0052x over previous
//
#include <hip/hip_runtime.h>

#define HD 128

constexpr int N_ATOMS = 20000;
constexpr int N_EDGES = 320000;
constexpr int NLAY   = 4;
constexpr int NMOL   = 200;
constexpr float FCUT  = 5.0f;
constexpr float DELTA = FCUT / 127.0f;
constexpr float GCOEFF = -0.5f / (DELTA * DELTA);
constexpr float PI_F  = 3.14159265358979323846f;
constexpr float LN2F  = 0.6931471805599453f;

typedef unsigned short u16;
typedef __attribute__((ext_vector_type(8))) short short8v;
typedef __attribute__((ext_vector_type(4))) float f32x4;

__device__ __forceinline__ float sspf(float x) {
  return fmaxf(x, 0.0f) + log1pf(expf(-fabsf(x))) - LN2F;
}
__device__ __forceinline__ float sigmf(float x) {
  return 1.0f / (1.0f + expf(-x));
}

// bf16 pack/unpack (round-to-nearest-even)
__device__ __forceinline__ unsigned bfpack(float a, float b) {
  unsigned ua = __float_as_uint(a);
  unsigned ub = __float_as_uint(b);
  ua = (ua + 0x7FFFu + ((ua >> 16) & 1u)) >> 16;
  ub = (ub + 0x7FFFu + ((ub >> 16) & 1u)) >> 16;
  return (ub << 16) | ua;
}
__device__ __forceinline__ float bflo(unsigned p) { return __uint_as_float(p << 16); }
__device__ __forceinline__ float bfhi(unsigned p) { return __uint_as_float(p & 0xFFFF0000u); }
__device__ __forceinline__ u16 f2bf(float x) {
  unsigned u = __float_as_uint(x);
  u = (u + 0x7FFFu + ((u >> 16) & 1u)) >> 16;
  return (u16)u;
}
__device__ __forceinline__ float bf2f(u16 b) { return __uint_as_float((unsigned)b << 16); }

// split f32 into hi bf16 (truncate) + lo bf16, packed u32 (hi<<16 | lo)
__device__ __forceinline__ unsigned packhl(float s) {
  unsigned hs = __float_as_uint(s) & 0xffff0000u;
  float lo = s - __uint_as_float(hs);
  return hs | (__float_as_uint(lo) >> 16);
}

// two f32 bit patterns -> hi-pair uint and lo-pair uint (bf16 pairs)
__device__ __forceinline__ unsigned hpair_f32(unsigned a, unsigned b, unsigned& lopair) {
  unsigned ha = a & 0xffff0000u, hb = b & 0xffff0000u;
  float la = __uint_as_float(a) - __uint_as_float(ha);
  float lb = __uint_as_float(b) - __uint_as_float(hb);
  lopair = (__float_as_uint(lb) & 0xffff0000u) | (__float_as_uint(la) >> 16);
  return hb | (ha >> 16);
}

// ------------------------------------------------------------------
// small elementwise kernels
// ------------------------------------------------------------------

__global__ __launch_bounds__(256) void h0_k(
    const float* __restrict__ emb, const int* __restrict__ z,
    float* __restrict__ h0)
{
  int i = blockIdx.x * 256 + threadIdx.x;
  if (i >= N_ATOMS * HD) return;
  int n = i >> 7, k = i & 127;
  h0[i] = emb[z[n] * HD + k];
}

// bf16 weight prep:
//  wsel 0..2 (lin1,lin2,blk): wp = bf16(W) row-major, wt = bf16(W^T)
//  wsel 3..4 (mlp_w1,mlp_w2): mt = bf16(W^T) only
//  tail range: head weights hw1 -> hw1t (transposed) + hw1b (row-major)
__global__ __launch_bounds__(256) void wprep_k(
    const float* __restrict__ l1, const float* __restrict__ l2,
    const float* __restrict__ bw, const float* __restrict__ mw1,
    const float* __restrict__ mw2, const float* __restrict__ hw1,
    u16* __restrict__ wt, u16* __restrict__ wp, u16* __restrict__ mt,
    u16* __restrict__ hw1t, u16* __restrict__ hw1b)
{
  int i = blockIdx.x * 256 + threadIdx.x;
  const int NW = NLAY * 5 * HD * HD;
  if (i < NW) {
    int e = i & (HD * HD - 1);
    int wl = i >> 14;
    int wsel = wl % 5;
    int lay = wl / 5;
    const float* W;
    if      (wsel == 0) W = l1;
    else if (wsel == 1) W = l2;
    else if (wsel == 2) W = bw;
    else if (wsel == 3) W = mw1;
    else                W = mw2;
    W += (size_t)lay * HD * HD;
    u16 b = f2bf(W[e]);
    int k = e >> 7, n = e & 127;
    if (wsel < 3) {
      size_t base = (size_t)(lay * 3 + wsel) << 14;
      wp[base + e] = b;
      wt[base + (size_t)n * HD + k] = b;
    } else {
      size_t base = (size_t)(lay * 2 + (wsel - 3)) << 14;
      mt[base + (size_t)n * HD + k] = b;
    }
  } else {
    int e = i - NW;
    if (e >= HD * 64) return;
    int k = e >> 6, n = e & 63;
    u16 b = f2bf(hw1[e]);
    hw1b[e] = b;
    hw1t[(size_t)n * HD + k] = b;
  }
}

// ------------------------------------------------------------------
// CSR build: combined histogram, dual scan (+degree-bin exclusive
// prefix fused in), scatter
// ------------------------------------------------------------------
__global__ __launch_bounds__(256) void histboth_k(
    const int* __restrict__ row, const int* __restrict__ col,
    int* __restrict__ cntR, int* __restrict__ cntC)
{
  int e = blockIdx.x * 256 + threadIdx.x;
  if (e >= N_EDGES) return;
  atomicAdd(&cntC[col[e]], 1);
  atomicAdd(&cntR[row[e]], 1);
}

// block 0: cnt0 -> cptr,cur0,binc ; block 1: cnt1 -> rptr,cur1,binr
// bins written as EXCLUSIVE PREFIX directly (dscan fused)
__global__ __launch_bounds__(256) void scan2_k(
    const int* __restrict__ cnt0, const int* __restrict__ cnt1,
    int* __restrict__ cptr, int* __restrict__ rptr,
    int* __restrict__ cur0, int* __restrict__ cur1,
    int* __restrict__ binc, int* __restrict__ binr)
{
  constexpr int CH = 80;  // 256*80 = 20480 >= 20001
  __shared__ int part[256];
  __shared__ int lh[256];
  __shared__ int lp[256];
  const int* cnt = blockIdx.x == 0 ? cnt0 : cnt1;
  int* ptr = blockIdx.x == 0 ? cptr : rptr;
  int* cur = blockIdx.x == 0 ? cur0 : cur1;
  int* bin = blockIdx.x == 0 ? binc : binr;
  int t = threadIdx.x;
  lh[t] = 0;
  int base = t * CH;
  int v[CH];
  if (base + CH <= N_ATOMS) {
#pragma unroll
    for (int i = 0; i < CH / 4; i++) {
      int4 q = *(const int4*)(cnt + base + i * 4);
      v[4*i+0] = q.x; v[4*i+1] = q.y; v[4*i+2] = q.z; v[4*i+3] = q.w;
    }
  } else {
#pragma unroll
    for (int i = 0; i < CH; i++)
      v[i] = (base + i < N_ATOMS) ? cnt[base + i] : 0;
  }
  __syncthreads();   // lh zeroed before atomics
#pragma unroll
  for (int i = 0; i < CH; i++)
    if (base + i < N_ATOMS) atomicAdd(&lh[255 - min(v[i], 255)], 1);
  int s = 0;
#pragma unroll
  for (int i = 0; i < CH; i++) s += v[i];
  part[t] = s;
  __syncthreads();   // lh atomics + part writes complete
  // bins: inclusive prefix over lh, store exclusive
  lp[t] = lh[t];
  __syncthreads();
  for (int off = 1; off < 256; off <<= 1) {
    int u = (t >= off) ? lp[t - off] : 0;
    __syncthreads();
    lp[t] += u;
    __syncthreads();
  }
  bin[t] = lp[t] - lh[t];
  // atom-count prefix
  for (int off = 1; off < 256; off <<= 1) {
    int u = (t >= off) ? part[t - off] : 0;
    __syncthreads();
    part[t] += u;
    __syncthreads();
  }
  int run = part[t] - s;
#pragma unroll
  for (int i = 0; i < CH; i++) {
    int idx = base + i;
    if (idx < N_ATOMS) { ptr[idx] = run; cur[idx] = run; }
    else if (idx == N_ATOMS) ptr[idx] = run;
    run += v[i];
  }
}

// geometry + both-direction CSR scatter; stores packed {other|i0<<16, t}
__global__ __launch_bounds__(256) void scatboth_k(
    const float* __restrict__ pos, const int* __restrict__ row,
    const int* __restrict__ col, int* __restrict__ cur0,
    int* __restrict__ cur1, uint2* __restrict__ cpk2,
    uint2* __restrict__ rpk2, int* __restrict__ cslot, float inv_h)
{
  int e = blockIdx.x * 256 + threadIdx.x;
  if (e >= N_EDGES) return;
  int r = row[e], c = col[e];
  float dx = pos[3*r+0] - pos[3*c+0];
  float dy = pos[3*r+1] - pos[3*c+1];
  float dz = pos[3*r+2] - pos[3*c+2];
  float d = sqrtf(dx*dx + dy*dy + dz*dz);
  float fi = d * inv_h;
  int i0 = (int)fi;
  float t = fi - (float)i0;
  unsigned pk = (unsigned)c | ((unsigned)i0 << 16);
  unsigned tu = __float_as_uint(t);
  int pr = atomicAdd(&cur1[r], 1);
  rpk2[pr] = make_uint2(pk, tu);
  int pc = atomicAdd(&cur0[c], 1);
  cpk2[pc] = make_uint2((unsigned)r | ((unsigned)i0 << 16), tu);
  cslot[pc] = pr;
}

__global__ __launch_bounds__(256) void dscat_k(
    const int* __restrict__ cptr, const int* __restrict__ rptr,
    int* __restrict__ binc, int* __restrict__ binr,
    int* __restrict__ permc, int* __restrict__ permr)
{
  __shared__ int lhc[256], lhr[256], lbc[256], lbr[256];
  int t = threadIdx.x;
  lhc[t] = 0; lhr[t] = 0;
  __syncthreads();
  int a = blockIdx.x * 256 + t;
  int bc = 0, br = 0, rc = 0, rr = 0;
  bool valid = a < N_ATOMS;
  if (valid) {
    int dc = cptr[a+1] - cptr[a];
    int dr = rptr[a+1] - rptr[a];
    bc = 255 - min(dc, 255);
    br = 255 - min(dr, 255);
    rc = atomicAdd(&lhc[bc], 1);
    rr = atomicAdd(&lhr[br], 1);
  }
  __syncthreads();
  if (lhc[t] > 0) lbc[t] = atomicAdd(&binc[t], lhc[t]);
  if (lhr[t] > 0) lbr[t] = atomicAdd(&binr[t], lhr[t]);
  __syncthreads();
  if (valid) {
    permc[lbc[bc] + rc] = a;
    permr[lbr[br] + rr] = a;
  }
}

// ------------------------------------------------------------------
// table build
// ------------------------------------------------------------------
__global__ __launch_bounds__(256) void nodeA_k(
    float* __restrict__ A, float* __restrict__ dA, int nnode, float hstep)
{
  int i = blockIdx.x * 256 + threadIdx.x;
  if (i >= nnode * HD) return;
  int node = i >> 7, g = i & 127;
  float d = (float)node * hstep;
  float t = d - (float)g * DELTA;
  float a = expf(GCOEFF * t * t);
  A[i] = a;
  dA[i] = a * 2.0f * GCOEFF * t;
}

// ------------------------------------------------------------------
// no-LDS MFMA wave GEMM: wave computes rows [m0,m0+16) x cols
// [wbase,wbase+32) of C = A[M,128] @ B[128,ncols]. Bt stride = HD.
// ------------------------------------------------------------------
__device__ __forceinline__ void wave_mm(
    const float* __restrict__ Av, const u16* __restrict__ Bt,
    int m0, int wbase, int lc, int lg, int mclamp, f32x4 acc[2])
{
  short8v bfr[4][2];
#pragma unroll
  for (int ks = 0; ks < 4; ++ks)
#pragma unroll
    for (int nt = 0; nt < 2; ++nt)
      bfr[ks][nt] = *(const short8v*)(Bt + (size_t)(wbase + nt*16 + lc) * HD + ks*32 + lg*8);
  int ar = m0 + lc;
  if (ar > mclamp) ar = mclamp;   // row-clamped load; garbage rows never stored
  f32x4 z = {0.f, 0.f, 0.f, 0.f};
  acc[0] = z; acc[1] = z;
#pragma unroll
  for (int ks = 0; ks < 4; ++ks) {
    const float* p = Av + (size_t)ar * HD + ks*32 + lg*8;
    uint4 u0 = *(const uint4*)p;
    uint4 u1 = *(const uint4*)(p + 4);
    unsigned p0l, p1l, p2l, p3l;
    unsigned p0h = hpair_f32(u0.x, u0.y, p0l);
    unsigned p1h = hpair_f32(u0.z, u0.w, p1l);
    unsigned p2h = hpair_f32(u1.x, u1.y, p2l);
    unsigned p3h = hpair_f32(u1.z, u1.w, p3l);
    uint4 hv = make_uint4(p0h, p1h, p2h, p3h);
    uint4 lv = make_uint4(p0l, p1l, p2l, p3l);
    short8v ah = *(short8v*)&hv, al = *(short8v*)&lv;
    acc[0] = __builtin_amdgcn_mfma_f32_16x16x32_bf16(ah, bfr[ks][0], acc[0], 0, 0, 0);
    acc[1] = __builtin_amdgcn_mfma_f32_16x16x32_bf16(ah, bfr[ks][1], acc[1], 0, 0, 0);
    acc[0] = __builtin_amdgcn_mfma_f32_16x16x32_bf16(al, bfr[ks][0], acc[0], 0, 0, 0);
    acc[1] = __builtin_amdgcn_mfma_f32_16x16x32_bf16(al, bfr[ks][1], acc[1], 0, 0, 0);
  }
}

// dual-A variant: two A streams share the once-loaded B fragments
__device__ __forceinline__ void wave_mm2(
    const float* __restrict__ A0v, const float* __restrict__ A1v,
    const u16* __restrict__ Bt, int m0, int wbase, int lc, int lg,
    int mclamp, f32x4 acc0[2], f32x4 acc1[2])
{
  short8v bfr[4][2];
#pragma unroll
  for (int ks = 0; ks < 4; ++ks)
#pragma unroll
    for (int nt = 0; nt < 2; ++nt)
      bfr[ks][nt] = *(const short8v*)(Bt + (size_t)(wbase + nt*16 + lc) * HD + ks*32 + lg*8);
  int ar = m0 + lc;
  if (ar > mclamp) ar = mclamp;
  f32x4 z = {0.f, 0.f, 0.f, 0.f};
  acc0[0] = z; acc0[1] = z; acc1[0] = z; acc1[1] = z;
#pragma unroll
  for (int ks = 0; ks < 4; ++ks) {
#pragma unroll
    for (int which = 0; which < 2; ++which) {
      const float* p = (which ? A1v : A0v) + (size_t)ar * HD + ks*32 + lg*8;
      uint4 u0 = *(const uint4*)p;
      uint4 u1 = *(const uint4*)(p + 4);
      unsigned p0l, p1l, p2l, p3l;
      unsigned p0h = hpair_f32(u0.x, u0.y, p0l);
      unsigned p1h = hpair_f32(u0.z, u0.w, p1l);
      unsigned p2h = hpair_f32(u1.x, u1.y, p2l);
      unsigned p3h = hpair_f32(u1.z, u1.w, p3l);
      uint4 hv = make_uint4(p0h, p1h, p2h, p3h);
      uint4 lv = make_uint4(p0l, p1l, p2l, p3l);
      short8v ah = *(short8v*)&hv, al = *(short8v*)&lv;
      f32x4* acc = which ? acc1 : acc0;
      acc[0] = __builtin_amdgcn_mfma_f32_16x16x32_bf16(ah, bfr[ks][0], acc[0], 0, 0, 0);
      acc[1] = __builtin_amdgcn_mfma_f32_16x16x32_bf16(ah, bfr[ks][1], acc[1], 0, 0, 0);
      acc[0] = __builtin_amdgcn_mfma_f32_16x16x32_bf16(al, bfr[ks][0], acc[0], 0, 0, 0);
      acc[1] = __builtin_amdgcn_mfma_f32_16x16x32_bf16(al, bfr[ks][1], acc[1], 0, 0, 0);
    }
  }
}

// same, A from LDS tile of packed (hi16|lo16) u32, rows [16][132]
__device__ __forceinline__ void wave_mm_lds(
    const unsigned (*__restrict__ Sl)[132], const u16* __restrict__ Bt,
    int wbase, int lc, int lg, f32x4 acc[2])
{
  short8v bfr[4][2];
#pragma unroll
  for (int ks = 0; ks < 4; ++ks)
#pragma unroll
    for (int nt = 0; nt < 2; ++nt)
      bfr[ks][nt] = *(const short8v*)(Bt + (size_t)(wbase + nt*16 + lc) * HD + ks*32 + lg*8);
  f32x4 z = {0.f, 0.f, 0.f, 0.f};
  acc[0] = z; acc[1] = z;
#pragma unroll
  for (int ks = 0; ks < 4; ++ks) {
    uint4 u0 = *(const uint4*)&Sl[lc][ks*32 + lg*8];
    uint4 u1 = *(const uint4*)&Sl[lc][ks*32 + lg*8 + 4];
    uint4 hv = make_uint4(
      (u0.y & 0xffff0000u) | (u0.x >> 16),
      (u0.w & 0xffff0000u) | (u0.z >> 16),
      (u1.y & 0xffff0000u) | (u1.x >> 16),
      (u1.w & 0xffff0000u) | (u1.z >> 16));
    uint4 lv = make_uint4(
      (u0.y << 16) | (u0.x & 0xffffu),
      (u0.w << 16) | (u0.z & 0xffffu),
      (u1.y << 16) | (u1.x & 0xffffu),
      (u1.w << 16) | (u1.z & 0xffffu));
    short8v ah = *(short8v*)&hv, al = *(short8v*)&lv;
    acc[0] = __builtin_amdgcn_mfma_f32_16x16x32_bf16(ah, bfr[ks][0], acc[0], 0, 0, 0);
    acc[1] = __builtin_amdgcn_mfma_f32_16x16x32_bf16(ah, bfr[ks][1], acc[1], 0, 0, 0);
    acc[0] = __builtin_amdgcn_mfma_f32_16x16x32_bf16(al, bfr[ks][0], acc[0], 0, 0, 0);
    acc[1] = __builtin_amdgcn_mfma_f32_16x16x32_bf16(al, bfr[ks][1], acc[1], 0, 0, 0);
  }
}

// table pass A: t1 = Anode@w1 + b1 (via w1^T), u = dAnode@w1;
// epilogue (fused nodeact): s = ssp(t1), sp = sigm(t1)*u
__global__ __launch_bounds__(256) void tblA_k(
    const float* __restrict__ Anode, const float* __restrict__ dAnode,
    const u16* __restrict__ mt, const float* __restrict__ mlp_b1,
    float* __restrict__ s, float* __restrict__ sp, int nn)
{
  int l = blockIdx.y;
  const u16* B = mt + (size_t)l * 32768;
  const float* b1 = mlp_b1 + (size_t)l * HD;
  float* sl  = s  + (size_t)l * nn * HD;
  float* spl = sp + (size_t)l * nn * HD;
  int t = threadIdx.x, lane = t & 63;
  int lc = lane & 15, lg = lane >> 4;
  int wbase = (t >> 6) * 32;
  int m0 = blockIdx.x * 16;
  f32x4 a0[2], a1[2];
  wave_mm2(Anode, dAnode, B, m0, wbase, lc, lg, nn - 1, a0, a1);
#pragma unroll
  for (int nt = 0; nt < 2; ++nt) {
    int ccol = wbase + nt*16 + lc;
    float bv = b1[ccol];
#pragma unroll
    for (int j = 0; j < 4; ++j) {
      int grow = m0 + lg*4 + j;
      if (grow < nn) {
        float x = a0[nt][j] + bv;
        sl[(size_t)grow * HD + ccol]  = sspf(x);
        spl[(size_t)grow * HD + ccol] = sigmf(x) * a1[nt][j];
      }
    }
  }
}

// table pass B: P = s@w2 + b2, D = sp@w2;
// epilogue (fused nodecomb): T = pack(P*C, D*C + P*C')
__global__ __launch_bounds__(256) void tblB_k(
    const float* __restrict__ s, const float* __restrict__ sp,
    const u16* __restrict__ mt, const float* __restrict__ mlp_b2,
    unsigned* __restrict__ T, int nn, float hstep)
{
  int l = blockIdx.y;
  const u16* B = mt + (size_t)l * 32768 + 16384;
  const float* b2 = mlp_b2 + (size_t)l * HD;
  const float* sl  = s  + (size_t)l * nn * HD;
  const float* spl = sp + (size_t)l * nn * HD;
  unsigned* Tl = T + (size_t)l * nn * HD;
  int t = threadIdx.x, lane = t & 63;
  int lc = lane & 15, lg = lane >> 4;
  int wbase = (t >> 6) * 32;
  int m0 = blockIdx.x * 16;
  f32x4 a0[2], a1[2];
  wave_mm2(sl, spl, B, m0, wbase, lc, lg, nn - 1, a0, a1);
#pragma unroll
  for (int nt = 0; nt < 2; ++nt) {
    int ccol = wbase + nt*16 + lc;
    float bv = b2[ccol];
#pragma unroll
    for (int j = 0; j < 4; ++j) {
      int grow = m0 + lg*4 + j;
      if (grow < nn) {
        float d = (float)grow * hstep;
        float C  = 0.5f * cosf(d * (PI_F / FCUT)) + 0.5f;
        float Cp = -0.5f * sinf(d * (PI_F / FCUT)) * (PI_F / FCUT);
        float p = a0[nt][j] + bv;
        float q = a1[nt][j];
        Tl[(size_t)grow * HD + ccol] = bfpack(p * C, q * C + p * Cp);
      }
    }
  }
}

// hx = h @ W  (Bt = W^T bf16), output u16 bf16  (layer 0 only)
__global__ __launch_bounds__(256) void nmm_hx_k(
    const float* __restrict__ h, const u16* __restrict__ Bt,
    u16* __restrict__ hx, int M)
{
  int t = threadIdx.x, lane = t & 63;
  int lc = lane & 15, lg = lane >> 4;
  int wbase = (t >> 6) * 32;
  int m0 = blockIdx.x * 16;
  f32x4 acc[2];
  wave_mm(h, Bt, m0, wbase, lc, lg, M - 1, acc);
#pragma unroll
  for (int nt = 0; nt < 2; ++nt) {
    int ccol = wbase + nt*16 + lc;
#pragma unroll
    for (int j = 0; j < 4; ++j) {
      int grow = m0 + lg*4 + j;
      if (grow < M) hx[(size_t)grow * HD + ccol] = f2bf(acc[nt][j]);
    }
  }
}

// fused fwd tail: V = agg@l2 + l2b; svb = bf16(sigm(V));
// hout = h + ssp(V)@bw + bb; optional hxn = bf16(hout @ l1next)
__global__ __launch_bounds__(256) void ftail_f_k(
    const float* __restrict__ agg, const u16* __restrict__ l2t,
    const float* __restrict__ l2b, const u16* __restrict__ bwt,
    const float* __restrict__ bb, const float* __restrict__ h,
    u16* __restrict__ svb, float* __restrict__ hout,
    const u16* __restrict__ l1n, u16* __restrict__ hxn, int M)
{
  __shared__ unsigned Sl[16][132];
  int t = threadIdx.x, lane = t & 63;
  int lc = lane & 15, lg = lane >> 4;
  int wbase = (t >> 6) * 32;
  int m0 = blockIdx.x * 16;
  f32x4 acc[2];
  wave_mm(agg, l2t, m0, wbase, lc, lg, M - 1, acc);
#pragma unroll
  for (int nt = 0; nt < 2; ++nt) {
    int ccol = wbase + nt*16 + lc;
    float bv = l2b[ccol];
#pragma unroll
    for (int j = 0; j < 4; ++j) {
      int lrow = lg*4 + j;
      int grow = m0 + lrow;
      float s = 0.0f;
      if (grow < M) {
        float x = acc[nt][j] + bv;
        svb[(size_t)grow * HD + ccol] = f2bf(sigmf(x));
        s = sspf(x);
      }
      Sl[lrow][ccol] = packhl(s);
    }
  }
  __syncthreads();
  wave_mm_lds(Sl, bwt, wbase, lc, lg, acc);

  float ho[2][4];
#pragma unroll
  for (int nt = 0; nt < 2; ++nt) {
    int ccol = wbase + nt*16 + lc;
    float bv = bb[ccol];
#pragma unroll
    for (int j = 0; j < 4; ++j) {
      int grow = m0 + lg*4 + j;
      float x = 0.0f;
      if (grow < M) {
        x = acc[nt][j] + bv + h[(size_t)grow * HD + ccol];
        hout[(size_t)grow * HD + ccol] = x;
      }
      ho[nt][j] = x;
    }
  }
  if (l1n) {
    __syncthreads();   // all waves done reading Sl (bw pass)
#pragma unroll
    for (int nt = 0; nt < 2; ++nt) {
      int ccol = wbase + nt*16 + lc;
#pragma unroll
      for (int j = 0; j < 4; ++j)
        Sl[lg*4 + j][ccol] = packhl(ho[nt][j]);
    }
    __syncthreads();
    wave_mm_lds(Sl, l1n, wbase, lc, lg, acc);
#pragma unroll
    for (int nt = 0; nt < 2; ++nt) {
      int ccol = wbase + nt*16 + lc;
#pragma unroll
      for (int j = 0; j < 4; ++j) {
        int grow = m0 + lg*4 + j;
        if (grow < M) hxn[(size_t)grow * HD + ccol] = f2bf(acc[nt][j]);
      }
    }
  }
}

// fused bwd head, optionally with the previous layer's bwdT GEMM folded in
__global__ __launch_bounds__(256) void bhead2_f_k(
    const float* __restrict__ aggprev, const u16* __restrict__ l1prev,
    const float* __restrict__ gadd, const float* __restrict__ gdirect,
    const u16* __restrict__ bwp, const u16* __restrict__ svb,
    const u16* __restrict__ l2p, u16* __restrict__ dagg,
    float* __restrict__ gout, int M)
{
  __shared__ unsigned Sl[16][132];
  int t = threadIdx.x, lane = t & 63;
  int lc = lane & 15, lg = lane >> 4;
  int wbase = (t >> 6) * 32;
  int m0 = blockIdx.x * 16;
  f32x4 acc[2];
  if (aggprev) {
    wave_mm(aggprev, l1prev, m0, wbase, lc, lg, M - 1, acc);
#pragma unroll
    for (int nt = 0; nt < 2; ++nt) {
      int ccol = wbase + nt*16 + lc;
#pragma unroll
      for (int j = 0; j < 4; ++j) {
        int lrow = lg*4 + j;
        int grow = m0 + lrow;
        float x = 0.0f;
        if (grow < M) {
          x = acc[nt][j] + gadd[(size_t)grow * HD + ccol];
          if (gout) gout[(size_t)grow * HD + ccol] = x;
        }
        Sl[lrow][ccol] = packhl(x);
      }
    }
    __syncthreads();
    wave_mm_lds(Sl, bwp, wbase, lc, lg, acc);
    __syncthreads();   // all waves done reading g before dv overwrites Sl
  } else {
    wave_mm(gdirect, bwp, m0, wbase, lc, lg, M - 1, acc);
  }
  // dv = acc * sigm(V), pack into Sl
#pragma unroll
  for (int nt = 0; nt < 2; ++nt) {
    int ccol = wbase + nt*16 + lc;
#pragma unroll
    for (int j = 0; j < 4; ++j) {
      int lrow = lg*4 + j;
      int grow = m0 + lrow;
      float dv = 0.0f;
      if (grow < M)
        dv = acc[nt][j] * bf2f(svb[(size_t)grow * HD + ccol]);
      Sl[lrow][ccol] = packhl(dv);
    }
  }
  __syncthreads();
  wave_mm_lds(Sl, l2p, wbase, lc, lg, acc);
#pragma unroll
  for (int nt = 0; nt < 2; ++nt) {
    int ccol = wbase + nt*16 + lc;
#pragma unroll
    for (int j = 0; j < 4; ++j) {
      int grow = m0 + lg*4 + j;
      if (grow < M) dagg[(size_t)grow * HD + ccol] = f2bf(acc[nt][j]);
    }
  }
}

// ------------------------------------------------------------------
// MFMA fused head (round-11 verified)
// ------------------------------------------------------------------
__global__ __launch_bounds__(256) void headf_mfma_k(
    const float* __restrict__ h4, const u16* __restrict__ hw1t,
    const float* __restrict__ hb1, const float* __restrict__ hw2f,
    const u16* __restrict__ hw1b, const float* __restrict__ hb2,
    float* __restrict__ ea, float* __restrict__ gh, int M)
{
  __shared__ unsigned Sl[32][68];
  __shared__ float spd[32][68];
  int t = threadIdx.x, lane = t & 63, w = t >> 6;
  int lc = lane & 15, lg = lane >> 4;
  int rowh = w >> 1;
  int m0 = blockIdx.x * 32 + rowh * 16;
  int wbase = (w & 1) * 32;
  f32x4 acc[2];
  wave_mm(h4, hw1t, m0, wbase, lc, lg, M - 1, acc);
#pragma unroll
  for (int nt = 0; nt < 2; ++nt) {
    int ccol = wbase + nt*16 + lc;
    float b1 = hb1[ccol], w2 = hw2f[ccol];
#pragma unroll
    for (int j = 0; j < 4; ++j) {
      int lrow = rowh*16 + lg*4 + j;
      float x = acc[nt][j] + b1;
      Sl[lrow][ccol] = packhl(sigmf(x) * w2);
      spd[lrow][ccol] = sspf(x) * w2;
    }
  }
  __syncthreads();
  if (t < 32) {
    int gm = blockIdx.x * 32 + t;
    if (gm < M) {
      float s = hb2[0];
#pragma unroll
      for (int j = 0; j < 64; ++j) s += spd[t][j];
      ea[gm] = s;
    }
  }
  int cb = (w & 1) * 64;
  short8v bfr[2][4];
#pragma unroll
  for (int ks = 0; ks < 2; ++ks)
#pragma unroll
    for (int nt = 0; nt < 4; ++nt)
      bfr[ks][nt] = *(const short8v*)(hw1b + (size_t)(cb + nt*16 + lc) * 64 + ks*32 + lg*8);
  f32x4 z = {0.f, 0.f, 0.f, 0.f};
  f32x4 acc4[4];
#pragma unroll
  for (int nt = 0; nt < 4; ++nt) acc4[nt] = z;
#pragma unroll
  for (int ks = 0; ks < 2; ++ks) {
    uint4 u0 = *(const uint4*)&Sl[rowh*16 + lc][ks*32 + lg*8];
    uint4 u1 = *(const uint4*)&Sl[rowh*16 + lc][ks*32 + lg*8 + 4];
    uint4 hv = make_uint4(
      (u0.y & 0xffff0000u) | (u0.x >> 16),
      (u0.w & 0xffff0000u) | (u0.z >> 16),
      (u1.y & 0xffff0000u) | (u1.x >> 16),
      (u1.w & 0xffff0000u) | (u1.z >> 16));
    uint4 lv = make_uint4(
      (u0.y << 16) | (u0.x & 0xffffu),
      (u0.w << 16) | (u0.z & 0xffffu),
      (u1.y << 16) | (u1.x & 0xffffu),
      (u1.w << 16) | (u1.z & 0xffffu));
    short8v ah = *(short8v*)&hv, al = *(short8v*)&lv;
#pragma unroll
    for (int nt = 0; nt < 4; ++nt) {
      acc4[nt] = __builtin_amdgcn_mfma_f32_16x16x32_bf16(ah, bfr[ks][nt], acc4[nt], 0, 0, 0);
      acc4[nt] = __builtin_amdgcn_mfma_f32_16x16x32_bf16(al, bfr[ks][nt], acc4[nt], 0, 0, 0);
    }
  }
#pragma unroll
  for (int nt = 0; nt < 4; ++nt) {
    int ccol = cb + nt*16 + lc;
#pragma unroll
    for (int j = 0; j < 4; ++j) {
      int grow = m0 + lg*4 + j;
      if (grow < M) gh[(size_t)grow * HD + ccol] = acc4[nt][j];
    }
  }
}

// ------------------------------------------------------------------
// forward gather: agg[a] = sum_in hx[src] * P(d); coeffs from (i0,t)
// ------------------------------------------------------------------
__global__ __launch_bounds__(256) void gath_fwd_k(
    const int* __restrict__ perm, const int* __restrict__ cptr,
    const uint2* __restrict__ cpk2, const unsigned* __restrict__ T,
    const unsigned* __restrict__ hx, float* __restrict__ agg, float hstep)
{
  int ai = blockIdx.x * 4 + (threadIdx.x >> 6);
  if (ai >= N_ATOMS) return;
  int a = perm[ai];
  int half = (threadIdx.x >> 5) & 1;
  int l32 = threadIdx.x & 31;
  int ch = l32 * 4;
  int beg = cptr[a], end = cptr[a + 1];
  float s0 = 0.f, s1 = 0.f, s2 = 0.f, s3 = 0.f;
#pragma unroll 2
  for (int j = beg + half; j < end; j += 2) {
    uint2 pk2 = cpk2[j];
    float t = __uint_as_float(pk2.y);
    int other = pk2.x & 0xffffu;
    float t2 = t * t, t3 = t2 * t;
    float cx = 2.f*t3 - 3.f*t2 + 1.f;
    float cy = (t3 - 2.f*t2 + t) * hstep;
    float cz = 3.f*t2 - 2.f*t3;
    float cw = (t3 - t2) * hstep;
    const unsigned* tp = T + (size_t)(pk2.x >> 16) * HD + ch;
    uint4 q0 = *(const uint4*)(tp);
    uint4 q1 = *(const uint4*)(tp + HD);
    uint2 hp = *(const uint2*)(hx + (size_t)other * 64 + l32 * 2);
    float v0 = cx*bflo(q0.x) + cy*bfhi(q0.x) + cz*bflo(q1.x) + cw*bfhi(q1.x);
    float v1 = cx*bflo(q0.y) + cy*bfhi(q0.y) + cz*bflo(q1.y) + cw*bfhi(q1.y);
    float v2 = cx*bflo(q0.z) + cy*bfhi(q0.z) + cz*bflo(q1.z) + cw*bfhi(q1.z);
    float v3 = cx*bflo(q0.w) + cy*bfhi(q0.w) + cz*bflo(q1.w) + cw*bfhi(q1.w);
    s0 = fmaf(bflo(hp.x), v0, s0);
    s1 = fmaf(bfhi(hp.x), v1, s1);
    s2 = fmaf(bflo(hp.y), v2, s2);
    s3 = fmaf(bfhi(hp.y), v3, s3);
  }
  s0 += __shfl_xor(s0, 32, 64);
  s1 += __shfl_xor(s1, 32, 64);
  s2 += __shfl_xor(s2, 32, 64);
  s3 += __shfl_xor(s3, 32, 64);
  if (half == 0)
    *(float4*)(agg + (size_t)a * HD + ch) = make_float4(s0, s1, s2, s3);
}

// ------------------------------------------------------------------
// backward gather: ddslot (write on first layer, else +=);
// dhx only when need_dhx (dead at the last backward layer)
// ------------------------------------------------------------------
__global__ __launch_bounds__(256) void gath_bwd_k(
    const int* __restrict__ perm, const int* __restrict__ rptr,
    const uint2* __restrict__ rpk2, const unsigned* __restrict__ T,
    const unsigned* __restrict__ dagg, const unsigned* __restrict__ hx,
    float* __restrict__ dhx, float* __restrict__ ddslot, int accum,
    int need_dhx, float hstep, float inv_h)
{
  int ai = blockIdx.x * 4 + (threadIdx.x >> 6);
  if (ai >= N_ATOMS) return;
  int a = perm[ai];
  int half = (threadIdx.x >> 5) & 1;
  int l32 = threadIdx.x & 31;
  int ch = l32 * 4;
  int beg = rptr[a], end = rptr[a + 1];
  uint2 hp = *(const uint2*)(hx + (size_t)a * 64 + l32 * 2);
  float h0 = bflo(hp.x), h1 = bfhi(hp.x), h2 = bflo(hp.y), h3 = bfhi(hp.y);
  float s0 = 0.f, s1 = 0.f, s2 = 0.f, s3 = 0.f;
#pragma unroll 2
  for (int j = beg + half; j < end; j += 2) {
    uint2 pk2 = rpk2[j];
    float t = __uint_as_float(pk2.y);
    int other = pk2.x & 0xffffu;
    float t2 = t * t, t3 = t2 * t;
    float cbx = (6.f*t2 - 6.f*t) * inv_h;
    float cby = 3.f*t2 - 4.f*t + 1.f;
    float cbz = -cbx;
    float cbw = 3.f*t2 - 2.f*t;
    const unsigned* tp = T + (size_t)(pk2.x >> 16) * HD + ch;
    uint4 q0 = *(const uint4*)(tp);
    uint4 q1 = *(const uint4*)(tp + HD);
    uint2 dp = *(const uint2*)(dagg + (size_t)other * 64 + l32 * 2);
    float da0 = bflo(dp.x), da1 = bfhi(dp.x), da2 = bflo(dp.y), da3 = bfhi(dp.y);
    float x0l = bflo(q0.x), x0h = bfhi(q0.x), y0l = bflo(q1.x), y0h = bfhi(q1.x);
    float x1l = bflo(q0.y), x1h = bfhi(q0.y), y1l = bflo(q1.y), y1h = bfhi(q1.y);
    float x2l = bflo(q0.z), x2h = bfhi(q0.z), y2l = bflo(q1.z), y2h = bfhi(q1.z);
    float x3l = bflo(q0.w), x3h = bfhi(q0.w), y3l = bflo(q1.w), y3h = bfhi(q1.w);
    float g0 = cbx*x0l + cby*x0h + cbz*y0l + cbw*y0h;
    float g1 = cbx*x1l + cby*x1h + cbz*y1l + cbw*y1h;
    float g2 = cbx*x2l + cby*x2h + cbz*y2l + cbw*y2h;
    float g3 = cbx*x3l + cby*x3h + cbz*y3l + cbw*y3h;
    float dah0 = da0*h0, dah1 = da1*h1, dah2 = da2*h2, dah3 = da3*h3;
    float dot = dah0*g0;
    dot = fmaf(dah1, g1, dot);
    dot = fmaf(dah2, g2, dot);
    dot = fmaf(dah3, g3, dot);
#pragma unroll
    for (int off = 16; off > 0; off >>= 1) dot += __shfl_down(dot, off, 32);
    if (l32 == 0) ddslot[j] = accum ? (ddslot[j] + dot) : dot;
    if (need_dhx) {
      float cax = 2.f*t3 - 3.f*t2 + 1.f;
      float cay = (t3 - 2.f*t2 + t) * hstep;
      float caz = 3.f*t2 - 2.f*t3;
      float caw = (t3 - t2) * hstep;
      float v0 = cax*x0l + cay*x0h + caz*y0l + caw*y0h;
      float v1 = cax*x1l + cay*x1h + caz*y1l + caw*y1h;
      float v2 = cax*x2l + cay*x2h + caz*y2l + caw*y2h;
      float v3 = cax*x3l + cay*x3h + caz*y3l + caw*y3h;
      s0 = fmaf(da0, v0, s0);
      s1 = fmaf(da1, v1, s1);
      s2 = fmaf(da2, v2, s2);
      s3 = fmaf(da3, v3, s3);
    }
  }
  if (need_dhx) {
    s0 += __shfl_xor(s0, 32, 64);
    s1 += __shfl_xor(s1, 32, 64);
    s2 += __shfl_xor(s2, 32, 64);
    s3 += __shfl_xor(s3, 32, 64);
    if (half == 0)
      *(float4*)(dhx + (size_t)a * HD + ch) = make_float4(s0, s1, s2, s3);
  }
}

// ------------------------------------------------------------------
// per-molecule energy reduction
// ------------------------------------------------------------------
__global__ __launch_bounds__(64) void ered_k(
    const int* __restrict__ batch, const float* __restrict__ ea,
    float* __restrict__ energy)
{
  int m = blockIdx.x;
  int lo = 0, hi = N_ATOMS;
  while (lo < hi) { int mid = (lo + hi) >> 1; if (batch[mid] < m) lo = mid + 1; else hi = mid; }
  int beg = lo;
  lo = beg; hi = N_ATOMS;
  while (lo < hi) { int mid = (lo + hi) >> 1; if (batch[mid] < m + 1) lo = mid + 1; else hi = mid; }
  int end = lo;
  float s = 0.0f;
  for (int i = beg + threadIdx.x; i < end; i += 64) s += ea[i];
#pragma unroll
  for (int off = 32; off > 0; off >>= 1) s += __shfl_down(s, off, 64);
  if (threadIdx.x == 0) energy[m] = s;
}

// ------------------------------------------------------------------
// force gather; distance reconstructed from pk2: d = (i0 + t) * hstep
// ------------------------------------------------------------------
__global__ __launch_bounds__(256) void forceg_k(
    const int* __restrict__ rptr, const uint2* __restrict__ rpk2,
    const int* __restrict__ cptr, const uint2* __restrict__ cpk2,
    const int* __restrict__ cslot, const float* __restrict__ ddslot,
    const float* __restrict__ pos, float* __restrict__ force, float hstep)
{
  int idx = blockIdx.x * 256 + threadIdx.x;
  int a = idx >> 3;
  int g = idx & 7;
  if (a >= N_ATOMS) return;
  float px = pos[3*a+0], py = pos[3*a+1], pz = pos[3*a+2];
  float fx = 0.f, fy = 0.f, fz = 0.f;
  int beg = rptr[a], end = rptr[a+1];
  for (int j = beg + g; j < end; j += 8) {
    uint2 p = rpk2[j];
    int o = p.x & 0xffffu;
    float d = ((float)(p.x >> 16) + __uint_as_float(p.y)) * hstep;
    float w = ddslot[j] / d;
    fx -= w * (px - pos[3*o+0]);
    fy -= w * (py - pos[3*o+1]);
    fz -= w * (pz - pos[3*o+2]);
  }
  beg = cptr[a]; end = cptr[a+1];
  for (int j = beg + g; j < end; j += 8) {
    uint2 p = cpk2[j];
    int o = p.x & 0xffffu;
    float d = ((float)(p.x >> 16) + __uint_as_float(p.y)) * hstep;
    float w = ddslot[cslot[j]] / d;
    fx -= w * (px - pos[3*o+0]);
    fy -= w * (py - pos[3*o+1]);
    fz -= w * (pz - pos[3*o+2]);
  }
#pragma unroll
  for (int off = 4; off > 0; off >>= 1) {
    fx += __shfl_down(fx, off, 8);
    fy += __shfl_down(fy, off, 8);
    fz += __shfl_down(fz, off, 8);
  }
  if (g == 0) {
    force[3*a+0] = fx;
    force[3*a+1] = fy;
    force[3*a+2] = fz;
  }
}

// ------------------------------------------------------------------
// host launch
// ------------------------------------------------------------------
extern "C" void kernel_launch(void* const* d_in, const int* in_sizes, int n_in,
                              void* d_out, int out_size, void* d_ws, size_t ws_size,
                              hipStream_t stream)
{
  const float* pos   = (const float*)d_in[0];
  const int*   z     = (const int*)d_in[1];
  const int*   batch = (const int*)d_in[2];
  const int*   eidx  = (const int*)d_in[3];
  const float* emb   = (const float*)d_in[4];
  const float* mlp_w1 = (const float*)d_in[5];
  const float* mlp_b1 = (const float*)d_in[6];
  const float* mlp_w2 = (const float*)d_in[7];
  const float* mlp_b2 = (const float*)d_in[8];
  const float* lin1_w = (const float*)d_in[9];
  const float* lin2_w = (const float*)d_in[10];
  const float* lin2_b = (const float*)d_in[11];
  const float* blk_w  = (const float*)d_in[12];
  const float* blk_b  = (const float*)d_in[13];
  const float* hw1 = (const float*)d_in[14];
  const float* hb1 = (const float*)d_in[15];
  const float* hw2 = (const float*)d_in[16];
  const float* hb2 = (const float*)d_in[17];

  float* out = (float*)d_out;          // [NMOL] energies ++ [N,3] forces
  float* ws  = (float*)d_ws;

  const int* row = eidx;
  const int* col = eidx + N_EDGES;

  const size_t NH = (size_t)N_ATOMS * HD;
  size_t o = 0;
  float* ddslot = ws + o; o += N_EDGES;
  int* cptr = (int*)(ws + o); o += N_ATOMS + 1;
  int* rptr = (int*)(ws + o); o += N_ATOMS + 1;
  int* cnt0 = (int*)(ws + o); o += N_ATOMS;      // cnt0,cnt1 contiguous:
  int* cnt1 = (int*)(ws + o); o += N_ATOMS;      // one memset
  int* binc = (int*)(ws + o); o += 256;
  int* binr = (int*)(ws + o); o += 256;
  int* cur0 = (int*)(ws + o); o += N_ATOMS;
  int* cur1 = (int*)(ws + o); o += N_ATOMS;
  int* permc = (int*)(ws + o); o += N_ATOMS;
  int* permr = (int*)(ws + o); o += N_ATOMS;
  int* cslot = (int*)(ws + o); o += N_EDGES;
  o = (o + 1) & ~(size_t)1;                      // 8B align for uint2
  uint2* cpk2 = (uint2*)(ws + o); o += (size_t)2 * N_EDGES;
  uint2* rpk2 = (uint2*)(ws + o); o += (size_t)2 * N_EDGES;
  // bf16 weights: wt = transposed, wp = plain, mt = transposed mlp weights
  u16* wt = (u16*)(ws + o); o += (size_t)NLAY * 3 * HD * HD / 2;
  u16* wp = (u16*)(ws + o); o += (size_t)NLAY * 3 * HD * HD / 2;
  u16* mt = (u16*)(ws + o); o += (size_t)NLAY * 2 * HD * HD / 2;
  u16* hw1t = (u16*)(ws + o); o += (size_t)HD * 64 / 2;   // [64][128] bf16
  u16* hw1b = (u16*)(ws + o); o += (size_t)HD * 64 / 2;   // [128][64] bf16
  float* hxb[4];   // bf16 (128 u16 per row) -> NH/2 floats each
  for (int i = 0; i < 4; i++) { hxb[i] = ws + o; o += NH / 2; }
  float* svb[4];   // bf16 sigm(V) -> NH/2 floats each
  for (int i = 0; i < 4; i++) { svb[i] = ws + o; o += NH / 2; }
  float* hA  = ws + o; o += NH;
  float* hB  = ws + o; o += NH;
  float* agg = ws + o; o += NH;       // fwd agg / bwd dhx / table temps
  float* g0b = ws + o; o += NH;
  float* g1b = ws + o; o += NH;
  float* dgb = ws + o; o += NH / 2;   // dagg(bf16) / ea

  // table: bf16 pairs {P*C, (P*C)'}, 1 uint per (node,ch)
  int NT = 1024;
  while (NT > 128) {
    size_t need = o + (size_t)NLAY * (NT + 1) * HD;
    if (need * sizeof(float) <= ws_size) break;
    NT >>= 1;
  }
  const int NN = NT + 1;
  const float hstep = FCUT / (float)NT;
  const float inv_h = (float)NT / FCUT;
  unsigned* T = (unsigned*)(ws + o); o += (size_t)NLAY * NN * HD;

  const int EB = (N_EDGES + 255) / 256;
  const int ABK = (N_ATOMS + 255) / 256;

  hipMemsetAsync(cnt0, 0, 2 * N_ATOMS * sizeof(int), stream);

  wprep_k<<<(NLAY * 5 * HD * HD + HD * 64 + 255) / 256, 256, 0, stream>>>(
      lin1_w, lin2_w, blk_w, mlp_w1, mlp_w2, hw1, wt, wp, mt, hw1t, hw1b);

  // ---------------- CSR build (both directions) ----------------
  histboth_k<<<EB, 256, 0, stream>>>(row, col, cnt1, cnt0);
  scan2_k<<<2, 256, 0, stream>>>(cnt0, cnt1, cptr, rptr, cur0, cur1, binc, binr);
  scatboth_k<<<EB, 256, 0, stream>>>(pos, row, col, cur0, cur1, cpk2, rpk2,
                                     cslot, inv_h);

  // ---------------- degree-sort perms (bins already prefixed) ----------
  dscat_k<<<ABK, 256, 0, stream>>>(cptr, rptr, binc, binr, permc, permr);

  // ---------------- build filter tables (all 4 layers, fused) ----------
  {
    float* Anode  = agg;
    float* dAnode = agg + (size_t)NN * HD;
    float* s  = g1b;
    float* sp = hA;
    nodeA_k<<<((NN * HD) + 255) / 256, 256, 0, stream>>>(Anode, dAnode, NN, hstep);
    dim3 gB16((NN + 15) / 16, NLAY);
    tblA_k<<<gB16, 256, 0, stream>>>(Anode, dAnode, mt, mlp_b1, s, sp, NN);
    tblB_k<<<gB16, 256, 0, stream>>>(s, sp, mt, mlp_b2, T, NN, hstep);
  }

  h0_k<<<(N_ATOMS * HD + 255) / 256, 256, 0, stream>>>(emb, z, hA);

  const int AB = (N_ATOMS + 3) / 4;
  const int NB16 = (N_ATOMS + 15) / 16;   // 1250 blocks for no-LDS MFMA GEMMs
  const int HB = (N_ATOMS + 31) / 32;     // 625 blocks for the MFMA head

  // ---------------- forward ----------------
  float* hcur = hA;
  float* hnxt = hB;
  nmm_hx_k<<<NB16, 256, 0, stream>>>(hcur, wt, (u16*)hxb[0], N_ATOMS);
  for (int i = 0; i < NLAY; i++) {
    const u16* l2t = wt + ((size_t)(i*3 + 1) << 14);
    const u16* bwt = wt + ((size_t)(i*3 + 2) << 14);
    const u16* l1n = (i < NLAY - 1) ? wt + ((size_t)((i+1)*3 + 0) << 14) : nullptr;
    u16* hxn = (i < NLAY - 1) ? (u16*)hxb[i+1] : nullptr;
    const float* l2bi = lin2_b + (size_t)i * HD;
    const float* bbi  = blk_b + (size_t)i * HD;
    const unsigned* Tl = T + (size_t)i * NN * HD;

    gath_fwd_k<<<AB, 256, 0, stream>>>(permc, cptr, cpk2, Tl,
                                       (const unsigned*)hxb[i], agg, hstep);
    ftail_f_k<<<NB16, 256, 0, stream>>>(agg, l2t, l2bi, bwt, bbi, hcur,
                                        (u16*)svb[i], hnxt, l1n, hxn, N_ATOMS);
    float* tmp = hcur; hcur = hnxt; hnxt = tmp;
  }

  // ---------------- head (MFMA fused) + per-molecule energy ----------------
  // NLAY even -> hcur == hA here
  float* ea = dgb;
  headf_mfma_k<<<HB, 256, 0, stream>>>(hcur, hw1t, hb1, hw2, hw1b, hb2,
                                       ea, g0b, N_ATOMS);
  ered_k<<<NMOL, 64, 0, stream>>>(batch, ea, out);

  // ---------------- backward ----------------
  // g_3 = gh (g0b). For i < 3 the bwdT GEMM of layer i+1 is fused into
  // bhead2: g_i = agg(dhx_{i+1}) @ l1_{i+1}^T + g_{i+1}, stored to gnxt
  // (except at i==0 where g_0 is never consumed).
  float* gcur = g0b;
  float* gnxt = g1b;
  for (int i = NLAY - 1; i >= 0; i--) {
    const u16* l2p = wp + ((size_t)(i*3 + 1) << 14);
    const u16* bwp = wp + ((size_t)(i*3 + 2) << 14);
    const unsigned* Tl = T + (size_t)i * NN * HD;

    if (i == NLAY - 1) {
      bhead2_f_k<<<NB16, 256, 0, stream>>>(nullptr, nullptr, nullptr, gcur,
                                           bwp, (const u16*)svb[i], l2p,
                                           (u16*)dgb, nullptr, N_ATOMS);
    } else {
      const u16* l1nx = wp + ((size_t)((i+1)*3 + 0) << 14);
      float* gout = (i > 0) ? gnxt : nullptr;
      bhead2_f_k<<<NB16, 256, 0, stream>>>(agg, l1nx, gcur, nullptr,
                                           bwp, (const u16*)svb[i], l2p,
                                           (u16*)dgb, gout, N_ATOMS);
      if (i > 0) { float* tmp = gcur; gcur = gnxt; gnxt = tmp; }
    }
    gath_bwd_k<<<AB, 256, 0, stream>>>(permr, rptr, rpk2, Tl,
                                       (const unsigned*)dgb,
                                       (const unsigned*)hxb[i], agg, ddslot,
                                       i != NLAY - 1, i != 0, hstep, inv_h);
  }

  forceg_k<<<(N_ATOMS * 8 + 255) / 256, 256, 0, stream>>>(
      rptr, rpk2, cptr, cpk2, cslot, ddslot, pos, out + NMOL, hstep);
}